// Round 6
// baseline (559.925 us; speedup 1.0000x reference)
//
#include <hip/hip_runtime.h>
#include <stdint.h>

typedef unsigned short u16;
typedef unsigned int u32;

// Problem constants
#define B_    2
#define S_    2048
#define NQ_   16
#define NKV_  4
#define DH_   128
#define DR_   64
#define DT_   192
#define M_    4096   // B_*S_

using short8 = __attribute__((ext_vector_type(8))) short;
using f32x4  = __attribute__((ext_vector_type(4))) float;
using half8  = __attribute__((ext_vector_type(8))) _Float16;
using u16x4  = __attribute__((ext_vector_type(4))) u16;

__device__ __forceinline__ float cl(float f) {   // clamp diagnostic: inf/NaN -> +-3.38e38 signature
    return fminf(fmaxf(f, -3.38e38f), 3.38e38f);
}
__device__ __forceinline__ u16 f2b(float f) {    // fp32 -> bf16 RNE
    union { float f; u32 u; } v; v.f = f;
    u32 u = v.u;
    return (u16)((u + 0x7fffu + ((u >> 16) & 1u)) >> 16);
}
// async global->LDS, 16B per lane. LDS dest is wave-uniform base + lane*16.
__device__ __forceinline__ void gload16(const void* g, void* l) {
    __builtin_amdgcn_global_load_lds(
        (const __attribute__((address_space(1))) void*)g,
        (__attribute__((address_space(3))) void*)l,
        16, 0, 0);
}

// ---------------------------------------------------------------------------
// x_f16: x fp32 -> fp16
// ---------------------------------------------------------------------------
__global__ __launch_bounds__(256) void x_f16(const float* __restrict__ X,
                                             _Float16* __restrict__ F) {
    size_t i = ((size_t)blockIdx.x * 256 + threadIdx.x) * 8;
    float4 a = *(const float4*)(X + i);
    float4 b4 = *(const float4*)(X + i + 4);
    float va[8] = {a.x, a.y, a.z, a.w, b4.x, b4.y, b4.z, b4.w};
    half8 f;
#pragma unroll
    for (int j = 0; j < 8; ++j) f[j] = (_Float16)va[j];
    *(half8*)(F + i) = f;
}

// ---------------------------------------------------------------------------
// Weight transpose to fp16: W[K][N] fp32 -> T [N][K] fp16.
// block (32,8), grid (K/32, N/32)
// ---------------------------------------------------------------------------
__global__ __launch_bounds__(256) void wt_f16(const float* __restrict__ W,
                                              _Float16* __restrict__ T,
                                              int K, int N) {
    __shared__ float tile[32][33];
    int k0 = blockIdx.x * 32, n0 = blockIdx.y * 32;
    int tx = threadIdx.x, ty = threadIdx.y;
#pragma unroll
    for (int i = 0; i < 32; i += 8)
        tile[ty + i][tx] = W[(size_t)(k0 + ty + i) * N + n0 + tx];
    __syncthreads();
#pragma unroll
    for (int i = 0; i < 32; i += 8)
        T[(size_t)(n0 + ty + i) * K + k0 + tx] = (_Float16)tile[tx][ty + i];
}

// ---------------------------------------------------------------------------
// fp16 single-pass MFMA GEMM body. C = A[M][lda] @ Bt[N][K]^T, fp32 accum.
// Tile 128x128, BK=32, 4 waves (2x2), global_load_lds staging. [verified r3-r5]
// Epilogue modes:
//  0: p0 = fp32 C [stride N], clamped
//  2: p0 = qb16 bf16 [m][h*192 + (n&127)], scaled by cscale (Q content)
//  3: p0 = Kp bf16 [g][s][192] cols 0..127 (n<512);
//     p1 = Vt bf16 [g][d][2048]            (n>=512)   -- fused K/V pack
//  6: mega projection split:
//     nn<512 : p0=ckv fp32 [m][512] (cl) + p1=ckf fp16 [m][512]
//     nn<768 : p2=krr fp32 [m][256]
//     nn<2304: p3=dqc fp16 [m][1536]
//     else   : p4=qrf fp16 [m][1024]
// Layouts [m89/m91 verified]: A-frag A[m=lane&15][k=quad*8+j];
// B-frag B[n=lane&15][k=quad*8+j]; C/D col=lane&15, row=quad*4+reg.
// ---------------------------------------------------------------------------
__device__ __forceinline__ void gemm_body(const _Float16* __restrict__ A, int lda,
                                          const _Float16* __restrict__ Bt,
                                          void* p0, void* p1, void* p2,
                                          void* p3, void* p4,
                                          float cscale, int mode,
                                          int N, int K, int bx,
                                          _Float16* lA, _Float16* lB) {
    const int t = threadIdx.x, lane = t & 63, w = t >> 6;
    const int quad = lane >> 4, l16 = lane & 15;
    const int wr = w >> 1, wc = w & 1;
    const int m0 = blockIdx.y * 128, n0 = bx * 128;
    f32x4 acc[4][4] = {};

    for (int kt = 0; kt < K; kt += 32) {
        __syncthreads();
#pragma unroll
        for (int c = 0; c < 2; ++c) {
            const int chunk = c * 256 + t;
            const int row = chunk >> 2, co = (chunk & 3) * 8;
            const int lofs = (c * 256 + w * 64) * 8;   // fp16 units, wave-uniform
            gload16(A + (size_t)(m0 + row) * lda + kt + co, lA + lofs);
            gload16(Bt + (size_t)(n0 + row) * K + kt + co, lB + lofs);
        }
        __syncthreads();
        half8 af[4], bf4[4];
#pragma unroll
        for (int i = 0; i < 4; ++i) {
            af[i]  = *(const half8*)&lA[(wr * 64 + i * 16 + l16) * 32 + quad * 8];
            bf4[i] = *(const half8*)&lB[(wc * 64 + i * 16 + l16) * 32 + quad * 8];
        }
#pragma unroll
        for (int i = 0; i < 4; ++i)
#pragma unroll
            for (int j = 0; j < 4; ++j)
                acc[i][j] = __builtin_amdgcn_mfma_f32_16x16x32_f16(af[i], bf4[j], acc[i][j], 0, 0, 0);
    }
#pragma unroll
    for (int i = 0; i < 4; ++i)
#pragma unroll
        for (int j = 0; j < 4; ++j) {
            const int mbase = m0 + wr * 64 + i * 16 + quad * 4;
            const int nn = n0 + wc * 64 + j * 16 + l16;
            if (mode == 0) {
                float* C = (float*)p0;
#pragma unroll
                for (int r = 0; r < 4; ++r)
                    C[(size_t)(mbase + r) * N + nn] = cl(acc[i][j][r]);
            } else if (mode == 2) {
                u16* Q = (u16*)p0;
                const int h = nn >> 7, dcol = nn & 127;
#pragma unroll
                for (int r = 0; r < 4; ++r)
                    Q[(size_t)(mbase + r) * 3072 + h * 192 + dcol] =
                        f2b(acc[i][j][r] * cscale);
            } else if (mode == 3) {
                const int bb = mbase >> 11, s = mbase & 2047;
                if (nn < 512) {
                    u16* Kp = (u16*)p0;
                    const int kv = nn >> 7, d = nn & 127;
                    const size_t rb = ((size_t)((bb * 4 + kv) * 2048 + s)) * 192 + d;
#pragma unroll
                    for (int r = 0; r < 4; ++r)
                        Kp[rb + (size_t)r * 192] = f2b(acc[i][j][r]);
                } else {
                    u16* Vt = (u16*)p1;
                    const int e = nn - 512, kv = e >> 7, d = e & 127;
                    u16x4 pk;
                    pk[0] = f2b(acc[i][j][0]); pk[1] = f2b(acc[i][j][1]);
                    pk[2] = f2b(acc[i][j][2]); pk[3] = f2b(acc[i][j][3]);
                    *(u16x4*)&((u16*)Vt)[((size_t)((bb * 4 + kv) * 128 + d)) * 2048 + s] = pk;
                }
            } else {   // mode 6: mega projection split
                if (nn < 512) {
                    float* ckv = (float*)p0;
                    _Float16* ckf = (_Float16*)p1;
#pragma unroll
                    for (int r = 0; r < 4; ++r) {
                        float v = acc[i][j][r];
                        ckv[(size_t)(mbase + r) * 512 + nn] = cl(v);
                        ckf[(size_t)(mbase + r) * 512 + nn] = (_Float16)v;
                    }
                } else if (nn < 768) {
                    float* krr = (float*)p2;
#pragma unroll
                    for (int r = 0; r < 4; ++r)
                        krr[(size_t)(mbase + r) * 256 + (nn - 512)] = acc[i][j][r];
                } else if (nn < 2304) {
                    _Float16* dqc = (_Float16*)p3;
#pragma unroll
                    for (int r = 0; r < 4; ++r)
                        dqc[(size_t)(mbase + r) * 1536 + (nn - 768)] = (_Float16)acc[i][j][r];
                } else {
                    _Float16* qrf = (_Float16*)p4;
#pragma unroll
                    for (int r = 0; r < 4; ++r)
                        qrf[(size_t)(mbase + r) * 1024 + (nn - 2304)] = (_Float16)acc[i][j][r];
                }
            }
        }
}

__global__ __launch_bounds__(256) void gemm_f16(const _Float16* __restrict__ A, int lda,
                                                const _Float16* __restrict__ Bt,
                                                void* p0, void* p1, void* p2,
                                                void* p3, void* p4,
                                                float cscale, int mode,
                                                int N, int K) {
    __shared__ __align__(16) _Float16 lA[128 * 32];
    __shared__ __align__(16) _Float16 lB[128 * 32];
    gemm_body(A, lda, Bt, p0, p1, p2, p3, p4, cscale, mode, N, K, blockIdx.x, lA, lB);
}

// Heterogeneous dispatch: blocks x<16 -> UQ (Q content, mode 2);
// x>=16 -> UKV (K content | V pack, mode 3). 768 blocks = 3/CU.
__global__ __launch_bounds__(256) void gemm_uqkv(const _Float16* __restrict__ dqc,
                                                 const _Float16* __restrict__ Wuq,
                                                 u16* __restrict__ qb16, float sc,
                                                 const _Float16* __restrict__ ckf,
                                                 const _Float16* __restrict__ Wukv,
                                                 u16* __restrict__ Kp,
                                                 u16* __restrict__ Vt) {
    __shared__ __align__(16) _Float16 lA[128 * 32];
    __shared__ __align__(16) _Float16 lB[128 * 32];
    const int bx = blockIdx.x;
    if (bx < 16)
        gemm_body(dqc, 1536, Wuq, qb16, nullptr, nullptr, nullptr, nullptr,
                  sc, 2, 2048, 1536, bx, lA, lB);
    else
        gemm_body(ckf, 512, Wukv, Kp, Vt, nullptr, nullptr, nullptr,
                  1.f, 3, 1024, 512, bx - 16, lA, lB);
}

// ---------------------------------------------------------------------------
// RoPE Q: qrf fp16 [(b,s)][1024] -> qb16 bf16 [(b,s)][h*192+128+d],
// pre-scaled by 1/sqrt(192).
// ---------------------------------------------------------------------------
__global__ __launch_bounds__(256) void rope_q16(const _Float16* __restrict__ qrf,
                                                const float* __restrict__ cosc,
                                                const float* __restrict__ sinc,
                                                const int* __restrict__ pos,
                                                u16* __restrict__ qb16) {
    const float sc = 0.07216878364870322f;           // 1/sqrt(192)
    int t = blockIdx.x * 256 + threadIdx.x;          // t < 4096*16*32
    int d = t & 31, h = (t >> 5) & 15, rowi = t >> 9;
    int s = rowi & 2047;
    int p = pos[s];
    float c1 = cosc[p * 64 + d],      s1 = sinc[p * 64 + d];
    float c2 = cosc[p * 64 + 32 + d], s2 = sinc[p * 64 + 32 + d];
    const _Float16* base = qrf + (size_t)rowi * 1024 + h * 64;
    float x1 = (float)base[d];
    float x2 = (float)base[d + 32];
    u16* q = qb16 + (size_t)rowi * 3072 + h * 192 + 128;
    q[d]      = f2b((x1 * c1 - x2 * s1) * sc);
    q[d + 32] = f2b((x2 * c2 + x1 * s2) * sc);
}

// RoPE K: krr fp32 [(b,s)][256] -> Krope fp32 (Output 2) + Kp bf16 cols 128..191
__global__ __launch_bounds__(256) void rope_k(const float* __restrict__ krr,
                                              const float* __restrict__ cosc,
                                              const float* __restrict__ sinc,
                                              const int* __restrict__ pos,
                                              float* __restrict__ Krope,
                                              u16* __restrict__ Kp) {
    int t = blockIdx.x * 256 + threadIdx.x;          // t < 4096*4*32
    int d = t & 31, kv = (t >> 5) & 3, rowi = t >> 7;
    int b = rowi >> 11, s = rowi & 2047;
    int p = pos[s];
    float c1 = cosc[p * 64 + d],      s1 = sinc[p * 64 + d];
    float c2 = cosc[p * 64 + 32 + d], s2 = sinc[p * 64 + 32 + d];
    float x1 = krr[(size_t)rowi * 256 + kv * 64 + d];
    float x2 = krr[(size_t)rowi * 256 + kv * 64 + 32 + d];
    float o1 = x1 * c1 - x2 * s1;
    float o2 = x2 * c2 + x1 * s2;
    int g = b * NKV_ + kv;
    size_t ob = ((size_t)(g * S_) + s) * 64;
    Krope[ob + d]      = cl(o1);
    Krope[ob + 32 + d] = cl(o2);
    u16* kp = Kp + ((size_t)(g * S_ + s)) * 192 + 128;
    kp[d]      = f2b(o1);
    kp[32 + d] = f2b(o2);
}

// ---------------------------------------------------------------------------
// MFMA flash attention. Block = 4 waves = 64 q-rows of one (b,h).
// Paired q-tiles: qt = 31-px then px -> 33 kv-tile units per block, uniform.
// Flat grid 512; id decode puts the 64 blocks of each KV group g on one XCD
// (id&7 == g) so K/V (~1.3MB/g) stay in the 4MB XCD L2. [verified r5: FETCH
// 48.8->17.7MB]
// T14 async-stage: K/V tile t+1 global-loaded into regs (10x uint4/thread)
// right after tile t's stage barrier, flattened across both q-tile phases --
// HBM/L2 latency hides under compute. ds_write from regs + 2 barriers per tile.
// Mask-skip: only the LAST kv-tile per q-tile is diagonal (j0+63 <= iw for all
// earlier tiles) -> mask VALU runs once per q-tile.
// Row-sum l via bf16-ones d-row (row 128) in lVt: PV's 9th n-chunk accumulates
// l into O9[8]. Defer-max (T13, THR=8) skips O-rescale when max grows <= 8.
// Q from qb16 bf16 [(b,s)][h*192+k], pre-scaled by 1/sqrt(192).
// Out: atf fp16 [(b,s)][h*128+d].
// Layouts [m89/m91 verified]: A-frag A[m=lane&15][k=quad*8+j];
// B-frag B[n=lane&15][k=quad*8+j]; C/D col=lane&15, row=quad*4+reg.
// ---------------------------------------------------------------------------
__global__ __launch_bounds__(256) void attn_mfma(const u16* __restrict__ qb16,
                                                 const u16* __restrict__ Kp,
                                                 const u16* __restrict__ Vt,
                                                 _Float16* __restrict__ atf) {
    __shared__ __align__(16) u16 lK[64 * 200];     // 64 kv-rows x 192 (+8 pad)
    __shared__ __align__(16) u16 lVt[144 * 72];    // 128 d-rows + 16 (ones) x 64 (+8 pad)
    __shared__ __align__(16) u16 lP[4][16 * 72];   // per-wave P 16x64 (+8 pad)

    const int t = threadIdx.x, lane = t & 63, w = t >> 6;
    const int quad = lane >> 4, l16 = lane & 15;
    // XCD-aligned decode: g = id&7 so all blocks of a KV group share an XCD
    const int id = blockIdx.x;                     // 0..511
    const int g = id & 7;                          // (b*4 + kv)
    const int b = g >> 2;
    const int k = id >> 3;                         // 0..63
    const int h = (g & 3) * 4 + (k & 3);
    const int px = k >> 2;                         // 0..15

    // ones-row init for the l-column trick (rows 128..143, cols 0..63)
#pragma unroll
    for (int c = 0; c < 4; ++c) {
        int i = c * 256 + t;                       // 0..1023
        int rr = 128 + (i >> 6), ccol = i & 63;
        lVt[rr * 72 + ccol] = (rr == 128) ? (u16)0x3F80 : (u16)0;
    }

    // T14 prefetch registers (per-thread fixed LDS coords)
    uint4 kreg0, kreg1, kreg2, kreg3, kreg4, kreg5;
    uint4 vreg0, vreg1, vreg2, vreg3;
#define PREFETCH(j0)                                                            \
    {                                                                           \
        const int _j0 = (j0);                                                   \
        { int seg = t;            kreg0 = *(const uint4*)&Kp[((size_t)g * S_ + _j0 + seg / 24) * 192 + (seg % 24) * 8]; } \
        { int seg = 256 + t;      kreg1 = *(const uint4*)&Kp[((size_t)g * S_ + _j0 + seg / 24) * 192 + (seg % 24) * 8]; } \
        { int seg = 512 + t;      kreg2 = *(const uint4*)&Kp[((size_t)g * S_ + _j0 + seg / 24) * 192 + (seg % 24) * 8]; } \
        { int seg = 768 + t;      kreg3 = *(const uint4*)&Kp[((size_t)g * S_ + _j0 + seg / 24) * 192 + (seg % 24) * 8]; } \
        { int seg = 1024 + t;     kreg4 = *(const uint4*)&Kp[((size_t)g * S_ + _j0 + seg / 24) * 192 + (seg % 24) * 8]; } \
        { int seg = 1280 + t;     kreg5 = *(const uint4*)&Kp[((size_t)g * S_ + _j0 + seg / 24) * 192 + (seg % 24) * 8]; } \
        { int seg = t;            vreg0 = *(const uint4*)&Vt[((size_t)g * 128 + (seg >> 3)) * S_ + _j0 + (seg & 7) * 8]; } \
        { int seg = 256 + t;      vreg1 = *(const uint4*)&Vt[((size_t)g * 128 + (seg >> 3)) * S_ + _j0 + (seg & 7) * 8]; } \
        { int seg = 512 + t;      vreg2 = *(const uint4*)&Vt[((size_t)g * 128 + (seg >> 3)) * S_ + _j0 + (seg & 7) * 8]; } \
        { int seg = 768 + t;      vreg3 = *(const uint4*)&Vt[((size_t)g * 128 + (seg >> 3)) * S_ + _j0 + (seg & 7) * 8]; } \
    }

    PREFETCH(0);                                   // tile 0 of phase 0

    for (int ph = 0; ph < 2; ++ph) {
        const int qt = ph ? px : (31 - px);        // heavy tile first
        const int q0 = qt * 64;
        const int iw = q0 + w * 16;                // wave's q-row base

        // Q fragments: rows m=l16, contiguous 192-col row (pre-scaled bf16)
        short8 qf[6];
        {
            const u16* qp = qb16 + ((size_t)(b * S_ + iw + l16)) * 3072 + h * 192;
#pragma unroll
            for (int kc = 0; kc < 6; ++kc)
                qf[kc] = *(const short8*)&qp[kc * 32 + quad * 8];
        }

        f32x4 O9[9] = {};                          // [0..7]=O d-chunks, [8]=l (col l16==0)
        float mr[4] = {-1e30f, -1e30f, -1e30f, -1e30f};

        const int ntile = qt + 1;
        for (int tile = 0; tile < ntile; ++tile) {
            const int j0 = tile * 64;
            __syncthreads();                       // prev compute done, LDS writable
            // ds_write staged regs (same per-thread coords as prefetch)
            { int seg = t;        *(uint4*)&lK[(seg / 24) * 200 + (seg % 24) * 8] = kreg0; }
            { int seg = 256 + t;  *(uint4*)&lK[(seg / 24) * 200 + (seg % 24) * 8] = kreg1; }
            { int seg = 512 + t;  *(uint4*)&lK[(seg / 24) * 200 + (seg % 24) * 8] = kreg2; }
            { int seg = 768 + t;  *(uint4*)&lK[(seg / 24) * 200 + (seg % 24) * 8] = kreg3; }
            { int seg = 1024 + t; *(uint4*)&lK[(seg / 24) * 200 + (seg % 24) * 8] = kreg4; }
            { int seg = 1280 + t; *(uint4*)&lK[(seg / 24) * 200 + (seg % 24) * 8] = kreg5; }
            { int seg = t;        *(uint4*)&lVt[(seg >> 3) * 72 + (seg & 7) * 8] = vreg0; }
            { int seg = 256 + t;  *(uint4*)&lVt[(seg >> 3) * 72 + (seg & 7) * 8] = vreg1; }
            { int seg = 512 + t;  *(uint4*)&lVt[(seg >> 3) * 72 + (seg & 7) * 8] = vreg2; }
            { int seg = 768 + t;  *(uint4*)&lVt[(seg >> 3) * 72 + (seg & 7) * 8] = vreg3; }
            __syncthreads();
            // prefetch next tile in the flattened (ph0, ph1) sequence
            if (tile + 1 < ntile)      PREFETCH(j0 + 64)
            else if (ph == 0)          PREFETCH(0)

            // S = Q K^T, four 16-col chunks
            f32x4 s4[4];
            __builtin_amdgcn_s_setprio(1);
#pragma unroll
            for (int cc = 0; cc < 4; ++cc) {
                f32x4 sx = {};
#pragma unroll
                for (int kc = 0; kc < 6; ++kc) {
                    short8 kf = *(const short8*)&lK[(cc * 16 + l16) * 200 + kc * 32 + quad * 8];
                    sx = __builtin_amdgcn_mfma_f32_16x16x32_bf16(qf[kc], kf, sx, 0, 0, 0);
                }
                s4[cc] = sx;
            }
            __builtin_amdgcn_s_setprio(0);

            // mask only the diagonal tile (provably the last one per q-tile)
            float sv[4][4];
#pragma unroll
            for (int cc = 0; cc < 4; ++cc)
#pragma unroll
                for (int r = 0; r < 4; ++r) sv[cc][r] = s4[cc][r];
            if (tile == ntile - 1) {
#pragma unroll
                for (int cc = 0; cc < 4; ++cc)
#pragma unroll
                    for (int r = 0; r < 4; ++r) {
                        int ir = iw + quad * 4 + r;
                        if (j0 + cc * 16 + l16 > ir) sv[cc][r] = -1e30f;
                    }
            }
            // row max across the 16-lane group
            float tm[4];
#pragma unroll
            for (int r = 0; r < 4; ++r)
                tm[r] = fmaxf(fmaxf(sv[0][r], sv[1][r]), fmaxf(sv[2][r], sv[3][r]));
#pragma unroll
            for (int m = 1; m < 16; m <<= 1)
#pragma unroll
                for (int r = 0; r < 4; ++r) tm[r] = fmaxf(tm[r], __shfl_xor(tm[r], m));
            // defer-max: only rescale when the max grew by > 8
            int small = (tm[0] <= mr[0] + 8.f) && (tm[1] <= mr[1] + 8.f) &&
                        (tm[2] <= mr[2] + 8.f) && (tm[3] <= mr[3] + 8.f);
            if (!__all(small)) {
                float al[4];
#pragma unroll
                for (int r = 0; r < 4; ++r) {
                    float mn = fmaxf(mr[r], tm[r]);
                    al[r] = __expf(mr[r] - mn);
                    mr[r] = mn;
                }
#pragma unroll
                for (int dc = 0; dc < 9; ++dc)
#pragma unroll
                    for (int r = 0; r < 4; ++r) O9[dc][r] *= al[r];
            }
            // P = exp(S - mr)  (bounded by e^8 when deferred)
            float p[4][4];
#pragma unroll
            for (int cc = 0; cc < 4; ++cc)
#pragma unroll
                for (int r = 0; r < 4; ++r)
                    p[cc][r] = __expf(sv[cc][r] - mr[r]);
            // P (C layout) -> LDS -> A-layout frags (k = 0..31, 32..63)
#pragma unroll
            for (int cc = 0; cc < 4; ++cc)
#pragma unroll
                for (int r = 0; r < 4; ++r)
                    lP[w][(quad * 4 + r) * 72 + cc * 16 + l16] = f2b(p[cc][r]);
            short8 pf0 = *(const short8*)&lP[w][l16 * 72 + quad * 8];
            short8 pf1 = *(const short8*)&lP[w][l16 * 72 + 32 + quad * 8];
            // O += P V ; 9th chunk accumulates l via the ones-row
            __builtin_amdgcn_s_setprio(1);
#pragma unroll
            for (int dc = 0; dc < 9; ++dc) {
                short8 vf0 = *(const short8*)&lVt[(dc * 16 + l16) * 72 + quad * 8];
                short8 vf1 = *(const short8*)&lVt[(dc * 16 + l16) * 72 + 32 + quad * 8];
                O9[dc] = __builtin_amdgcn_mfma_f32_16x16x32_bf16(pf0, vf0, O9[dc], 0, 0, 0);
                O9[dc] = __builtin_amdgcn_mfma_f32_16x16x32_bf16(pf1, vf1, O9[dc], 0, 0, 0);
            }
            __builtin_amdgcn_s_setprio(0);
        }
        // epilogue: l lives in O9[8] at col l16==0; broadcast within quad
        float inv[4];
#pragma unroll
        for (int r = 0; r < 4; ++r) {
            float lr = __shfl(O9[8][r], quad * 16);
            inv[r] = 1.f / fmaxf(lr, 1e-30f);
        }
#pragma unroll
        for (int dc = 0; dc < 8; ++dc)
#pragma unroll
            for (int r = 0; r < 4; ++r) {
                int ir = iw + quad * 4 + r;
                atf[((size_t)(b * S_ + ir)) * 2048 + h * 128 + dc * 16 + l16] =
                    (_Float16)cl(O9[dc][r] * inv[r]);
            }
    }
#undef PREFETCH
}

// ---------------------------------------------------------------------------
extern "C" void kernel_launch(void* const* d_in, const int* in_sizes, int n_in,
                              void* d_out, int out_size, void* d_ws, size_t ws_size,
                              hipStream_t stream) {
    const float* x     = (const float*)d_in[0];
    const float* cosc  = (const float*)d_in[1];
    const float* sinc  = (const float*)d_in[2];
    const int*   pos   = (const int*)d_in[3];
    // d_in[4] = attn_mask (causal tril) -- implemented analytically
    const float* W_DKV = (const float*)d_in[5];
    const float* W_UK  = (const float*)d_in[6];
    const float* W_UV  = (const float*)d_in[7];
    const float* W_DQ  = (const float*)d_in[8];
    const float* W_UQ  = (const float*)d_in[9];
    const float* W_KR  = (const float*)d_in[10];
    const float* W_QR  = (const float*)d_in[11];
    const float* W_O   = (const float*)d_in[12];
    (void)ws_size;

    float* outp      = (float*)d_out;            // [B,S,2048]
    float* ckv_out   = outp + 8388608;           // [B,S,512]
    float* krope_out = outp + 10485760;          // [B,NKV,S,64]

    // ---- workspace (~128 MB) ----
    char* w = (char*)d_ws;
    auto alloc = [&](size_t bytes) { char* p = w; w += bytes; return p; };
    _Float16* xf   = (_Float16*)alloc(16777216);  // x fp16 [4096][2048]
    _Float16* ckf  = (_Float16*)alloc(4194304);   // c_kv fp16 [4096][512]
    float*    krr  = (float*)alloc(4194304);      // K-rope raw fp32 [4096][256]
    _Float16* dqc  = (_Float16*)alloc(12582912);  // c_q fp16 [4096][1536]
    _Float16* qrf  = (_Float16*)alloc(8388608);   // q_rope_raw fp16 [4096][1024]
    u16*      qb16 = (u16*)alloc(25165824);       // Q bf16 pre-scaled [4096][16][192]
    u16*      Kp   = (u16*)alloc(6291456);        // [8][2048][192] bf16
    u16*      Vt   = (u16*)alloc(4194304);        // [8][128][2048] bf16
    _Float16* atf  = (_Float16*)alloc(16777216);  // attn out fp16 [4096][2048]
    _Float16* Wmeg = (_Float16*)alloc(13631488);  // [3328][2048] (DKV|KR|DQ|QR)
    _Float16* Wuq  = (_Float16*)alloc(6291456);   // [2048][1536]
    _Float16* Wukv = (_Float16*)alloc(1048576);   // [1024][512]  (UK|UV)
    _Float16* Wo   = (_Float16*)alloc(8388608);   // [2048][2048]

    const float sc = 0.07216878364870322f;        // 1/sqrt(192)
    const dim3 tb(32, 8);

    // input / weight prep (fp16)
    x_f16<<<4096, 256, 0, stream>>>(x, xf);
    wt_f16<<<dim3(64, 16), tb, 0, stream>>>(W_DKV, Wmeg, 2048, 512);
    wt_f16<<<dim3(64, 8),  tb, 0, stream>>>(W_KR,  Wmeg + (size_t)512 * 2048, 2048, 256);
    wt_f16<<<dim3(64, 48), tb, 0, stream>>>(W_DQ,  Wmeg + (size_t)768 * 2048, 2048, 1536);
    wt_f16<<<dim3(64, 32), tb, 0, stream>>>(W_QR,  Wmeg + (size_t)2304 * 2048, 2048, 1024);
    wt_f16<<<dim3(48, 64), tb, 0, stream>>>(W_UQ,  Wuq, 1536, 2048);
    wt_f16<<<dim3(16, 16), tb, 0, stream>>>(W_UK,  Wukv, 512, 512);
    wt_f16<<<dim3(16, 16), tb, 0, stream>>>(W_UV,  Wukv + (size_t)512 * 512, 512, 512);
    wt_f16<<<dim3(64, 64), tb, 0, stream>>>(W_O,   Wo, 2048, 2048);

    // mega projection: c_kv (Output 1) | ckf | K-rope-raw | c_q | q-rope-raw
    gemm_f16<<<dim3(26, 32), 256, 0, stream>>>(xf, 2048, Wmeg,
                                               ckv_out, ckf, krr, dqc, qrf,
                                               1.f, 6, 3328, 2048);
    // Q content (mode 2) + K content | V pack (mode 3), heterogeneous dispatch
    gemm_uqkv<<<dim3(24, 32), 256, 0, stream>>>(dqc, Wuq, qb16, sc,
                                                ckf, Wukv, Kp, Vt);

    // rope: Q -> qb16 cols 128..191; K -> Output 2 + Kp cols 128..191
    rope_q16<<<8192, 256, 0, stream>>>(qrf, cosc, sinc, pos, qb16);
    rope_k<<<2048, 256, 0, stream>>>(krr, cosc, sinc, pos, krope_out, Kp);

    // attention + output projection
    attn_mfma<<<512, 256, 0, stream>>>(qb16, Kp, Vt, atf);
    gemm_f16<<<dim3(16, 32), 256, 0, stream>>>(atf, 2048, Wo,
                                               outp, nullptr, nullptr, nullptr, nullptr,
                                               1.f, 0, 2048, 2048);
}

// Round 7
// 549.460 us; speedup vs baseline: 1.0190x; 1.0190x over previous
//
#include <hip/hip_runtime.h>
#include <stdint.h>

typedef unsigned short u16;
typedef unsigned int u32;

// Problem constants
#define B_    2
#define S_    2048
#define NQ_   16
#define NKV_  4
#define DH_   128
#define DR_   64
#define DT_   192
#define M_    4096   // B_*S_

using short8 = __attribute__((ext_vector_type(8))) short;
using f32x4  = __attribute__((ext_vector_type(4))) float;
using half8  = __attribute__((ext_vector_type(8))) _Float16;
using u16x4  = __attribute__((ext_vector_type(4))) u16;

__device__ __forceinline__ float cl(float f) {   // clamp diagnostic: inf/NaN -> +-3.38e38 signature
    return fminf(fmaxf(f, -3.38e38f), 3.38e38f);
}
__device__ __forceinline__ u16 f2b(float f) {    // fp32 -> bf16 RNE
    union { float f; u32 u; } v; v.f = f;
    u32 u = v.u;
    return (u16)((u + 0x7fffu + ((u >> 16) & 1u)) >> 16);
}
// async global->LDS, 16B per lane. LDS dest is wave-uniform base + lane*16.
__device__ __forceinline__ void gload16(const void* g, void* l) {
    __builtin_amdgcn_global_load_lds(
        (const __attribute__((address_space(1))) void*)g,
        (__attribute__((address_space(3))) void*)l,
        16, 0, 0);
}

// ---------------------------------------------------------------------------
// x_f16: x fp32 -> fp16
// ---------------------------------------------------------------------------
__global__ __launch_bounds__(256) void x_f16(const float* __restrict__ X,
                                             _Float16* __restrict__ F) {
    size_t i = ((size_t)blockIdx.x * 256 + threadIdx.x) * 8;
    float4 a = *(const float4*)(X + i);
    float4 b4 = *(const float4*)(X + i + 4);
    float va[8] = {a.x, a.y, a.z, a.w, b4.x, b4.y, b4.z, b4.w};
    half8 f;
#pragma unroll
    for (int j = 0; j < 8; ++j) f[j] = (_Float16)va[j];
    *(half8*)(F + i) = f;
}

// ---------------------------------------------------------------------------
// Weight transpose to fp16: W[K][N] fp32 -> T [N][K] fp16.
// block (32,8), grid (K/32, N/32)
// ---------------------------------------------------------------------------
__global__ __launch_bounds__(256) void wt_f16(const float* __restrict__ W,
                                              _Float16* __restrict__ T,
                                              int K, int N) {
    __shared__ float tile[32][33];
    int k0 = blockIdx.x * 32, n0 = blockIdx.y * 32;
    int tx = threadIdx.x, ty = threadIdx.y;
#pragma unroll
    for (int i = 0; i < 32; i += 8)
        tile[ty + i][tx] = W[(size_t)(k0 + ty + i) * N + n0 + tx];
    __syncthreads();
#pragma unroll
    for (int i = 0; i < 32; i += 8)
        T[(size_t)(n0 + ty + i) * K + k0 + tx] = (_Float16)tile[tx][ty + i];
}

// ---------------------------------------------------------------------------
// fp16 single-pass MFMA GEMM body. C = A[M][lda] @ Bt[N][K]^T, fp32 accum.
// Tile 128x128, BK=32, 4 waves (2x2), global_load_lds staging. [verified r3-r6]
// Epilogue modes:
//  0: p0 = fp32 C [stride N], clamped
//  2: p0 = qb16 bf16 [m][h*192 + (n&127)], scaled by cscale (Q content)
//  3: p0 = Kp bf16 [g][s][192] cols 0..127 (n<512);
//     p1 = Vt bf16 [g][d][2048]            (n>=512)   -- fused K/V pack
//  6: mega projection split:
//     nn<512 : p0=ckv fp32 [m][512] (cl) + p1=ckf fp16 [m][512]
//     nn<768 : p2=krr fp32 [m][256]
//     nn<2304: p3=dqc fp16 [m][1536]
//     else   : p4=qrf fp16 [m][1024]
// Layouts [m89/m91 verified]: A-frag A[m=lane&15][k=quad*8+j];
// B-frag B[n=lane&15][k=quad*8+j]; C/D col=lane&15, row=quad*4+reg.
// ---------------------------------------------------------------------------
__device__ __forceinline__ void gemm_body(const _Float16* __restrict__ A, int lda,
                                          const _Float16* __restrict__ Bt,
                                          void* p0, void* p1, void* p2,
                                          void* p3, void* p4,
                                          float cscale, int mode,
                                          int N, int K, int bx,
                                          _Float16* lA, _Float16* lB) {
    const int t = threadIdx.x, lane = t & 63, w = t >> 6;
    const int quad = lane >> 4, l16 = lane & 15;
    const int wr = w >> 1, wc = w & 1;
    const int m0 = blockIdx.y * 128, n0 = bx * 128;
    f32x4 acc[4][4] = {};

    for (int kt = 0; kt < K; kt += 32) {
        __syncthreads();
#pragma unroll
        for (int c = 0; c < 2; ++c) {
            const int chunk = c * 256 + t;
            const int row = chunk >> 2, co = (chunk & 3) * 8;
            const int lofs = (c * 256 + w * 64) * 8;   // fp16 units, wave-uniform
            gload16(A + (size_t)(m0 + row) * lda + kt + co, lA + lofs);
            gload16(Bt + (size_t)(n0 + row) * K + kt + co, lB + lofs);
        }
        __syncthreads();
        half8 af[4], bf4[4];
#pragma unroll
        for (int i = 0; i < 4; ++i) {
            af[i]  = *(const half8*)&lA[(wr * 64 + i * 16 + l16) * 32 + quad * 8];
            bf4[i] = *(const half8*)&lB[(wc * 64 + i * 16 + l16) * 32 + quad * 8];
        }
#pragma unroll
        for (int i = 0; i < 4; ++i)
#pragma unroll
            for (int j = 0; j < 4; ++j)
                acc[i][j] = __builtin_amdgcn_mfma_f32_16x16x32_f16(af[i], bf4[j], acc[i][j], 0, 0, 0);
    }
#pragma unroll
    for (int i = 0; i < 4; ++i)
#pragma unroll
        for (int j = 0; j < 4; ++j) {
            const int mbase = m0 + wr * 64 + i * 16 + quad * 4;
            const int nn = n0 + wc * 64 + j * 16 + l16;
            if (mode == 0) {
                float* C = (float*)p0;
#pragma unroll
                for (int r = 0; r < 4; ++r)
                    C[(size_t)(mbase + r) * N + nn] = cl(acc[i][j][r]);
            } else if (mode == 2) {
                u16* Q = (u16*)p0;
                const int h = nn >> 7, dcol = nn & 127;
#pragma unroll
                for (int r = 0; r < 4; ++r)
                    Q[(size_t)(mbase + r) * 3072 + h * 192 + dcol] =
                        f2b(acc[i][j][r] * cscale);
            } else if (mode == 3) {
                const int bb = mbase >> 11, s = mbase & 2047;
                if (nn < 512) {
                    u16* Kp = (u16*)p0;
                    const int kv = nn >> 7, d = nn & 127;
                    const size_t rb = ((size_t)((bb * 4 + kv) * 2048 + s)) * 192 + d;
#pragma unroll
                    for (int r = 0; r < 4; ++r)
                        Kp[rb + (size_t)r * 192] = f2b(acc[i][j][r]);
                } else {
                    u16* Vt = (u16*)p1;
                    const int e = nn - 512, kv = e >> 7, d = e & 127;
                    u16x4 pk;
                    pk[0] = f2b(acc[i][j][0]); pk[1] = f2b(acc[i][j][1]);
                    pk[2] = f2b(acc[i][j][2]); pk[3] = f2b(acc[i][j][3]);
                    *(u16x4*)&((u16*)Vt)[((size_t)((bb * 4 + kv) * 128 + d)) * 2048 + s] = pk;
                }
            } else {   // mode 6: mega projection split
                if (nn < 512) {
                    float* ckv = (float*)p0;
                    _Float16* ckf = (_Float16*)p1;
#pragma unroll
                    for (int r = 0; r < 4; ++r) {
                        float v = acc[i][j][r];
                        ckv[(size_t)(mbase + r) * 512 + nn] = cl(v);
                        ckf[(size_t)(mbase + r) * 512 + nn] = (_Float16)v;
                    }
                } else if (nn < 768) {
                    float* krr = (float*)p2;
#pragma unroll
                    for (int r = 0; r < 4; ++r)
                        krr[(size_t)(mbase + r) * 256 + (nn - 512)] = acc[i][j][r];
                } else if (nn < 2304) {
                    _Float16* dqc = (_Float16*)p3;
#pragma unroll
                    for (int r = 0; r < 4; ++r)
                        dqc[(size_t)(mbase + r) * 1536 + (nn - 768)] = (_Float16)acc[i][j][r];
                } else {
                    _Float16* qrf = (_Float16*)p4;
#pragma unroll
                    for (int r = 0; r < 4; ++r)
                        qrf[(size_t)(mbase + r) * 1024 + (nn - 2304)] = (_Float16)acc[i][j][r];
                }
            }
        }
}

__global__ __launch_bounds__(256) void gemm_f16(const _Float16* __restrict__ A, int lda,
                                                const _Float16* __restrict__ Bt,
                                                void* p0, void* p1, void* p2,
                                                void* p3, void* p4,
                                                float cscale, int mode,
                                                int N, int K) {
    __shared__ __align__(16) _Float16 lA[128 * 32];
    __shared__ __align__(16) _Float16 lB[128 * 32];
    gemm_body(A, lda, Bt, p0, p1, p2, p3, p4, cscale, mode, N, K, blockIdx.x, lA, lB);
}

// Heterogeneous dispatch: blocks x<16 -> UQ (Q content, mode 2);
// x>=16 -> UKV (K content | V pack, mode 3). 768 blocks = 3/CU.
__global__ __launch_bounds__(256) void gemm_uqkv(const _Float16* __restrict__ dqc,
                                                 const _Float16* __restrict__ Wuq,
                                                 u16* __restrict__ qb16, float sc,
                                                 const _Float16* __restrict__ ckf,
                                                 const _Float16* __restrict__ Wukv,
                                                 u16* __restrict__ Kp,
                                                 u16* __restrict__ Vt) {
    __shared__ __align__(16) _Float16 lA[128 * 32];
    __shared__ __align__(16) _Float16 lB[128 * 32];
    const int bx = blockIdx.x;
    if (bx < 16)
        gemm_body(dqc, 1536, Wuq, qb16, nullptr, nullptr, nullptr, nullptr,
                  sc, 2, 2048, 1536, bx, lA, lB);
    else
        gemm_body(ckf, 512, Wukv, Kp, Vt, nullptr, nullptr, nullptr,
                  1.f, 3, 1024, 512, bx - 16, lA, lB);
}

// ---------------------------------------------------------------------------
// RoPE Q: qrf fp16 [(b,s)][1024] -> qb16 bf16 [(b,s)][h*192+128+d],
// pre-scaled by 1/sqrt(192).
// ---------------------------------------------------------------------------
__global__ __launch_bounds__(256) void rope_q16(const _Float16* __restrict__ qrf,
                                                const float* __restrict__ cosc,
                                                const float* __restrict__ sinc,
                                                const int* __restrict__ pos,
                                                u16* __restrict__ qb16) {
    const float sc = 0.07216878364870322f;           // 1/sqrt(192)
    int t = blockIdx.x * 256 + threadIdx.x;          // t < 4096*16*32
    int d = t & 31, h = (t >> 5) & 15, rowi = t >> 9;
    int s = rowi & 2047;
    int p = pos[s];
    float c1 = cosc[p * 64 + d],      s1 = sinc[p * 64 + d];
    float c2 = cosc[p * 64 + 32 + d], s2 = sinc[p * 64 + 32 + d];
    const _Float16* base = qrf + (size_t)rowi * 1024 + h * 64;
    float x1 = (float)base[d];
    float x2 = (float)base[d + 32];
    u16* q = qb16 + (size_t)rowi * 3072 + h * 192 + 128;
    q[d]      = f2b((x1 * c1 - x2 * s1) * sc);
    q[d + 32] = f2b((x2 * c2 + x1 * s2) * sc);
}

// RoPE K: krr fp32 [(b,s)][256] -> Krope fp32 (Output 2) + Kp bf16 cols 128..191
__global__ __launch_bounds__(256) void rope_k(const float* __restrict__ krr,
                                              const float* __restrict__ cosc,
                                              const float* __restrict__ sinc,
                                              const int* __restrict__ pos,
                                              float* __restrict__ Krope,
                                              u16* __restrict__ Kp) {
    int t = blockIdx.x * 256 + threadIdx.x;          // t < 4096*4*32
    int d = t & 31, kv = (t >> 5) & 3, rowi = t >> 7;
    int b = rowi >> 11, s = rowi & 2047;
    int p = pos[s];
    float c1 = cosc[p * 64 + d],      s1 = sinc[p * 64 + d];
    float c2 = cosc[p * 64 + 32 + d], s2 = sinc[p * 64 + 32 + d];
    float x1 = krr[(size_t)rowi * 256 + kv * 64 + d];
    float x2 = krr[(size_t)rowi * 256 + kv * 64 + 32 + d];
    float o1 = x1 * c1 - x2 * s1;
    float o2 = x2 * c2 + x1 * s2;
    int g = b * NKV_ + kv;
    size_t ob = ((size_t)(g * S_) + s) * 64;
    Krope[ob + d]      = cl(o1);
    Krope[ob + 32 + d] = cl(o2);
    u16* kp = Kp + ((size_t)(g * S_ + s)) * 192 + 128;
    kp[d]      = f2b(o1);
    kp[32 + d] = f2b(o2);
}

// ---------------------------------------------------------------------------
// MFMA flash attention. Block = 4 waves = 64 q-rows of one (b,h).
// Paired q-tiles: qt = 31-px then px -> 33 kv-tile units per block, uniform.
// Flat grid 512; id decode puts the 64 blocks of each KV group g on one XCD
// (id&7 == g) so K/V (~1.3MB/g) stay in the 4MB XCD L2. [verified r5: FETCH
// 48.8->17.7MB]
// Staging: r5's direct synchronous copy (compiler pipelines the per-chunk
// vmcnt waits). [r6 post-mortem: explicit reg-prefetch split REGRESSED
// 109->186us -- occupancy 20->11%, VGPR 116->132; do not reintroduce.]
// Mask-skip: only the LAST kv-tile per q-tile is diagonal (j0+63 <= iw for all
// earlier tiles) -> mask VALU runs once per q-tile. [verified r6: absmax same]
// Row-sum l via bf16-ones d-row (row 128) in lVt: PV's 9th n-chunk accumulates
// l into O9[8]. Defer-max (T13, THR=8) skips O-rescale when max grows <= 8.
// Q from qb16 bf16 [(b,s)][h*192+k], pre-scaled by 1/sqrt(192).
// Out: atf fp16 [(b,s)][h*128+d].
// Layouts [m89/m91 verified]: A-frag A[m=lane&15][k=quad*8+j];
// B-frag B[n=lane&15][k=quad*8+j]; C/D col=lane&15, row=quad*4+reg.
// ---------------------------------------------------------------------------
__global__ __launch_bounds__(256) void attn_mfma(const u16* __restrict__ qb16,
                                                 const u16* __restrict__ Kp,
                                                 const u16* __restrict__ Vt,
                                                 _Float16* __restrict__ atf) {
    __shared__ __align__(16) u16 lK[64 * 200];     // 64 kv-rows x 192 (+8 pad)
    __shared__ __align__(16) u16 lVt[144 * 72];    // 128 d-rows + 16 (ones) x 64 (+8 pad)
    __shared__ __align__(16) u16 lP[4][16 * 72];   // per-wave P 16x64 (+8 pad)

    const int t = threadIdx.x, lane = t & 63, w = t >> 6;
    const int quad = lane >> 4, l16 = lane & 15;
    // XCD-aligned decode: g = id&7 so all blocks of a KV group share an XCD
    const int id = blockIdx.x;                     // 0..511
    const int g = id & 7;                          // (b*4 + kv)
    const int b = g >> 2;
    const int k = id >> 3;                         // 0..63
    const int h = (g & 3) * 4 + (k & 3);
    const int px = k >> 2;                         // 0..15

    // ones-row init for the l-column trick (rows 128..143, cols 0..63)
#pragma unroll
    for (int c = 0; c < 4; ++c) {
        int i = c * 256 + t;                       // 0..1023
        int rr = 128 + (i >> 6), ccol = i & 63;
        lVt[rr * 72 + ccol] = (rr == 128) ? (u16)0x3F80 : (u16)0;
    }

    for (int ph = 0; ph < 2; ++ph) {
        const int qt = ph ? px : (31 - px);        // heavy tile first
        const int q0 = qt * 64;
        const int iw = q0 + w * 16;                // wave's q-row base

        // Q fragments: rows m=l16, contiguous 192-col row (pre-scaled bf16)
        short8 qf[6];
        {
            const u16* qp = qb16 + ((size_t)(b * S_ + iw + l16)) * 3072 + h * 192;
#pragma unroll
            for (int kc = 0; kc < 6; ++kc)
                qf[kc] = *(const short8*)&qp[kc * 32 + quad * 8];
        }

        f32x4 O9[9] = {};                          // [0..7]=O d-chunks, [8]=l (col l16==0)
        float mr[4] = {-1e30f, -1e30f, -1e30f, -1e30f};

        const int ntile = qt + 1;
        for (int tile = 0; tile < ntile; ++tile) {
            const int j0 = tile * 64;
            __syncthreads();
            // stage K tile: 64 rows x 192 u16 = 1536 x 16B, 6/thread
#pragma unroll
            for (int c = 0; c < 6; ++c) {
                int seg = c * 256 + t;
                int row = seg / 24, ch = (seg % 24) * 8;
                *(uint4*)&lK[row * 200 + ch] =
                    *(const uint4*)&Kp[((size_t)g * S_ + j0 + row) * 192 + ch];
            }
            // stage Vt tile: 128 d-rows x 64 u16 = 1024 x 16B, 4/thread
#pragma unroll
            for (int c = 0; c < 4; ++c) {
                int seg = c * 256 + t;
                int d = seg >> 3, ch = (seg & 7) * 8;
                *(uint4*)&lVt[d * 72 + ch] =
                    *(const uint4*)&Vt[((size_t)g * 128 + d) * S_ + j0 + ch];
            }
            __syncthreads();

            // S = Q K^T, four 16-col chunks
            f32x4 s4[4];
            __builtin_amdgcn_s_setprio(1);
#pragma unroll
            for (int cc = 0; cc < 4; ++cc) {
                f32x4 sx = {};
#pragma unroll
                for (int kc = 0; kc < 6; ++kc) {
                    short8 kf = *(const short8*)&lK[(cc * 16 + l16) * 200 + kc * 32 + quad * 8];
                    sx = __builtin_amdgcn_mfma_f32_16x16x32_bf16(qf[kc], kf, sx, 0, 0, 0);
                }
                s4[cc] = sx;
            }
            __builtin_amdgcn_s_setprio(0);

            // mask only the diagonal tile (provably the last one per q-tile)
            float sv[4][4];
#pragma unroll
            for (int cc = 0; cc < 4; ++cc)
#pragma unroll
                for (int r = 0; r < 4; ++r) sv[cc][r] = s4[cc][r];
            if (tile == ntile - 1) {
#pragma unroll
                for (int cc = 0; cc < 4; ++cc)
#pragma unroll
                    for (int r = 0; r < 4; ++r) {
                        int ir = iw + quad * 4 + r;
                        if (j0 + cc * 16 + l16 > ir) sv[cc][r] = -1e30f;
                    }
            }
            // row max across the 16-lane group
            float tm[4];
#pragma unroll
            for (int r = 0; r < 4; ++r)
                tm[r] = fmaxf(fmaxf(sv[0][r], sv[1][r]), fmaxf(sv[2][r], sv[3][r]));
#pragma unroll
            for (int m = 1; m < 16; m <<= 1)
#pragma unroll
                for (int r = 0; r < 4; ++r) tm[r] = fmaxf(tm[r], __shfl_xor(tm[r], m));
            // defer-max: only rescale when the max grew by > 8
            int small = (tm[0] <= mr[0] + 8.f) && (tm[1] <= mr[1] + 8.f) &&
                        (tm[2] <= mr[2] + 8.f) && (tm[3] <= mr[3] + 8.f);
            if (!__all(small)) {
                float al[4];
#pragma unroll
                for (int r = 0; r < 4; ++r) {
                    float mn = fmaxf(mr[r], tm[r]);
                    al[r] = __expf(mr[r] - mn);
                    mr[r] = mn;
                }
#pragma unroll
                for (int dc = 0; dc < 9; ++dc)
#pragma unroll
                    for (int r = 0; r < 4; ++r) O9[dc][r] *= al[r];
            }
            // P = exp(S - mr)  (bounded by e^8 when deferred)
            float p[4][4];
#pragma unroll
            for (int cc = 0; cc < 4; ++cc)
#pragma unroll
                for (int r = 0; r < 4; ++r)
                    p[cc][r] = __expf(sv[cc][r] - mr[r]);
            // P (C layout) -> LDS -> A-layout frags (k = 0..31, 32..63)
#pragma unroll
            for (int cc = 0; cc < 4; ++cc)
#pragma unroll
                for (int r = 0; r < 4; ++r)
                    lP[w][(quad * 4 + r) * 72 + cc * 16 + l16] = f2b(p[cc][r]);
            short8 pf0 = *(const short8*)&lP[w][l16 * 72 + quad * 8];
            short8 pf1 = *(const short8*)&lP[w][l16 * 72 + 32 + quad * 8];
            // O += P V ; 9th chunk accumulates l via the ones-row
            __builtin_amdgcn_s_setprio(1);
#pragma unroll
            for (int dc = 0; dc < 9; ++dc) {
                short8 vf0 = *(const short8*)&lVt[(dc * 16 + l16) * 72 + quad * 8];
                short8 vf1 = *(const short8*)&lVt[(dc * 16 + l16) * 72 + 32 + quad * 8];
                O9[dc] = __builtin_amdgcn_mfma_f32_16x16x32_bf16(pf0, vf0, O9[dc], 0, 0, 0);
                O9[dc] = __builtin_amdgcn_mfma_f32_16x16x32_bf16(pf1, vf1, O9[dc], 0, 0, 0);
            }
            __builtin_amdgcn_s_setprio(0);
        }
        // epilogue: l lives in O9[8] at col l16==0; broadcast within quad
        float inv[4];
#pragma unroll
        for (int r = 0; r < 4; ++r) {
            float lr = __shfl(O9[8][r], quad * 16);
            inv[r] = 1.f / fmaxf(lr, 1e-30f);
        }
#pragma unroll
        for (int dc = 0; dc < 8; ++dc)
#pragma unroll
            for (int r = 0; r < 4; ++r) {
                int ir = iw + quad * 4 + r;
                atf[((size_t)(b * S_ + ir)) * 2048 + h * 128 + dc * 16 + l16] =
                    (_Float16)cl(O9[dc][r] * inv[r]);
            }
    }
}

// ---------------------------------------------------------------------------
extern "C" void kernel_launch(void* const* d_in, const int* in_sizes, int n_in,
                              void* d_out, int out_size, void* d_ws, size_t ws_size,
                              hipStream_t stream) {
    const float* x     = (const float*)d_in[0];
    const float* cosc  = (const float*)d_in[1];
    const float* sinc  = (const float*)d_in[2];
    const int*   pos   = (const int*)d_in[3];
    // d_in[4] = attn_mask (causal tril) -- implemented analytically
    const float* W_DKV = (const float*)d_in[5];
    const float* W_UK  = (const float*)d_in[6];
    const float* W_UV  = (const float*)d_in[7];
    const float* W_DQ  = (const float*)d_in[8];
    const float* W_UQ  = (const float*)d_in[9];
    const float* W_KR  = (const float*)d_in[10];
    const float* W_QR  = (const float*)d_in[11];
    const float* W_O   = (const float*)d_in[12];
    (void)ws_size;

    float* outp      = (float*)d_out;            // [B,S,2048]
    float* ckv_out   = outp + 8388608;           // [B,S,512]
    float* krope_out = outp + 10485760;          // [B,NKV,S,64]

    // ---- workspace (~128 MB) ----
    char* w = (char*)d_ws;
    auto alloc = [&](size_t bytes) { char* p = w; w += bytes; return p; };
    _Float16* xf   = (_Float16*)alloc(16777216);  // x fp16 [4096][2048]
    _Float16* ckf  = (_Float16*)alloc(4194304);   // c_kv fp16 [4096][512]
    float*    krr  = (float*)alloc(4194304);      // K-rope raw fp32 [4096][256]
    _Float16* dqc  = (_Float16*)alloc(12582912);  // c_q fp16 [4096][1536]
    _Float16* qrf  = (_Float16*)alloc(8388608);   // q_rope_raw fp16 [4096][1024]
    u16*      qb16 = (u16*)alloc(25165824);       // Q bf16 pre-scaled [4096][16][192]
    u16*      Kp   = (u16*)alloc(6291456);        // [8][2048][192] bf16
    u16*      Vt   = (u16*)alloc(4194304);        // [8][128][2048] bf16
    _Float16* atf  = (_Float16*)alloc(16777216);  // attn out fp16 [4096][2048]
    _Float16* Wmeg = (_Float16*)alloc(13631488);  // [3328][2048] (DKV|KR|DQ|QR)
    _Float16* Wuq  = (_Float16*)alloc(6291456);   // [2048][1536]
    _Float16* Wukv = (_Float16*)alloc(1048576);   // [1024][512]  (UK|UV)
    _Float16* Wo   = (_Float16*)alloc(8388608);   // [2048][2048]

    const float sc = 0.07216878364870322f;        // 1/sqrt(192)
    const dim3 tb(32, 8);

    // input / weight prep (fp16)
    x_f16<<<4096, 256, 0, stream>>>(x, xf);
    wt_f16<<<dim3(64, 16), tb, 0, stream>>>(W_DKV, Wmeg, 2048, 512);
    wt_f16<<<dim3(64, 8),  tb, 0, stream>>>(W_KR,  Wmeg + (size_t)512 * 2048, 2048, 256);
    wt_f16<<<dim3(64, 48), tb, 0, stream>>>(W_DQ,  Wmeg + (size_t)768 * 2048, 2048, 1536);
    wt_f16<<<dim3(64, 32), tb, 0, stream>>>(W_QR,  Wmeg + (size_t)2304 * 2048, 2048, 1024);
    wt_f16<<<dim3(48, 64), tb, 0, stream>>>(W_UQ,  Wuq, 1536, 2048);
    wt_f16<<<dim3(16, 16), tb, 0, stream>>>(W_UK,  Wukv, 512, 512);
    wt_f16<<<dim3(16, 16), tb, 0, stream>>>(W_UV,  Wukv + (size_t)512 * 512, 512, 512);
    wt_f16<<<dim3(64, 64), tb, 0, stream>>>(W_O,   Wo, 2048, 2048);

    // mega projection: c_kv (Output 1) | ckf | K-rope-raw | c_q | q-rope-raw
    gemm_f16<<<dim3(26, 32), 256, 0, stream>>>(xf, 2048, Wmeg,
                                               ckv_out, ckf, krr, dqc, qrf,
                                               1.f, 6, 3328, 2048);
    // Q content (mode 2) + K content | V pack (mode 3), heterogeneous dispatch
    gemm_uqkv<<<dim3(24, 32), 256, 0, stream>>>(dqc, Wuq, qb16, sc,
                                                ckf, Wukv, Kp, Vt);

    // rope: Q -> qb16 cols 128..191; K -> Output 2 + Kp cols 128..191
    rope_q16<<<8192, 256, 0, stream>>>(qrf, cosc, sinc, pos, qb16);
    rope_k<<<2048, 256, 0, stream>>>(krr, cosc, sinc, pos, krope_out, Kp);

    // attention + output projection
    attn_mfma<<<512, 256, 0, stream>>>(qb16, Kp, Vt, atf);
    gemm_f16<<<dim3(16, 32), 256, 0, stream>>>(atf, 2048, Wo,
                                               outp, nullptr, nullptr, nullptr, nullptr,
                                               1.f, 0, 2048, 2048);
}

// Round 8
// 541.054 us; speedup vs baseline: 1.0349x; 1.0155x over previous
//
#include <hip/hip_runtime.h>
#include <stdint.h>

typedef unsigned short u16;
typedef unsigned int u32;

// Problem constants
#define B_    2
#define S_    2048
#define NQ_   16
#define NKV_  4
#define DH_   128
#define DR_   64
#define DT_   192
#define M_    4096   // B_*S_

using short8 = __attribute__((ext_vector_type(8))) short;
using f32x4  = __attribute__((ext_vector_type(4))) float;
using half8  = __attribute__((ext_vector_type(8))) _Float16;
using u16x4  = __attribute__((ext_vector_type(4))) u16;

__device__ __forceinline__ float cl(float f) {   // clamp diagnostic: inf/NaN -> +-3.38e38 signature
    return fminf(fmaxf(f, -3.38e38f), 3.38e38f);
}
__device__ __forceinline__ u16 f2b(float f) {    // fp32 -> bf16 RNE
    union { float f; u32 u; } v; v.f = f;
    u32 u = v.u;
    return (u16)((u + 0x7fffu + ((u >> 16) & 1u)) >> 16);
}
// async global->LDS, 16B per lane. LDS dest is wave-uniform base + lane*16.
__device__ __forceinline__ void gload16(const void* g, void* l) {
    __builtin_amdgcn_global_load_lds(
        (const __attribute__((address_space(1))) void*)g,
        (__attribute__((address_space(3))) void*)l,
        16, 0, 0);
}

// ---------------------------------------------------------------------------
// x_f16: x fp32 -> fp16
// ---------------------------------------------------------------------------
__global__ __launch_bounds__(256) void x_f16(const float* __restrict__ X,
                                             _Float16* __restrict__ F) {
    size_t i = ((size_t)blockIdx.x * 256 + threadIdx.x) * 8;
    float4 a = *(const float4*)(X + i);
    float4 b4 = *(const float4*)(X + i + 4);
    float va[8] = {a.x, a.y, a.z, a.w, b4.x, b4.y, b4.z, b4.w};
    half8 f;
#pragma unroll
    for (int j = 0; j < 8; ++j) f[j] = (_Float16)va[j];
    *(half8*)(F + i) = f;
}

// ---------------------------------------------------------------------------
// Weight transpose to fp16: W[K][N] fp32 -> T [N][K] fp16.
// block (32,8), grid (K/32, N/32)
// ---------------------------------------------------------------------------
__global__ __launch_bounds__(256) void wt_f16(const float* __restrict__ W,
                                              _Float16* __restrict__ T,
                                              int K, int N) {
    __shared__ float tile[32][33];
    int k0 = blockIdx.x * 32, n0 = blockIdx.y * 32;
    int tx = threadIdx.x, ty = threadIdx.y;
#pragma unroll
    for (int i = 0; i < 32; i += 8)
        tile[ty + i][tx] = W[(size_t)(k0 + ty + i) * N + n0 + tx];
    __syncthreads();
#pragma unroll
    for (int i = 0; i < 32; i += 8)
        T[(size_t)(n0 + ty + i) * K + k0 + tx] = (_Float16)tile[tx][ty + i];
}

// ---------------------------------------------------------------------------
// fp16 single-pass MFMA GEMM body. C = A[M][lda] @ Bt[N][K]^T, fp32 accum.
// Tile 128x128, BK=32, 4 waves (2x2), global_load_lds staging. [verified r3-r7]
// Epilogue modes:
//  0: p0 = fp32 C [stride N], clamped
//  2: p0 = qb16 bf16 [m][h*192 + (n&127)], scaled by cscale (Q content)
//  3: p0 = Kp bf16 [g][s][192] cols 0..127 (n<512);
//     p1 = Vt bf16 [g][d][2048]            (n>=512)   -- fused K/V pack
//  6: mega projection split:
//     nn<512 : p0=ckv fp32 [m][512] (cl) + p1=ckf fp16 [m][512]
//     nn<768 : p2=krr fp32 [m][256]
//     nn<2304: p3=dqc fp16 [m][1536]
//     else   : p4=qrf fp16 [m][1024]
// Layouts [m89/m91 verified]: A-frag A[m=lane&15][k=quad*8+j];
// B-frag B[n=lane&15][k=quad*8+j]; C/D col=lane&15, row=quad*4+reg.
// ---------------------------------------------------------------------------
__device__ __forceinline__ void gemm_body(const _Float16* __restrict__ A, int lda,
                                          const _Float16* __restrict__ Bt,
                                          void* p0, void* p1, void* p2,
                                          void* p3, void* p4,
                                          float cscale, int mode,
                                          int N, int K, int bx,
                                          _Float16* lA, _Float16* lB) {
    const int t = threadIdx.x, lane = t & 63, w = t >> 6;
    const int quad = lane >> 4, l16 = lane & 15;
    const int wr = w >> 1, wc = w & 1;
    const int m0 = blockIdx.y * 128, n0 = bx * 128;
    f32x4 acc[4][4] = {};

    for (int kt = 0; kt < K; kt += 32) {
        __syncthreads();
#pragma unroll
        for (int c = 0; c < 2; ++c) {
            const int chunk = c * 256 + t;
            const int row = chunk >> 2, co = (chunk & 3) * 8;
            const int lofs = (c * 256 + w * 64) * 8;   // fp16 units, wave-uniform
            gload16(A + (size_t)(m0 + row) * lda + kt + co, lA + lofs);
            gload16(Bt + (size_t)(n0 + row) * K + kt + co, lB + lofs);
        }
        __syncthreads();
        half8 af[4], bf4[4];
#pragma unroll
        for (int i = 0; i < 4; ++i) {
            af[i]  = *(const half8*)&lA[(wr * 64 + i * 16 + l16) * 32 + quad * 8];
            bf4[i] = *(const half8*)&lB[(wc * 64 + i * 16 + l16) * 32 + quad * 8];
        }
#pragma unroll
        for (int i = 0; i < 4; ++i)
#pragma unroll
            for (int j = 0; j < 4; ++j)
                acc[i][j] = __builtin_amdgcn_mfma_f32_16x16x32_f16(af[i], bf4[j], acc[i][j], 0, 0, 0);
    }
#pragma unroll
    for (int i = 0; i < 4; ++i)
#pragma unroll
        for (int j = 0; j < 4; ++j) {
            const int mbase = m0 + wr * 64 + i * 16 + quad * 4;
            const int nn = n0 + wc * 64 + j * 16 + l16;
            if (mode == 0) {
                float* C = (float*)p0;
#pragma unroll
                for (int r = 0; r < 4; ++r)
                    C[(size_t)(mbase + r) * N + nn] = cl(acc[i][j][r]);
            } else if (mode == 2) {
                u16* Q = (u16*)p0;
                const int h = nn >> 7, dcol = nn & 127;
#pragma unroll
                for (int r = 0; r < 4; ++r)
                    Q[(size_t)(mbase + r) * 3072 + h * 192 + dcol] =
                        f2b(acc[i][j][r] * cscale);
            } else if (mode == 3) {
                const int bb = mbase >> 11, s = mbase & 2047;
                if (nn < 512) {
                    u16* Kp = (u16*)p0;
                    const int kv = nn >> 7, d = nn & 127;
                    const size_t rb = ((size_t)((bb * 4 + kv) * 2048 + s)) * 192 + d;
#pragma unroll
                    for (int r = 0; r < 4; ++r)
                        Kp[rb + (size_t)r * 192] = f2b(acc[i][j][r]);
                } else {
                    u16* Vt = (u16*)p1;
                    const int e = nn - 512, kv = e >> 7, d = e & 127;
                    u16x4 pk;
                    pk[0] = f2b(acc[i][j][0]); pk[1] = f2b(acc[i][j][1]);
                    pk[2] = f2b(acc[i][j][2]); pk[3] = f2b(acc[i][j][3]);
                    *(u16x4*)&((u16*)Vt)[((size_t)((bb * 4 + kv) * 128 + d)) * 2048 + s] = pk;
                }
            } else {   // mode 6: mega projection split
                if (nn < 512) {
                    float* ckv = (float*)p0;
                    _Float16* ckf = (_Float16*)p1;
#pragma unroll
                    for (int r = 0; r < 4; ++r) {
                        float v = acc[i][j][r];
                        ckv[(size_t)(mbase + r) * 512 + nn] = cl(v);
                        ckf[(size_t)(mbase + r) * 512 + nn] = (_Float16)v;
                    }
                } else if (nn < 768) {
                    float* krr = (float*)p2;
#pragma unroll
                    for (int r = 0; r < 4; ++r)
                        krr[(size_t)(mbase + r) * 256 + (nn - 512)] = acc[i][j][r];
                } else if (nn < 2304) {
                    _Float16* dqc = (_Float16*)p3;
#pragma unroll
                    for (int r = 0; r < 4; ++r)
                        dqc[(size_t)(mbase + r) * 1536 + (nn - 768)] = (_Float16)acc[i][j][r];
                } else {
                    _Float16* qrf = (_Float16*)p4;
#pragma unroll
                    for (int r = 0; r < 4; ++r)
                        qrf[(size_t)(mbase + r) * 1024 + (nn - 2304)] = (_Float16)acc[i][j][r];
                }
            }
        }
}

__global__ __launch_bounds__(256) void gemm_f16(const _Float16* __restrict__ A, int lda,
                                                const _Float16* __restrict__ Bt,
                                                void* p0, void* p1, void* p2,
                                                void* p3, void* p4,
                                                float cscale, int mode,
                                                int N, int K) {
    __shared__ __align__(16) _Float16 lA[128 * 32];
    __shared__ __align__(16) _Float16 lB[128 * 32];
    gemm_body(A, lda, Bt, p0, p1, p2, p3, p4, cscale, mode, N, K, blockIdx.x, lA, lB);
}

// Heterogeneous dispatch: blocks x<16 -> UQ (Q content, mode 2);
// x>=16 -> UKV (K content | V pack, mode 3). 768 blocks = 3/CU.
__global__ __launch_bounds__(256) void gemm_uqkv(const _Float16* __restrict__ dqc,
                                                 const _Float16* __restrict__ Wuq,
                                                 u16* __restrict__ qb16, float sc,
                                                 const _Float16* __restrict__ ckf,
                                                 const _Float16* __restrict__ Wukv,
                                                 u16* __restrict__ Kp,
                                                 u16* __restrict__ Vt) {
    __shared__ __align__(16) _Float16 lA[128 * 32];
    __shared__ __align__(16) _Float16 lB[128 * 32];
    const int bx = blockIdx.x;
    if (bx < 16)
        gemm_body(dqc, 1536, Wuq, qb16, nullptr, nullptr, nullptr, nullptr,
                  sc, 2, 2048, 1536, bx, lA, lB);
    else
        gemm_body(ckf, 512, Wukv, Kp, Vt, nullptr, nullptr, nullptr,
                  1.f, 3, 1024, 512, bx - 16, lA, lB);
}

// ---------------------------------------------------------------------------
// Merged RoPE (one launch). Blocks 0..8191: Q rope -- qrf fp16 [(b,s)][1024]
// -> qb16 bf16 [(b,s)][h*192+128+d], pre-scaled by 1/sqrt(192).
// Blocks 8192..10239: K rope -- krr fp32 [(b,s)][256] -> Krope fp32 (Output 2)
// + Kp bf16 cols 128..191. Math byte-identical to the split kernels [r3-r7].
// ---------------------------------------------------------------------------
__global__ __launch_bounds__(256) void rope_all(const _Float16* __restrict__ qrf,
                                                const float* __restrict__ krr,
                                                const float* __restrict__ cosc,
                                                const float* __restrict__ sinc,
                                                const int* __restrict__ pos,
                                                u16* __restrict__ qb16,
                                                float* __restrict__ Krope,
                                                u16* __restrict__ Kp) {
    const float sc = 0.07216878364870322f;           // 1/sqrt(192)
    if ((int)blockIdx.x < 8192) {
        int t = blockIdx.x * 256 + threadIdx.x;      // t < 4096*16*32
        int d = t & 31, h = (t >> 5) & 15, rowi = t >> 9;
        int s = rowi & 2047;
        int p = pos[s];
        float c1 = cosc[p * 64 + d],      s1 = sinc[p * 64 + d];
        float c2 = cosc[p * 64 + 32 + d], s2 = sinc[p * 64 + 32 + d];
        const _Float16* base = qrf + (size_t)rowi * 1024 + h * 64;
        float x1 = (float)base[d];
        float x2 = (float)base[d + 32];
        u16* q = qb16 + (size_t)rowi * 3072 + h * 192 + 128;
        q[d]      = f2b((x1 * c1 - x2 * s1) * sc);
        q[d + 32] = f2b((x2 * c2 + x1 * s2) * sc);
    } else {
        int t = (blockIdx.x - 8192) * 256 + threadIdx.x;   // t < 4096*4*32
        int d = t & 31, kv = (t >> 5) & 3, rowi = t >> 7;
        int b = rowi >> 11, s = rowi & 2047;
        int p = pos[s];
        float c1 = cosc[p * 64 + d],      s1 = sinc[p * 64 + d];
        float c2 = cosc[p * 64 + 32 + d], s2 = sinc[p * 64 + 32 + d];
        float x1 = krr[(size_t)rowi * 256 + kv * 64 + d];
        float x2 = krr[(size_t)rowi * 256 + kv * 64 + 32 + d];
        float o1 = x1 * c1 - x2 * s1;
        float o2 = x2 * c2 + x1 * s2;
        int g = b * NKV_ + kv;
        size_t ob = ((size_t)(g * S_) + s) * 64;
        Krope[ob + d]      = cl(o1);
        Krope[ob + 32 + d] = cl(o2);
        u16* kp = Kp + ((size_t)(g * S_ + s)) * 192 + 128;
        kp[d]      = f2b(o1);
        kp[32 + d] = f2b(o2);
    }
}

// ---------------------------------------------------------------------------
// MFMA flash attention. Block = 4 waves = 64 q-rows of one (b,h).
// Paired q-tiles: qt = 31-px then px -> 33 kv-tile units per block, uniform.
// Flat grid 512; id decode puts the 64 blocks of each KV group g on one XCD
// (id&7 == g) so K/V (~1.3MB/g) stay in the 4MB XCD L2. [verified r5: FETCH
// 48.8->17.7MB]
// Staging: direct synchronous copy (compiler pipelines the per-chunk vmcnt).
// [r6 post-mortem: explicit reg-prefetch split REGRESSED 109->186us.]
// REGISTER CLIFF [r7 post-mortem]: sv[4][4]+p[4][4] copies pushed VGPR
// 116->132, over the 128 boundary (m69) -> occupancy halved, 158us. Fix:
// mask AND exp IN PLACE on s4 -- no extra arrays. Keep VGPR <= 128.
// Mask-skip: only the LAST kv-tile per q-tile is diagonal.
// Row-sum l via bf16-ones d-row (row 128) in lVt: PV's 9th n-chunk
// accumulates l into O9[8]. Defer-max (T13, THR=8).
// Q from qb16 bf16 [(b,s)][h*192+k], pre-scaled by 1/sqrt(192).
// Out: atf fp16 [(b,s)][h*128+d].
// Layouts [m89/m91 verified]: A-frag A[m=lane&15][k=quad*8+j];
// B-frag B[n=lane&15][k=quad*8+j]; C/D col=lane&15, row=quad*4+reg.
// ---------------------------------------------------------------------------
__global__ __launch_bounds__(256) void attn_mfma(const u16* __restrict__ qb16,
                                                 const u16* __restrict__ Kp,
                                                 const u16* __restrict__ Vt,
                                                 _Float16* __restrict__ atf) {
    __shared__ __align__(16) u16 lK[64 * 200];     // 64 kv-rows x 192 (+8 pad)
    __shared__ __align__(16) u16 lVt[144 * 72];    // 128 d-rows + 16 (ones) x 64 (+8 pad)
    __shared__ __align__(16) u16 lP[4][16 * 72];   // per-wave P 16x64 (+8 pad)

    const int t = threadIdx.x, lane = t & 63, w = t >> 6;
    const int quad = lane >> 4, l16 = lane & 15;
    // XCD-aligned decode: g = id&7 so all blocks of a KV group share an XCD
    const int id = blockIdx.x;                     // 0..511
    const int g = id & 7;                          // (b*4 + kv)
    const int b = g >> 2;
    const int k = id >> 3;                         // 0..63
    const int h = (g & 3) * 4 + (k & 3);
    const int px = k >> 2;                         // 0..15

    // ones-row init for the l-column trick (rows 128..143, cols 0..63)
#pragma unroll
    for (int c = 0; c < 4; ++c) {
        int i = c * 256 + t;                       // 0..1023
        int rr = 128 + (i >> 6), ccol = i & 63;
        lVt[rr * 72 + ccol] = (rr == 128) ? (u16)0x3F80 : (u16)0;
    }

    for (int ph = 0; ph < 2; ++ph) {
        const int qt = ph ? px : (31 - px);        // heavy tile first
        const int q0 = qt * 64;
        const int iw = q0 + w * 16;                // wave's q-row base

        // Q fragments: rows m=l16, contiguous 192-col row (pre-scaled bf16)
        short8 qf[6];
        {
            const u16* qp = qb16 + ((size_t)(b * S_ + iw + l16)) * 3072 + h * 192;
#pragma unroll
            for (int kc = 0; kc < 6; ++kc)
                qf[kc] = *(const short8*)&qp[kc * 32 + quad * 8];
        }

        f32x4 O9[9] = {};                          // [0..7]=O d-chunks, [8]=l (col l16==0)
        float mr[4] = {-1e30f, -1e30f, -1e30f, -1e30f};

        const int ntile = qt + 1;
        for (int tile = 0; tile < ntile; ++tile) {
            const int j0 = tile * 64;
            __syncthreads();
            // stage K tile: 64 rows x 192 u16 = 1536 x 16B, 6/thread
#pragma unroll
            for (int c = 0; c < 6; ++c) {
                int seg = c * 256 + t;
                int row = seg / 24, ch = (seg % 24) * 8;
                *(uint4*)&lK[row * 200 + ch] =
                    *(const uint4*)&Kp[((size_t)g * S_ + j0 + row) * 192 + ch];
            }
            // stage Vt tile: 128 d-rows x 64 u16 = 1024 x 16B, 4/thread
#pragma unroll
            for (int c = 0; c < 4; ++c) {
                int seg = c * 256 + t;
                int d = seg >> 3, ch = (seg & 7) * 8;
                *(uint4*)&lVt[d * 72 + ch] =
                    *(const uint4*)&Vt[((size_t)g * 128 + d) * S_ + j0 + ch];
            }
            __syncthreads();

            // S = Q K^T, four 16-col chunks
            f32x4 s4[4];
            __builtin_amdgcn_s_setprio(1);
#pragma unroll
            for (int cc = 0; cc < 4; ++cc) {
                f32x4 sx = {};
#pragma unroll
                for (int kc = 0; kc < 6; ++kc) {
                    short8 kf = *(const short8*)&lK[(cc * 16 + l16) * 200 + kc * 32 + quad * 8];
                    sx = __builtin_amdgcn_mfma_f32_16x16x32_bf16(qf[kc], kf, sx, 0, 0, 0);
                }
                s4[cc] = sx;
            }
            __builtin_amdgcn_s_setprio(0);

            // mask IN PLACE, only the diagonal tile (provably the last one)
            if (tile == ntile - 1) {
#pragma unroll
                for (int cc = 0; cc < 4; ++cc)
#pragma unroll
                    for (int r = 0; r < 4; ++r) {
                        int ir = iw + quad * 4 + r;
                        if (j0 + cc * 16 + l16 > ir) s4[cc][r] = -1e30f;
                    }
            }
            // row max across the 16-lane group
            float tm[4];
#pragma unroll
            for (int r = 0; r < 4; ++r)
                tm[r] = fmaxf(fmaxf(s4[0][r], s4[1][r]), fmaxf(s4[2][r], s4[3][r]));
#pragma unroll
            for (int m = 1; m < 16; m <<= 1)
#pragma unroll
                for (int r = 0; r < 4; ++r) tm[r] = fmaxf(tm[r], __shfl_xor(tm[r], m));
            // defer-max: only rescale when the max grew by > 8
            int small = (tm[0] <= mr[0] + 8.f) && (tm[1] <= mr[1] + 8.f) &&
                        (tm[2] <= mr[2] + 8.f) && (tm[3] <= mr[3] + 8.f);
            if (!__all(small)) {
                float al[4];
#pragma unroll
                for (int r = 0; r < 4; ++r) {
                    float mn = fmaxf(mr[r], tm[r]);
                    al[r] = __expf(mr[r] - mn);
                    mr[r] = mn;
                }
#pragma unroll
                for (int dc = 0; dc < 9; ++dc)
#pragma unroll
                    for (int r = 0; r < 4; ++r) O9[dc][r] *= al[r];
            }
            // P = exp(S - mr) IN PLACE (bounded by e^8 when deferred)
#pragma unroll
            for (int cc = 0; cc < 4; ++cc)
#pragma unroll
                for (int r = 0; r < 4; ++r)
                    s4[cc][r] = __expf(s4[cc][r] - mr[r]);
            // P (C layout) -> LDS -> A-layout frags (k = 0..31, 32..63)
#pragma unroll
            for (int cc = 0; cc < 4; ++cc)
#pragma unroll
                for (int r = 0; r < 4; ++r)
                    lP[w][(quad * 4 + r) * 72 + cc * 16 + l16] = f2b(s4[cc][r]);
            short8 pf0 = *(const short8*)&lP[w][l16 * 72 + quad * 8];
            short8 pf1 = *(const short8*)&lP[w][l16 * 72 + 32 + quad * 8];
            // O += P V ; 9th chunk accumulates l via the ones-row
            __builtin_amdgcn_s_setprio(1);
#pragma unroll
            for (int dc = 0; dc < 9; ++dc) {
                short8 vf0 = *(const short8*)&lVt[(dc * 16 + l16) * 72 + quad * 8];
                short8 vf1 = *(const short8*)&lVt[(dc * 16 + l16) * 72 + 32 + quad * 8];
                O9[dc] = __builtin_amdgcn_mfma_f32_16x16x32_bf16(pf0, vf0, O9[dc], 0, 0, 0);
                O9[dc] = __builtin_amdgcn_mfma_f32_16x16x32_bf16(pf1, vf1, O9[dc], 0, 0, 0);
            }
            __builtin_amdgcn_s_setprio(0);
        }
        // epilogue: l lives in O9[8] at col l16==0; broadcast within quad
        float inv[4];
#pragma unroll
        for (int r = 0; r < 4; ++r) {
            float lr = __shfl(O9[8][r], quad * 16);
            inv[r] = 1.f / fmaxf(lr, 1e-30f);
        }
#pragma unroll
        for (int dc = 0; dc < 8; ++dc)
#pragma unroll
            for (int r = 0; r < 4; ++r) {
                int ir = iw + quad * 4 + r;
                atf[((size_t)(b * S_ + ir)) * 2048 + h * 128 + dc * 16 + l16] =
                    (_Float16)cl(O9[dc][r] * inv[r]);
            }
    }
}

// ---------------------------------------------------------------------------
extern "C" void kernel_launch(void* const* d_in, const int* in_sizes, int n_in,
                              void* d_out, int out_size, void* d_ws, size_t ws_size,
                              hipStream_t stream) {
    const float* x     = (const float*)d_in[0];
    const float* cosc  = (const float*)d_in[1];
    const float* sinc  = (const float*)d_in[2];
    const int*   pos   = (const int*)d_in[3];
    // d_in[4] = attn_mask (causal tril) -- implemented analytically
    const float* W_DKV = (const float*)d_in[5];
    const float* W_UK  = (const float*)d_in[6];
    const float* W_UV  = (const float*)d_in[7];
    const float* W_DQ  = (const float*)d_in[8];
    const float* W_UQ  = (const float*)d_in[9];
    const float* W_KR  = (const float*)d_in[10];
    const float* W_QR  = (const float*)d_in[11];
    const float* W_O   = (const float*)d_in[12];
    (void)ws_size;

    float* outp      = (float*)d_out;            // [B,S,2048]
    float* ckv_out   = outp + 8388608;           // [B,S,512]
    float* krope_out = outp + 10485760;          // [B,NKV,S,64]

    // ---- workspace (~128 MB) ----
    char* w = (char*)d_ws;
    auto alloc = [&](size_t bytes) { char* p = w; w += bytes; return p; };
    _Float16* xf   = (_Float16*)alloc(16777216);  // x fp16 [4096][2048]
    _Float16* ckf  = (_Float16*)alloc(4194304);   // c_kv fp16 [4096][512]
    float*    krr  = (float*)alloc(4194304);      // K-rope raw fp32 [4096][256]
    _Float16* dqc  = (_Float16*)alloc(12582912);  // c_q fp16 [4096][1536]
    _Float16* qrf  = (_Float16*)alloc(8388608);   // q_rope_raw fp16 [4096][1024]
    u16*      qb16 = (u16*)alloc(25165824);       // Q bf16 pre-scaled [4096][16][192]
    u16*      Kp   = (u16*)alloc(6291456);        // [8][2048][192] bf16
    u16*      Vt   = (u16*)alloc(4194304);        // [8][128][2048] bf16
    _Float16* atf  = (_Float16*)alloc(16777216);  // attn out fp16 [4096][2048]
    _Float16* Wmeg = (_Float16*)alloc(13631488);  // [3328][2048] (DKV|KR|DQ|QR)
    _Float16* Wuq  = (_Float16*)alloc(6291456);   // [2048][1536]
    _Float16* Wukv = (_Float16*)alloc(1048576);   // [1024][512]  (UK|UV)
    _Float16* Wo   = (_Float16*)alloc(8388608);   // [2048][2048]

    const float sc = 0.07216878364870322f;        // 1/sqrt(192)
    const dim3 tb(32, 8);

    // input / weight prep (fp16)
    x_f16<<<4096, 256, 0, stream>>>(x, xf);
    wt_f16<<<dim3(64, 16), tb, 0, stream>>>(W_DKV, Wmeg, 2048, 512);
    wt_f16<<<dim3(64, 8),  tb, 0, stream>>>(W_KR,  Wmeg + (size_t)512 * 2048, 2048, 256);
    wt_f16<<<dim3(64, 48), tb, 0, stream>>>(W_DQ,  Wmeg + (size_t)768 * 2048, 2048, 1536);
    wt_f16<<<dim3(64, 32), tb, 0, stream>>>(W_QR,  Wmeg + (size_t)2304 * 2048, 2048, 1024);
    wt_f16<<<dim3(48, 64), tb, 0, stream>>>(W_UQ,  Wuq, 1536, 2048);
    wt_f16<<<dim3(16, 16), tb, 0, stream>>>(W_UK,  Wukv, 512, 512);
    wt_f16<<<dim3(16, 16), tb, 0, stream>>>(W_UV,  Wukv + (size_t)512 * 512, 512, 512);
    wt_f16<<<dim3(64, 64), tb, 0, stream>>>(W_O,   Wo, 2048, 2048);

    // mega projection: c_kv (Output 1) | ckf | K-rope-raw | c_q | q-rope-raw
    gemm_f16<<<dim3(26, 32), 256, 0, stream>>>(xf, 2048, Wmeg,
                                               ckv_out, ckf, krr, dqc, qrf,
                                               1.f, 6, 3328, 2048);
    // Q content (mode 2) + K content | V pack (mode 3), heterogeneous dispatch
    gemm_uqkv<<<dim3(24, 32), 256, 0, stream>>>(dqc, Wuq, qb16, sc,
                                                ckf, Wukv, Kp, Vt);

    // rope (merged): Q -> qb16 cols 128..191; K -> Output 2 + Kp cols 128..191
    rope_all<<<10240, 256, 0, stream>>>(qrf, krr, cosc, sinc, pos,
                                        qb16, krope_out, Kp);

    // attention + output projection
    attn_mfma<<<512, 256, 0, stream>>>(qb16, Kp, Vt, atf);
    gemm_f16<<<dim3(16, 32), 256, 0, stream>>>(atf, 2048, Wo,
                                               outp, nullptr, nullptr, nullptr, nullptr,
                                               1.f, 0, 2048, 2048);
}

// Round 9
// 530.556 us; speedup vs baseline: 1.0554x; 1.0198x over previous
//
#include <hip/hip_runtime.h>
#include <stdint.h>

typedef unsigned short u16;
typedef unsigned int u32;

// Problem constants
#define B_    2
#define S_    2048
#define NQ_   16
#define NKV_  4
#define DH_   128
#define DR_   64
#define DT_   192
#define M_    4096   // B_*S_

using short8 = __attribute__((ext_vector_type(8))) short;
using f32x4  = __attribute__((ext_vector_type(4))) float;
using half8  = __attribute__((ext_vector_type(8))) _Float16;
using u16x4  = __attribute__((ext_vector_type(4))) u16;

__device__ __forceinline__ float cl(float f) {   // clamp diagnostic: inf/NaN -> +-3.38e38 signature
    return fminf(fmaxf(f, -3.38e38f), 3.38e38f);
}
__device__ __forceinline__ u16 f2b(float f) {    // fp32 -> bf16 RNE
    union { float f; u32 u; } v; v.f = f;
    u32 u = v.u;
    return (u16)((u + 0x7fffu + ((u >> 16) & 1u)) >> 16);
}
// async global->LDS, 16B per lane. LDS dest is wave-uniform base + lane*16.
__device__ __forceinline__ void gload16(const void* g, void* l) {
    __builtin_amdgcn_global_load_lds(
        (const __attribute__((address_space(1))) void*)g,
        (__attribute__((address_space(3))) void*)l,
        16, 0, 0);
}

// ---------------------------------------------------------------------------
// prep_all: ONE launch for all weight transposes + x->fp16.
// block (32,8); flat-id range decode (all shapes compile-time):
//   [0,1024)      W_DKV -> Wmeg[0]          K=2048 N=512
//   [1024,1536)   W_KR  -> Wmeg[512*2048]   K=2048 N=256
//   [1536,4608)   W_DQ  -> Wmeg[768*2048]   K=2048 N=1536
//   [4608,6656)   W_QR  -> Wmeg[2304*2048]  K=2048 N=1024
//   [6656,9728)   W_UQ  -> Wuq              K=1536 N=2048
//   [9728,9984)   W_UK  -> Wukv             K=512  N=512
//   [9984,10240)  W_UV  -> Wukv[512*512]    K=512  N=512
//   [10240,14336) W_O   -> Wo               K=2048 N=2048
//   [14336,18432) x fp32 -> xf fp16 (1-D, 8 elems/thread)
// Math byte-identical to the split wt_f16/x_f16 kernels [r3-r8].
// ---------------------------------------------------------------------------
__device__ __forceinline__ void wt_body(const float* __restrict__ W,
                                        _Float16* __restrict__ T,
                                        int K, int N, int kx, int ny,
                                        float (*tile)[33]) {
    int k0 = kx * 32, n0 = ny * 32;
    int tx = threadIdx.x, ty = threadIdx.y;
#pragma unroll
    for (int i = 0; i < 32; i += 8)
        tile[ty + i][tx] = W[(size_t)(k0 + ty + i) * N + n0 + tx];
    __syncthreads();
#pragma unroll
    for (int i = 0; i < 32; i += 8)
        T[(size_t)(n0 + ty + i) * K + k0 + tx] = (_Float16)tile[tx][ty + i];
}

__global__ __launch_bounds__(256) void prep_all(const float* __restrict__ x,
                                                _Float16* __restrict__ xf,
                                                const float* __restrict__ W_DKV,
                                                const float* __restrict__ W_KR,
                                                const float* __restrict__ W_DQ,
                                                const float* __restrict__ W_QR,
                                                const float* __restrict__ W_UQ,
                                                const float* __restrict__ W_UK,
                                                const float* __restrict__ W_UV,
                                                const float* __restrict__ W_O,
                                                _Float16* __restrict__ Wmeg,
                                                _Float16* __restrict__ Wuq,
                                                _Float16* __restrict__ Wukv,
                                                _Float16* __restrict__ Wo) {
    __shared__ float tile[32][33];
    const int id = blockIdx.x;
    if (id < 1024) {
        wt_body(W_DKV, Wmeg, 2048, 512, id & 63, id >> 6, tile);
    } else if (id < 1536) {
        int l = id - 1024;
        wt_body(W_KR, Wmeg + (size_t)512 * 2048, 2048, 256, l & 63, l >> 6, tile);
    } else if (id < 4608) {
        int l = id - 1536;
        wt_body(W_DQ, Wmeg + (size_t)768 * 2048, 2048, 1536, l & 63, l >> 6, tile);
    } else if (id < 6656) {
        int l = id - 4608;
        wt_body(W_QR, Wmeg + (size_t)2304 * 2048, 2048, 1024, l & 63, l >> 6, tile);
    } else if (id < 9728) {
        int l = id - 6656;
        wt_body(W_UQ, Wuq, 1536, 2048, l % 48, l / 48, tile);
    } else if (id < 9984) {
        int l = id - 9728;
        wt_body(W_UK, Wukv, 512, 512, l & 15, l >> 4, tile);
    } else if (id < 10240) {
        int l = id - 9984;
        wt_body(W_UV, Wukv + (size_t)512 * 512, 512, 512, l & 15, l >> 4, tile);
    } else if (id < 14336) {
        int l = id - 10240;
        wt_body(W_O, Wo, 2048, 2048, l & 63, l >> 6, tile);
    } else {
        int l = id - 14336;
        int t1 = threadIdx.y * 32 + threadIdx.x;
        size_t i = ((size_t)l * 256 + t1) * 8;
        float4 a = *(const float4*)(x + i);
        float4 b4 = *(const float4*)(x + i + 4);
        float va[8] = {a.x, a.y, a.z, a.w, b4.x, b4.y, b4.z, b4.w};
        half8 f;
#pragma unroll
        for (int j = 0; j < 8; ++j) f[j] = (_Float16)va[j];
        *(half8*)(xf + i) = f;
    }
}

// ---------------------------------------------------------------------------
// fp16 single-pass MFMA GEMM body. C = A[M][lda] @ Bt[N][K]^T, fp32 accum.
// Tile 128x128, BK=32, 4 waves (2x2), global_load_lds staging. [verified r3-r8]
// Epilogue modes:
//  0: p0 = fp32 C [stride N], clamped
//  2: p0 = qb16 bf16 [m][h*192 + (n&127)], scaled by cscale (Q content)
//  3: p0 = Kp bf16 [g][s][192] cols 0..127 (n<512);
//     p1 = Vt bf16 [g][d][2048]            (n>=512)   -- fused K/V pack
//  6: mega projection split:
//     nn<512 : p0=ckv fp32 [m][512] (cl) + p1=ckf fp16 [m][512]
//     nn<768 : p2=krr fp32 [m][256]
//     nn<2304: p3=dqc fp16 [m][1536]
//     else   : p4=qrf fp16 [m][1024]
// Layouts [m89/m91 verified]: A-frag A[m=lane&15][k=quad*8+j];
// B-frag B[n=lane&15][k=quad*8+j]; C/D col=lane&15, row=quad*4+reg.
// ---------------------------------------------------------------------------
__device__ __forceinline__ void gemm_body(const _Float16* __restrict__ A, int lda,
                                          const _Float16* __restrict__ Bt,
                                          void* p0, void* p1, void* p2,
                                          void* p3, void* p4,
                                          float cscale, int mode,
                                          int N, int K, int bx,
                                          _Float16* lA, _Float16* lB) {
    const int t = threadIdx.x, lane = t & 63, w = t >> 6;
    const int quad = lane >> 4, l16 = lane & 15;
    const int wr = w >> 1, wc = w & 1;
    const int m0 = blockIdx.y * 128, n0 = bx * 128;
    f32x4 acc[4][4] = {};

    for (int kt = 0; kt < K; kt += 32) {
        __syncthreads();
#pragma unroll
        for (int c = 0; c < 2; ++c) {
            const int chunk = c * 256 + t;
            const int row = chunk >> 2, co = (chunk & 3) * 8;
            const int lofs = (c * 256 + w * 64) * 8;   // fp16 units, wave-uniform
            gload16(A + (size_t)(m0 + row) * lda + kt + co, lA + lofs);
            gload16(Bt + (size_t)(n0 + row) * K + kt + co, lB + lofs);
        }
        __syncthreads();
        half8 af[4], bf4[4];
#pragma unroll
        for (int i = 0; i < 4; ++i) {
            af[i]  = *(const half8*)&lA[(wr * 64 + i * 16 + l16) * 32 + quad * 8];
            bf4[i] = *(const half8*)&lB[(wc * 64 + i * 16 + l16) * 32 + quad * 8];
        }
#pragma unroll
        for (int i = 0; i < 4; ++i)
#pragma unroll
            for (int j = 0; j < 4; ++j)
                acc[i][j] = __builtin_amdgcn_mfma_f32_16x16x32_f16(af[i], bf4[j], acc[i][j], 0, 0, 0);
    }
#pragma unroll
    for (int i = 0; i < 4; ++i)
#pragma unroll
        for (int j = 0; j < 4; ++j) {
            const int mbase = m0 + wr * 64 + i * 16 + quad * 4;
            const int nn = n0 + wc * 64 + j * 16 + l16;
            if (mode == 0) {
                float* C = (float*)p0;
#pragma unroll
                for (int r = 0; r < 4; ++r)
                    C[(size_t)(mbase + r) * N + nn] = cl(acc[i][j][r]);
            } else if (mode == 2) {
                u16* Q = (u16*)p0;
                const int h = nn >> 7, dcol = nn & 127;
#pragma unroll
                for (int r = 0; r < 4; ++r)
                    Q[(size_t)(mbase + r) * 3072 + h * 192 + dcol] =
                        f2b(acc[i][j][r] * cscale);
            } else if (mode == 3) {
                const int bb = mbase >> 11, s = mbase & 2047;
                if (nn < 512) {
                    u16* Kp = (u16*)p0;
                    const int kv = nn >> 7, d = nn & 127;
                    const size_t rb = ((size_t)((bb * 4 + kv) * 2048 + s)) * 192 + d;
#pragma unroll
                    for (int r = 0; r < 4; ++r)
                        Kp[rb + (size_t)r * 192] = f2b(acc[i][j][r]);
                } else {
                    u16* Vt = (u16*)p1;
                    const int e = nn - 512, kv = e >> 7, d = e & 127;
                    u16x4 pk;
                    pk[0] = f2b(acc[i][j][0]); pk[1] = f2b(acc[i][j][1]);
                    pk[2] = f2b(acc[i][j][2]); pk[3] = f2b(acc[i][j][3]);
                    *(u16x4*)&((u16*)Vt)[((size_t)((bb * 4 + kv) * 128 + d)) * 2048 + s] = pk;
                }
            } else {   // mode 6: mega projection split
                if (nn < 512) {
                    float* ckv = (float*)p0;
                    _Float16* ckf = (_Float16*)p1;
#pragma unroll
                    for (int r = 0; r < 4; ++r) {
                        float v = acc[i][j][r];
                        ckv[(size_t)(mbase + r) * 512 + nn] = cl(v);
                        ckf[(size_t)(mbase + r) * 512 + nn] = (_Float16)v;
                    }
                } else if (nn < 768) {
                    float* krr = (float*)p2;
#pragma unroll
                    for (int r = 0; r < 4; ++r)
                        krr[(size_t)(mbase + r) * 256 + (nn - 512)] = acc[i][j][r];
                } else if (nn < 2304) {
                    _Float16* dqc = (_Float16*)p3;
#pragma unroll
                    for (int r = 0; r < 4; ++r)
                        dqc[(size_t)(mbase + r) * 1536 + (nn - 768)] = (_Float16)acc[i][j][r];
                } else {
                    _Float16* qrf = (_Float16*)p4;
#pragma unroll
                    for (int r = 0; r < 4; ++r)
                        qrf[(size_t)(mbase + r) * 1024 + (nn - 2304)] = (_Float16)acc[i][j][r];
                }
            }
        }
}

__global__ __launch_bounds__(256) void gemm_f16(const _Float16* __restrict__ A, int lda,
                                                const _Float16* __restrict__ Bt,
                                                void* p0, void* p1, void* p2,
                                                void* p3, void* p4,
                                                float cscale, int mode,
                                                int N, int K) {
    __shared__ __align__(16) _Float16 lA[128 * 32];
    __shared__ __align__(16) _Float16 lB[128 * 32];
    gemm_body(A, lda, Bt, p0, p1, p2, p3, p4, cscale, mode, N, K, blockIdx.x, lA, lB);
}

// Heterogeneous dispatch: blocks x<16 -> UQ (Q content, mode 2);
// x>=16 -> UKV (K content | V pack, mode 3). 768 blocks = 3/CU.
__global__ __launch_bounds__(256) void gemm_uqkv(const _Float16* __restrict__ dqc,
                                                 const _Float16* __restrict__ Wuq,
                                                 u16* __restrict__ qb16, float sc,
                                                 const _Float16* __restrict__ ckf,
                                                 const _Float16* __restrict__ Wukv,
                                                 u16* __restrict__ Kp,
                                                 u16* __restrict__ Vt) {
    __shared__ __align__(16) _Float16 lA[128 * 32];
    __shared__ __align__(16) _Float16 lB[128 * 32];
    const int bx = blockIdx.x;
    if (bx < 16)
        gemm_body(dqc, 1536, Wuq, qb16, nullptr, nullptr, nullptr, nullptr,
                  sc, 2, 2048, 1536, bx, lA, lB);
    else
        gemm_body(ckf, 512, Wukv, Kp, Vt, nullptr, nullptr, nullptr,
                  1.f, 3, 1024, 512, bx - 16, lA, lB);
}

// ---------------------------------------------------------------------------
// Merged RoPE (one launch). Blocks 0..8191: Q rope -- qrf fp16 [(b,s)][1024]
// -> qb16 bf16 [(b,s)][h*192+128+d], pre-scaled by 1/sqrt(192).
// Blocks 8192..10239: K rope -- krr fp32 [(b,s)][256] -> Krope fp32 (Output 2)
// + Kp bf16 cols 128..191. Math byte-identical to the split kernels [r3-r8].
// ---------------------------------------------------------------------------
__global__ __launch_bounds__(256) void rope_all(const _Float16* __restrict__ qrf,
                                                const float* __restrict__ krr,
                                                const float* __restrict__ cosc,
                                                const float* __restrict__ sinc,
                                                const int* __restrict__ pos,
                                                u16* __restrict__ qb16,
                                                float* __restrict__ Krope,
                                                u16* __restrict__ Kp) {
    const float sc = 0.07216878364870322f;           // 1/sqrt(192)
    if ((int)blockIdx.x < 8192) {
        int t = blockIdx.x * 256 + threadIdx.x;      // t < 4096*16*32
        int d = t & 31, h = (t >> 5) & 15, rowi = t >> 9;
        int s = rowi & 2047;
        int p = pos[s];
        float c1 = cosc[p * 64 + d],      s1 = sinc[p * 64 + d];
        float c2 = cosc[p * 64 + 32 + d], s2 = sinc[p * 64 + 32 + d];
        const _Float16* base = qrf + (size_t)rowi * 1024 + h * 64;
        float x1 = (float)base[d];
        float x2 = (float)base[d + 32];
        u16* q = qb16 + (size_t)rowi * 3072 + h * 192 + 128;
        q[d]      = f2b((x1 * c1 - x2 * s1) * sc);
        q[d + 32] = f2b((x2 * c2 + x1 * s2) * sc);
    } else {
        int t = (blockIdx.x - 8192) * 256 + threadIdx.x;   // t < 4096*4*32
        int d = t & 31, kv = (t >> 5) & 3, rowi = t >> 7;
        int b = rowi >> 11, s = rowi & 2047;
        int p = pos[s];
        float c1 = cosc[p * 64 + d],      s1 = sinc[p * 64 + d];
        float c2 = cosc[p * 64 + 32 + d], s2 = sinc[p * 64 + 32 + d];
        float x1 = krr[(size_t)rowi * 256 + kv * 64 + d];
        float x2 = krr[(size_t)rowi * 256 + kv * 64 + 32 + d];
        float o1 = x1 * c1 - x2 * s1;
        float o2 = x2 * c2 + x1 * s2;
        int g = b * NKV_ + kv;
        size_t ob = ((size_t)(g * S_) + s) * 64;
        Krope[ob + d]      = cl(o1);
        Krope[ob + 32 + d] = cl(o2);
        u16* kp = Kp + ((size_t)(g * S_ + s)) * 192 + 128;
        kp[d]      = f2b(o1);
        kp[32 + d] = f2b(o2);
    }
}

// ---------------------------------------------------------------------------
// MFMA flash attention. Block = 4 waves = 64 q-rows of one (b,h).
// Paired q-tiles: qt = 31-px then px -> 33 kv-tile units per block, uniform.
// Flat grid 512; id decode puts the 64 blocks of each KV group g on one XCD
// (id&7 == g) so K/V (~1.3MB/g) stay in the 4MB XCD L2. [verified r5: FETCH
// 48.8->17.7MB]
// Staging: direct synchronous copy. [r6: reg-prefetch split regressed.]
// REGISTER CLIFF [r7/r8 post-mortem]: VGPR 132 > 128 boundary -> only 1
// block/CU resident (157us vs r5's 109 at 116 VGPR). Source-level array
// removal did NOT move the count (r8: still 132). Fix: __launch_bounds__
// (256, 4) -> allocator hard-cap 512/4 = 128 VGPR; ~4-reg spill is far
// cheaper than halved occupancy. LDS 54.5KB caps at 2 blocks/CU regardless.
// Mask-skip: only the LAST kv-tile per q-tile is diagonal.
// Row-sum l via bf16-ones d-row (row 128) in lVt: PV's 9th n-chunk
// accumulates l into O9[8]. Defer-max (T13, THR=8).
// Q from qb16 bf16 [(b,s)][h*192+k], pre-scaled by 1/sqrt(192).
// Out: atf fp16 [(b,s)][h*128+d].
// Layouts [m89/m91 verified]: A-frag A[m=lane&15][k=quad*8+j];
// B-frag B[n=lane&15][k=quad*8+j]; C/D col=lane&15, row=quad*4+reg.
// ---------------------------------------------------------------------------
__global__ __launch_bounds__(256, 4) void attn_mfma(const u16* __restrict__ qb16,
                                                    const u16* __restrict__ Kp,
                                                    const u16* __restrict__ Vt,
                                                    _Float16* __restrict__ atf) {
    __shared__ __align__(16) u16 lK[64 * 200];     // 64 kv-rows x 192 (+8 pad)
    __shared__ __align__(16) u16 lVt[144 * 72];    // 128 d-rows + 16 (ones) x 64 (+8 pad)
    __shared__ __align__(16) u16 lP[4][16 * 72];   // per-wave P 16x64 (+8 pad)

    const int t = threadIdx.x, lane = t & 63, w = t >> 6;
    const int quad = lane >> 4, l16 = lane & 15;
    // XCD-aligned decode: g = id&7 so all blocks of a KV group share an XCD
    const int id = blockIdx.x;                     // 0..511
    const int g = id & 7;                          // (b*4 + kv)
    const int b = g >> 2;
    const int k = id >> 3;                         // 0..63
    const int h = (g & 3) * 4 + (k & 3);
    const int px = k >> 2;                         // 0..15

    // ones-row init for the l-column trick (rows 128..143, cols 0..63)
#pragma unroll
    for (int c = 0; c < 4; ++c) {
        int i = c * 256 + t;                       // 0..1023
        int rr = 128 + (i >> 6), ccol = i & 63;
        lVt[rr * 72 + ccol] = (rr == 128) ? (u16)0x3F80 : (u16)0;
    }

    for (int ph = 0; ph < 2; ++ph) {
        const int qt = ph ? px : (31 - px);        // heavy tile first
        const int q0 = qt * 64;
        const int iw = q0 + w * 16;                // wave's q-row base

        // Q fragments: rows m=l16, contiguous 192-col row (pre-scaled bf16)
        short8 qf[6];
        {
            const u16* qp = qb16 + ((size_t)(b * S_ + iw + l16)) * 3072 + h * 192;
#pragma unroll
            for (int kc = 0; kc < 6; ++kc)
                qf[kc] = *(const short8*)&qp[kc * 32 + quad * 8];
        }

        f32x4 O9[9] = {};                          // [0..7]=O d-chunks, [8]=l (col l16==0)
        float mr[4] = {-1e30f, -1e30f, -1e30f, -1e30f};

        const int ntile = qt + 1;
        for (int tile = 0; tile < ntile; ++tile) {
            const int j0 = tile * 64;
            __syncthreads();
            // stage K tile: 64 rows x 192 u16 = 1536 x 16B, 6/thread
#pragma unroll
            for (int c = 0; c < 6; ++c) {
                int seg = c * 256 + t;
                int row = seg / 24, ch = (seg % 24) * 8;
                *(uint4*)&lK[row * 200 + ch] =
                    *(const uint4*)&Kp[((size_t)g * S_ + j0 + row) * 192 + ch];
            }
            // stage Vt tile: 128 d-rows x 64 u16 = 1024 x 16B, 4/thread
#pragma unroll
            for (int c = 0; c < 4; ++c) {
                int seg = c * 256 + t;
                int d = seg >> 3, ch = (seg & 7) * 8;
                *(uint4*)&lVt[d * 72 + ch] =
                    *(const uint4*)&Vt[((size_t)g * 128 + d) * S_ + j0 + ch];
            }
            __syncthreads();

            // S = Q K^T, four 16-col chunks
            f32x4 s4[4];
            __builtin_amdgcn_s_setprio(1);
#pragma unroll
            for (int cc = 0; cc < 4; ++cc) {
                f32x4 sx = {};
#pragma unroll
                for (int kc = 0; kc < 6; ++kc) {
                    short8 kf = *(const short8*)&lK[(cc * 16 + l16) * 200 + kc * 32 + quad * 8];
                    sx = __builtin_amdgcn_mfma_f32_16x16x32_bf16(qf[kc], kf, sx, 0, 0, 0);
                }
                s4[cc] = sx;
            }
            __builtin_amdgcn_s_setprio(0);

            // mask IN PLACE, only the diagonal tile (provably the last one)
            if (tile == ntile - 1) {
#pragma unroll
                for (int cc = 0; cc < 4; ++cc)
#pragma unroll
                    for (int r = 0; r < 4; ++r) {
                        int ir = iw + quad * 4 + r;
                        if (j0 + cc * 16 + l16 > ir) s4[cc][r] = -1e30f;
                    }
            }
            // row max across the 16-lane group
            float tm[4];
#pragma unroll
            for (int r = 0; r < 4; ++r)
                tm[r] = fmaxf(fmaxf(s4[0][r], s4[1][r]), fmaxf(s4[2][r], s4[3][r]));
#pragma unroll
            for (int m = 1; m < 16; m <<= 1)
#pragma unroll
                for (int r = 0; r < 4; ++r) tm[r] = fmaxf(tm[r], __shfl_xor(tm[r], m));
            // defer-max: only rescale when the max grew by > 8
            int small = (tm[0] <= mr[0] + 8.f) && (tm[1] <= mr[1] + 8.f) &&
                        (tm[2] <= mr[2] + 8.f) && (tm[3] <= mr[3] + 8.f);
            if (!__all(small)) {
                float al[4];
#pragma unroll
                for (int r = 0; r < 4; ++r) {
                    float mn = fmaxf(mr[r], tm[r]);
                    al[r] = __expf(mr[r] - mn);
                    mr[r] = mn;
                }
#pragma unroll
                for (int dc = 0; dc < 9; ++dc)
#pragma unroll
                    for (int r = 0; r < 4; ++r) O9[dc][r] *= al[r];
            }
            // P = exp(S - mr) IN PLACE (bounded by e^8 when deferred)
#pragma unroll
            for (int cc = 0; cc < 4; ++cc)
#pragma unroll
                for (int r = 0; r < 4; ++r)
                    s4[cc][r] = __expf(s4[cc][r] - mr[r]);
            // P (C layout) -> LDS -> A-layout frags (k = 0..31, 32..63)
#pragma unroll
            for (int cc = 0; cc < 4; ++cc)
#pragma unroll
                for (int r = 0; r < 4; ++r)
                    lP[w][(quad * 4 + r) * 72 + cc * 16 + l16] = f2b(s4[cc][r]);
            short8 pf0 = *(const short8*)&lP[w][l16 * 72 + quad * 8];
            short8 pf1 = *(const short8*)&lP[w][l16 * 72 + 32 + quad * 8];
            // O += P V ; 9th chunk accumulates l via the ones-row
            __builtin_amdgcn_s_setprio(1);
#pragma unroll
            for (int dc = 0; dc < 9; ++dc) {
                short8 vf0 = *(const short8*)&lVt[(dc * 16 + l16) * 72 + quad * 8];
                short8 vf1 = *(const short8*)&lVt[(dc * 16 + l16) * 72 + 32 + quad * 8];
                O9[dc] = __builtin_amdgcn_mfma_f32_16x16x32_bf16(pf0, vf0, O9[dc], 0, 0, 0);
                O9[dc] = __builtin_amdgcn_mfma_f32_16x16x32_bf16(pf1, vf1, O9[dc], 0, 0, 0);
            }
            __builtin_amdgcn_s_setprio(0);
        }
        // epilogue: l lives in O9[8] at col l16==0; broadcast within quad
        float inv[4];
#pragma unroll
        for (int r = 0; r < 4; ++r) {
            float lr = __shfl(O9[8][r], quad * 16);
            inv[r] = 1.f / fmaxf(lr, 1e-30f);
        }
#pragma unroll
        for (int dc = 0; dc < 8; ++dc)
#pragma unroll
            for (int r = 0; r < 4; ++r) {
                int ir = iw + quad * 4 + r;
                atf[((size_t)(b * S_ + ir)) * 2048 + h * 128 + dc * 16 + l16] =
                    (_Float16)cl(O9[dc][r] * inv[r]);
            }
    }
}

// ---------------------------------------------------------------------------
extern "C" void kernel_launch(void* const* d_in, const int* in_sizes, int n_in,
                              void* d_out, int out_size, void* d_ws, size_t ws_size,
                              hipStream_t stream) {
    const float* x     = (const float*)d_in[0];
    const float* cosc  = (const float*)d_in[1];
    const float* sinc  = (const float*)d_in[2];
    const int*   pos   = (const int*)d_in[3];
    // d_in[4] = attn_mask (causal tril) -- implemented analytically
    const float* W_DKV = (const float*)d_in[5];
    const float* W_UK  = (const float*)d_in[6];
    const float* W_UV  = (const float*)d_in[7];
    const float* W_DQ  = (const float*)d_in[8];
    const float* W_UQ  = (const float*)d_in[9];
    const float* W_KR  = (const float*)d_in[10];
    const float* W_QR  = (const float*)d_in[11];
    const float* W_O   = (const float*)d_in[12];
    (void)ws_size;

    float* outp      = (float*)d_out;            // [B,S,2048]
    float* ckv_out   = outp + 8388608;           // [B,S,512]
    float* krope_out = outp + 10485760;          // [B,NKV,S,64]

    // ---- workspace (~128 MB) ----
    char* w = (char*)d_ws;
    auto alloc = [&](size_t bytes) { char* p = w; w += bytes; return p; };
    _Float16* xf   = (_Float16*)alloc(16777216);  // x fp16 [4096][2048]
    _Float16* ckf  = (_Float16*)alloc(4194304);   // c_kv fp16 [4096][512]
    float*    krr  = (float*)alloc(4194304);      // K-rope raw fp32 [4096][256]
    _Float16* dqc  = (_Float16*)alloc(12582912);  // c_q fp16 [4096][1536]
    _Float16* qrf  = (_Float16*)alloc(8388608);   // q_rope_raw fp16 [4096][1024]
    u16*      qb16 = (u16*)alloc(25165824);       // Q bf16 pre-scaled [4096][16][192]
    u16*      Kp   = (u16*)alloc(6291456);        // [8][2048][192] bf16
    u16*      Vt   = (u16*)alloc(4194304);        // [8][128][2048] bf16
    _Float16* atf  = (_Float16*)alloc(16777216);  // attn out fp16 [4096][2048]
    _Float16* Wmeg = (_Float16*)alloc(13631488);  // [3328][2048] (DKV|KR|DQ|QR)
    _Float16* Wuq  = (_Float16*)alloc(6291456);   // [2048][1536]
    _Float16* Wukv = (_Float16*)alloc(1048576);   // [1024][512]  (UK|UV)
    _Float16* Wo   = (_Float16*)alloc(8388608);   // [2048][2048]

    const float sc = 0.07216878364870322f;        // 1/sqrt(192)

    // input / weight prep: ONE launch (8 transposes + x->fp16)
    prep_all<<<18432, dim3(32, 8), 0, stream>>>(x, xf,
                                                W_DKV, W_KR, W_DQ, W_QR,
                                                W_UQ, W_UK, W_UV, W_O,
                                                Wmeg, Wuq, Wukv, Wo);

    // mega projection: c_kv (Output 1) | ckf | K-rope-raw | c_q | q-rope-raw
    gemm_f16<<<dim3(26, 32), 256, 0, stream>>>(xf, 2048, Wmeg,
                                               ckv_out, ckf, krr, dqc, qrf,
                                               1.f, 6, 3328, 2048);
    // Q content (mode 2) + K content | V pack (mode 3), heterogeneous dispatch
    gemm_uqkv<<<dim3(24, 32), 256, 0, stream>>>(dqc, Wuq, qb16, sc,
                                                ckf, Wukv, Kp, Vt);

    // rope (merged): Q -> qb16 cols 128..191; K -> Output 2 + Kp cols 128..191
    rope_all<<<10240, 256, 0, stream>>>(qrf, krr, cosc, sinc, pos,
                                        qb16, krope_out, Kp);

    // attention + output projection
    attn_mfma<<<512, 256, 0, stream>>>(qb16, Kp, Vt, atf);
    gemm_f16<<<dim3(16, 32), 256, 0, stream>>>(atf, 2048, Wo,
                                               outp, nullptr, nullptr, nullptr, nullptr,
                                               1.f, 0, 2048, 2048);
}

// Round 10
// 484.138 us; speedup vs baseline: 1.1565x; 1.0959x over previous
//
#include <hip/hip_runtime.h>
#include <stdint.h>

typedef unsigned short u16;
typedef unsigned int u32;

// Problem constants
#define B_    2
#define S_    2048
#define NQ_   16
#define NKV_  4
#define DH_   128
#define DR_   64
#define DT_   192
#define M_    4096   // B_*S_

using short8 = __attribute__((ext_vector_type(8))) short;
using f32x4  = __attribute__((ext_vector_type(4))) float;
using half8  = __attribute__((ext_vector_type(8))) _Float16;
using u16x4  = __attribute__((ext_vector_type(4))) u16;

__device__ __forceinline__ float cl(float f) {   // clamp diagnostic: inf/NaN -> +-3.38e38 signature
    return fminf(fmaxf(f, -3.38e38f), 3.38e38f);
}
__device__ __forceinline__ u16 f2b(float f) {    // fp32 -> bf16 RNE
    union { float f; u32 u; } v; v.f = f;
    u32 u = v.u;
    return (u16)((u + 0x7fffu + ((u >> 16) & 1u)) >> 16);
}
// async global->LDS, 16B per lane. LDS dest is wave-uniform base + lane*16.
__device__ __forceinline__ void gload16(const void* g, void* l) {
    __builtin_amdgcn_global_load_lds(
        (const __attribute__((address_space(1))) void*)g,
        (__attribute__((address_space(3))) void*)l,
        16, 0, 0);
}

// ---------------------------------------------------------------------------
// prep_all: ONE launch for all weight transposes + x->fp16.
// block (32,8); flat-id range decode (all shapes compile-time):
//   [0,1024)      W_DKV -> Wmeg[0]          K=2048 N=512
//   [1024,1536)   W_KR  -> Wmeg[512*2048]   K=2048 N=256
//   [1536,4608)   W_DQ  -> Wmeg[768*2048]   K=2048 N=1536
//   [4608,6656)   W_QR  -> Wmeg[2304*2048]  K=2048 N=1024
//   [6656,9728)   W_UQ  -> Wuq              K=1536 N=2048
//   [9728,9984)   W_UK  -> Wukv             K=512  N=512
//   [9984,10240)  W_UV  -> Wukv[512*512]    K=512  N=512
//   [10240,14336) W_O   -> Wo               K=2048 N=2048
//   [14336,18432) x fp32 -> xf fp16 (1-D, 8 elems/thread)
// Math byte-identical to the split wt_f16/x_f16 kernels [r3-r9].
// ---------------------------------------------------------------------------
__device__ __forceinline__ void wt_body(const float* __restrict__ W,
                                        _Float16* __restrict__ T,
                                        int K, int N, int kx, int ny,
                                        float (*tile)[33]) {
    int k0 = kx * 32, n0 = ny * 32;
    int tx = threadIdx.x, ty = threadIdx.y;
#pragma unroll
    for (int i = 0; i < 32; i += 8)
        tile[ty + i][tx] = W[(size_t)(k0 + ty + i) * N + n0 + tx];
    __syncthreads();
#pragma unroll
    for (int i = 0; i < 32; i += 8)
        T[(size_t)(n0 + ty + i) * K + k0 + tx] = (_Float16)tile[tx][ty + i];
}

__global__ __launch_bounds__(256) void prep_all(const float* __restrict__ x,
                                                _Float16* __restrict__ xf,
                                                const float* __restrict__ W_DKV,
                                                const float* __restrict__ W_KR,
                                                const float* __restrict__ W_DQ,
                                                const float* __restrict__ W_QR,
                                                const float* __restrict__ W_UQ,
                                                const float* __restrict__ W_UK,
                                                const float* __restrict__ W_UV,
                                                const float* __restrict__ W_O,
                                                _Float16* __restrict__ Wmeg,
                                                _Float16* __restrict__ Wuq,
                                                _Float16* __restrict__ Wukv,
                                                _Float16* __restrict__ Wo) {
    __shared__ float tile[32][33];
    const int id = blockIdx.x;
    if (id < 1024) {
        wt_body(W_DKV, Wmeg, 2048, 512, id & 63, id >> 6, tile);
    } else if (id < 1536) {
        int l = id - 1024;
        wt_body(W_KR, Wmeg + (size_t)512 * 2048, 2048, 256, l & 63, l >> 6, tile);
    } else if (id < 4608) {
        int l = id - 1536;
        wt_body(W_DQ, Wmeg + (size_t)768 * 2048, 2048, 1536, l & 63, l >> 6, tile);
    } else if (id < 6656) {
        int l = id - 4608;
        wt_body(W_QR, Wmeg + (size_t)2304 * 2048, 2048, 1024, l & 63, l >> 6, tile);
    } else if (id < 9728) {
        int l = id - 6656;
        wt_body(W_UQ, Wuq, 1536, 2048, l % 48, l / 48, tile);
    } else if (id < 9984) {
        int l = id - 9728;
        wt_body(W_UK, Wukv, 512, 512, l & 15, l >> 4, tile);
    } else if (id < 10240) {
        int l = id - 9984;
        wt_body(W_UV, Wukv + (size_t)512 * 512, 512, 512, l & 15, l >> 4, tile);
    } else if (id < 14336) {
        int l = id - 10240;
        wt_body(W_O, Wo, 2048, 2048, l & 63, l >> 6, tile);
    } else {
        int l = id - 14336;
        int t1 = threadIdx.y * 32 + threadIdx.x;
        size_t i = ((size_t)l * 256 + t1) * 8;
        float4 a = *(const float4*)(x + i);
        float4 b4 = *(const float4*)(x + i + 4);
        float va[8] = {a.x, a.y, a.z, a.w, b4.x, b4.y, b4.z, b4.w};
        half8 f;
#pragma unroll
        for (int j = 0; j < 8; ++j) f[j] = (_Float16)va[j];
        *(half8*)(xf + i) = f;
    }
}

// ---------------------------------------------------------------------------
// fp16 single-pass MFMA GEMM body. C = A[M][lda] @ Bt[N][K]^T, fp32 accum.
// Tile 128x128, BK=32, 4 waves (2x2), global_load_lds staging. [verified r3-r9]
// Epilogue modes:
//  0: p0 = fp32 C [stride N], clamped
//  2: p0 = qb16 bf16 [m][h*192 + (n&127)], scaled by cscale (Q content)
//  3: p0 = Kp bf16 [g][s][192] cols 0..127 (n<512);
//     p1 = Vt bf16 [g][d][2048]            (n>=512)   -- fused K/V pack
//  6: mega projection split:
//     nn<512 : p0=ckv fp32 [m][512] (cl) + p1=ckf fp16 [m][512]
//     nn<768 : p2=krr fp32 [m][256]
//     nn<2304: p3=dqc fp16 [m][1536]
//     else   : p4=qrf fp16 [m][1024]
// Layouts [m89/m91 verified]: A-frag A[m=lane&15][k=quad*8+j];
// B-frag B[n=lane&15][k=quad*8+j]; C/D col=lane&15, row=quad*4+reg.
// ---------------------------------------------------------------------------
__device__ __forceinline__ void gemm_body(const _Float16* __restrict__ A, int lda,
                                          const _Float16* __restrict__ Bt,
                                          void* p0, void* p1, void* p2,
                                          void* p3, void* p4,
                                          float cscale, int mode,
                                          int N, int K, int bx,
                                          _Float16* lA, _Float16* lB) {
    const int t = threadIdx.x, lane = t & 63, w = t >> 6;
    const int quad = lane >> 4, l16 = lane & 15;
    const int wr = w >> 1, wc = w & 1;
    const int m0 = blockIdx.y * 128, n0 = bx * 128;
    f32x4 acc[4][4] = {};

    for (int kt = 0; kt < K; kt += 32) {
        __syncthreads();
#pragma unroll
        for (int c = 0; c < 2; ++c) {
            const int chunk = c * 256 + t;
            const int row = chunk >> 2, co = (chunk & 3) * 8;
            const int lofs = (c * 256 + w * 64) * 8;   // fp16 units, wave-uniform
            gload16(A + (size_t)(m0 + row) * lda + kt + co, lA + lofs);
            gload16(Bt + (size_t)(n0 + row) * K + kt + co, lB + lofs);
        }
        __syncthreads();
        half8 af[4], bf4[4];
#pragma unroll
        for (int i = 0; i < 4; ++i) {
            af[i]  = *(const half8*)&lA[(wr * 64 + i * 16 + l16) * 32 + quad * 8];
            bf4[i] = *(const half8*)&lB[(wc * 64 + i * 16 + l16) * 32 + quad * 8];
        }
#pragma unroll
        for (int i = 0; i < 4; ++i)
#pragma unroll
            for (int j = 0; j < 4; ++j)
                acc[i][j] = __builtin_amdgcn_mfma_f32_16x16x32_f16(af[i], bf4[j], acc[i][j], 0, 0, 0);
    }
#pragma unroll
    for (int i = 0; i < 4; ++i)
#pragma unroll
        for (int j = 0; j < 4; ++j) {
            const int mbase = m0 + wr * 64 + i * 16 + quad * 4;
            const int nn = n0 + wc * 64 + j * 16 + l16;
            if (mode == 0) {
                float* C = (float*)p0;
#pragma unroll
                for (int r = 0; r < 4; ++r)
                    C[(size_t)(mbase + r) * N + nn] = cl(acc[i][j][r]);
            } else if (mode == 2) {
                u16* Q = (u16*)p0;
                const int h = nn >> 7, dcol = nn & 127;
#pragma unroll
                for (int r = 0; r < 4; ++r)
                    Q[(size_t)(mbase + r) * 3072 + h * 192 + dcol] =
                        f2b(acc[i][j][r] * cscale);
            } else if (mode == 3) {
                const int bb = mbase >> 11, s = mbase & 2047;
                if (nn < 512) {
                    u16* Kp = (u16*)p0;
                    const int kv = nn >> 7, d = nn & 127;
                    const size_t rb = ((size_t)((bb * 4 + kv) * 2048 + s)) * 192 + d;
#pragma unroll
                    for (int r = 0; r < 4; ++r)
                        Kp[rb + (size_t)r * 192] = f2b(acc[i][j][r]);
                } else {
                    u16* Vt = (u16*)p1;
                    const int e = nn - 512, kv = e >> 7, d = e & 127;
                    u16x4 pk;
                    pk[0] = f2b(acc[i][j][0]); pk[1] = f2b(acc[i][j][1]);
                    pk[2] = f2b(acc[i][j][2]); pk[3] = f2b(acc[i][j][3]);
                    *(u16x4*)&((u16*)Vt)[((size_t)((bb * 4 + kv) * 128 + d)) * 2048 + s] = pk;
                }
            } else {   // mode 6: mega projection split
                if (nn < 512) {
                    float* ckv = (float*)p0;
                    _Float16* ckf = (_Float16*)p1;
#pragma unroll
                    for (int r = 0; r < 4; ++r) {
                        float v = acc[i][j][r];
                        ckv[(size_t)(mbase + r) * 512 + nn] = cl(v);
                        ckf[(size_t)(mbase + r) * 512 + nn] = (_Float16)v;
                    }
                } else if (nn < 768) {
                    float* krr = (float*)p2;
#pragma unroll
                    for (int r = 0; r < 4; ++r)
                        krr[(size_t)(mbase + r) * 256 + (nn - 512)] = acc[i][j][r];
                } else if (nn < 2304) {
                    _Float16* dqc = (_Float16*)p3;
#pragma unroll
                    for (int r = 0; r < 4; ++r)
                        dqc[(size_t)(mbase + r) * 1536 + (nn - 768)] = (_Float16)acc[i][j][r];
                } else {
                    _Float16* qrf = (_Float16*)p4;
#pragma unroll
                    for (int r = 0; r < 4; ++r)
                        qrf[(size_t)(mbase + r) * 1024 + (nn - 2304)] = (_Float16)acc[i][j][r];
                }
            }
        }
}

__global__ __launch_bounds__(256) void gemm_f16(const _Float16* __restrict__ A, int lda,
                                                const _Float16* __restrict__ Bt,
                                                void* p0, void* p1, void* p2,
                                                void* p3, void* p4,
                                                float cscale, int mode,
                                                int N, int K) {
    __shared__ __align__(16) _Float16 lA[128 * 32];
    __shared__ __align__(16) _Float16 lB[128 * 32];
    gemm_body(A, lda, Bt, p0, p1, p2, p3, p4, cscale, mode, N, K, blockIdx.x, lA, lB);
}

// Heterogeneous dispatch: blocks x<16 -> UQ (Q content, mode 2);
// x>=16 -> UKV (K content | V pack, mode 3). 768 blocks = 3/CU.
__global__ __launch_bounds__(256) void gemm_uqkv(const _Float16* __restrict__ dqc,
                                                 const _Float16* __restrict__ Wuq,
                                                 u16* __restrict__ qb16, float sc,
                                                 const _Float16* __restrict__ ckf,
                                                 const _Float16* __restrict__ Wukv,
                                                 u16* __restrict__ Kp,
                                                 u16* __restrict__ Vt) {
    __shared__ __align__(16) _Float16 lA[128 * 32];
    __shared__ __align__(16) _Float16 lB[128 * 32];
    const int bx = blockIdx.x;
    if (bx < 16)
        gemm_body(dqc, 1536, Wuq, qb16, nullptr, nullptr, nullptr, nullptr,
                  sc, 2, 2048, 1536, bx, lA, lB);
    else
        gemm_body(ckf, 512, Wukv, Kp, Vt, nullptr, nullptr, nullptr,
                  1.f, 3, 1024, 512, bx - 16, lA, lB);
}

// ---------------------------------------------------------------------------
// Merged RoPE (one launch). Blocks 0..8191: Q rope -- qrf fp16 [(b,s)][1024]
// -> qb16 bf16 [(b,s)][h*192+128+d], pre-scaled by 1/sqrt(192).
// Blocks 8192..10239: K rope -- krr fp32 [(b,s)][256] -> Krope fp32 (Output 2)
// + Kp bf16 cols 128..191. Math byte-identical to the split kernels [r3-r9].
// ---------------------------------------------------------------------------
__global__ __launch_bounds__(256) void rope_all(const _Float16* __restrict__ qrf,
                                                const float* __restrict__ krr,
                                                const float* __restrict__ cosc,
                                                const float* __restrict__ sinc,
                                                const int* __restrict__ pos,
                                                u16* __restrict__ qb16,
                                                float* __restrict__ Krope,
                                                u16* __restrict__ Kp) {
    const float sc = 0.07216878364870322f;           // 1/sqrt(192)
    if ((int)blockIdx.x < 8192) {
        int t = blockIdx.x * 256 + threadIdx.x;      // t < 4096*16*32
        int d = t & 31, h = (t >> 5) & 15, rowi = t >> 9;
        int s = rowi & 2047;
        int p = pos[s];
        float c1 = cosc[p * 64 + d],      s1 = sinc[p * 64 + d];
        float c2 = cosc[p * 64 + 32 + d], s2 = sinc[p * 64 + 32 + d];
        const _Float16* base = qrf + (size_t)rowi * 1024 + h * 64;
        float x1 = (float)base[d];
        float x2 = (float)base[d + 32];
        u16* q = qb16 + (size_t)rowi * 3072 + h * 192 + 128;
        q[d]      = f2b((x1 * c1 - x2 * s1) * sc);
        q[d + 32] = f2b((x2 * c2 + x1 * s2) * sc);
    } else {
        int t = (blockIdx.x - 8192) * 256 + threadIdx.x;   // t < 4096*4*32
        int d = t & 31, kv = (t >> 5) & 3, rowi = t >> 7;
        int b = rowi >> 11, s = rowi & 2047;
        int p = pos[s];
        float c1 = cosc[p * 64 + d],      s1 = sinc[p * 64 + d];
        float c2 = cosc[p * 64 + 32 + d], s2 = sinc[p * 64 + 32 + d];
        float x1 = krr[(size_t)rowi * 256 + kv * 64 + d];
        float x2 = krr[(size_t)rowi * 256 + kv * 64 + 32 + d];
        float o1 = x1 * c1 - x2 * s1;
        float o2 = x2 * c2 + x1 * s2;
        int g = b * NKV_ + kv;
        size_t ob = ((size_t)(g * S_) + s) * 64;
        Krope[ob + d]      = cl(o1);
        Krope[ob + 32 + d] = cl(o2);
        u16* kp = Kp + ((size_t)(g * S_ + s)) * 192 + 128;
        kp[d]      = f2b(o1);
        kp[32 + d] = f2b(o2);
    }
}

// ---------------------------------------------------------------------------
// MFMA flash attention -- EXACT r5 version (109us, VGPR 116, occ 20.4%).
// [r6-r9 post-mortem: mask-skip (`if tile==ntile-1` in the tile loop) is the
// feature perfectly correlated with VGPR 116->132 and occupancy 20->11%;
// three source rewrites + __launch_bounds__(256,4) all failed to undo it.
// Reverted to the proven kernel; masking every tile is numerically identical
// since non-diagonal tiles never trigger the predicate. DO NOT reintroduce
// the conditional-mask or reg-prefetch variants.]
// Block = 4 waves = 64 q-rows of one (b,h). Paired q-tiles: qt = 31-px then
// px -> 33 kv-tile units per block, uniform. Flat grid 512; id&7 == g puts
// each KV group's 64 blocks on one XCD (K/V ~1.3MB L2-resident; FETCH
// 48.8->17.7MB, r5). Row-sum l via bf16-ones d-row: PV's 9th n-chunk
// accumulates l into O9[8]. Defer-max (T13, THR=8).
// Q from qb16 bf16 [(b,s)][h*192+k], pre-scaled by 1/sqrt(192).
// Out: atf fp16 [(b,s)][h*128+d].
// Layouts [m89/m91 verified]: A-frag A[m=lane&15][k=quad*8+j];
// B-frag B[n=lane&15][k=quad*8+j]; C/D col=lane&15, row=quad*4+reg.
// ---------------------------------------------------------------------------
__global__ __launch_bounds__(256) void attn_mfma(const u16* __restrict__ qb16,
                                                 const u16* __restrict__ Kp,
                                                 const u16* __restrict__ Vt,
                                                 _Float16* __restrict__ atf) {
    __shared__ __align__(16) u16 lK[64 * 200];     // 64 kv-rows x 192 (+8 pad)
    __shared__ __align__(16) u16 lVt[144 * 72];    // 128 d-rows + 16 (ones) x 64 (+8 pad)
    __shared__ __align__(16) u16 lP[4][16 * 72];   // per-wave P 16x64 (+8 pad)

    const int t = threadIdx.x, lane = t & 63, w = t >> 6;
    const int quad = lane >> 4, l16 = lane & 15;
    // XCD-aligned decode: g = id&7 so all blocks of a KV group share an XCD
    const int id = blockIdx.x;                     // 0..511
    const int g = id & 7;                          // (b*4 + kv)
    const int b = g >> 2;
    const int k = id >> 3;                         // 0..63
    const int h = (g & 3) * 4 + (k & 3);
    const int px = k >> 2;                         // 0..15

    // ones-row init for the l-column trick (rows 128..143, cols 0..63)
#pragma unroll
    for (int c = 0; c < 4; ++c) {
        int i = c * 256 + t;                       // 0..1023
        int rr = 128 + (i >> 6), ccol = i & 63;
        lVt[rr * 72 + ccol] = (rr == 128) ? (u16)0x3F80 : (u16)0;
    }

    for (int ph = 0; ph < 2; ++ph) {
        const int qt = ph ? px : (31 - px);        // heavy tile first
        const int q0 = qt * 64;
        const int iw = q0 + w * 16;                // wave's q-row base

        // Q fragments: rows m=l16, contiguous 192-col row (pre-scaled bf16)
        short8 qf[6];
        {
            const u16* qp = qb16 + ((size_t)(b * S_ + iw + l16)) * 3072 + h * 192;
#pragma unroll
            for (int kc = 0; kc < 6; ++kc)
                qf[kc] = *(const short8*)&qp[kc * 32 + quad * 8];
        }

        f32x4 O9[9] = {};                          // [0..7]=O d-chunks, [8]=l (col l16==0)
        float mr[4] = {-1e30f, -1e30f, -1e30f, -1e30f};

        const int ntile = qt + 1;
        for (int tile = 0; tile < ntile; ++tile) {
            const int j0 = tile * 64;
            __syncthreads();
            // stage K tile: 64 rows x 192 u16 = 1536 x 16B, 6/thread
#pragma unroll
            for (int c = 0; c < 6; ++c) {
                int seg = c * 256 + t;
                int row = seg / 24, ch = (seg % 24) * 8;
                *(uint4*)&lK[row * 200 + ch] =
                    *(const uint4*)&Kp[((size_t)g * S_ + j0 + row) * 192 + ch];
            }
            // stage Vt tile: 128 d-rows x 64 u16 = 1024 x 16B, 4/thread
#pragma unroll
            for (int c = 0; c < 4; ++c) {
                int seg = c * 256 + t;
                int d = seg >> 3, ch = (seg & 7) * 8;
                *(uint4*)&lVt[d * 72 + ch] =
                    *(const uint4*)&Vt[((size_t)g * 128 + d) * S_ + j0 + ch];
            }
            __syncthreads();

            // S = Q K^T, four 16-col chunks
            f32x4 s4[4];
            __builtin_amdgcn_s_setprio(1);
#pragma unroll
            for (int cc = 0; cc < 4; ++cc) {
                f32x4 sx = {};
#pragma unroll
                for (int kc = 0; kc < 6; ++kc) {
                    short8 kf = *(const short8*)&lK[(cc * 16 + l16) * 200 + kc * 32 + quad * 8];
                    sx = __builtin_amdgcn_mfma_f32_16x16x32_bf16(qf[kc], kf, sx, 0, 0, 0);
                }
                s4[cc] = sx;
            }
            __builtin_amdgcn_s_setprio(0);

            // causal mask; rows ir = iw + quad*4 + r, cols j0 + cc*16 + l16
            float sv[4][4];
#pragma unroll
            for (int cc = 0; cc < 4; ++cc)
#pragma unroll
                for (int r = 0; r < 4; ++r) {
                    int ir = iw + quad * 4 + r;
                    sv[cc][r] = (j0 + cc * 16 + l16 <= ir) ? s4[cc][r] : -1e30f;
                }
            // row max across the 16-lane group
            float tm[4];
#pragma unroll
            for (int r = 0; r < 4; ++r)
                tm[r] = fmaxf(fmaxf(sv[0][r], sv[1][r]), fmaxf(sv[2][r], sv[3][r]));
#pragma unroll
            for (int m = 1; m < 16; m <<= 1)
#pragma unroll
                for (int r = 0; r < 4; ++r) tm[r] = fmaxf(tm[r], __shfl_xor(tm[r], m));
            // defer-max: only rescale when the max grew by > 8
            int small = (tm[0] <= mr[0] + 8.f) && (tm[1] <= mr[1] + 8.f) &&
                        (tm[2] <= mr[2] + 8.f) && (tm[3] <= mr[3] + 8.f);
            if (!__all(small)) {
                float al[4];
#pragma unroll
                for (int r = 0; r < 4; ++r) {
                    float mn = fmaxf(mr[r], tm[r]);
                    al[r] = __expf(mr[r] - mn);
                    mr[r] = mn;
                }
#pragma unroll
                for (int dc = 0; dc < 9; ++dc)
#pragma unroll
                    for (int r = 0; r < 4; ++r) O9[dc][r] *= al[r];
            }
            // P = exp(S - mr)  (bounded by e^8 when deferred)
            float p[4][4];
#pragma unroll
            for (int cc = 0; cc < 4; ++cc)
#pragma unroll
                for (int r = 0; r < 4; ++r)
                    p[cc][r] = __expf(sv[cc][r] - mr[r]);
            // P (C layout) -> LDS -> A-layout frags (k = 0..31, 32..63)
#pragma unroll
            for (int cc = 0; cc < 4; ++cc)
#pragma unroll
                for (int r = 0; r < 4; ++r)
                    lP[w][(quad * 4 + r) * 72 + cc * 16 + l16] = f2b(p[cc][r]);
            short8 pf0 = *(const short8*)&lP[w][l16 * 72 + quad * 8];
            short8 pf1 = *(const short8*)&lP[w][l16 * 72 + 32 + quad * 8];
            // O += P V ; 9th chunk accumulates l via the ones-row
            __builtin_amdgcn_s_setprio(1);
#pragma unroll
            for (int dc = 0; dc < 9; ++dc) {
                short8 vf0 = *(const short8*)&lVt[(dc * 16 + l16) * 72 + quad * 8];
                short8 vf1 = *(const short8*)&lVt[(dc * 16 + l16) * 72 + 32 + quad * 8];
                O9[dc] = __builtin_amdgcn_mfma_f32_16x16x32_bf16(pf0, vf0, O9[dc], 0, 0, 0);
                O9[dc] = __builtin_amdgcn_mfma_f32_16x16x32_bf16(pf1, vf1, O9[dc], 0, 0, 0);
            }
            __builtin_amdgcn_s_setprio(0);
        }
        // epilogue: l lives in O9[8] at col l16==0; broadcast within quad
        float inv[4];
#pragma unroll
        for (int r = 0; r < 4; ++r) {
            float lr = __shfl(O9[8][r], quad * 16);
            inv[r] = 1.f / fmaxf(lr, 1e-30f);
        }
#pragma unroll
        for (int dc = 0; dc < 8; ++dc)
#pragma unroll
            for (int r = 0; r < 4; ++r) {
                int ir = iw + quad * 4 + r;
                atf[((size_t)(b * S_ + ir)) * 2048 + h * 128 + dc * 16 + l16] =
                    (_Float16)cl(O9[dc][r] * inv[r]);
            }
    }
}

// ---------------------------------------------------------------------------
extern "C" void kernel_launch(void* const* d_in, const int* in_sizes, int n_in,
                              void* d_out, int out_size, void* d_ws, size_t ws_size,
                              hipStream_t stream) {
    const float* x     = (const float*)d_in[0];
    const float* cosc  = (const float*)d_in[1];
    const float* sinc  = (const float*)d_in[2];
    const int*   pos   = (const int*)d_in[3];
    // d_in[4] = attn_mask (causal tril) -- implemented analytically
    const float* W_DKV = (const float*)d_in[5];
    const float* W_UK  = (const float*)d_in[6];
    const float* W_UV  = (const float*)d_in[7];
    const float* W_DQ  = (const float*)d_in[8];
    const float* W_UQ  = (const float*)d_in[9];
    const float* W_KR  = (const float*)d_in[10];
    const float* W_QR  = (const float*)d_in[11];
    const float* W_O   = (const float*)d_in[12];
    (void)ws_size;

    float* outp      = (float*)d_out;            // [B,S,2048]
    float* ckv_out   = outp + 8388608;           // [B,S,512]
    float* krope_out = outp + 10485760;          // [B,NKV,S,64]

    // ---- workspace (~128 MB) ----
    char* w = (char*)d_ws;
    auto alloc = [&](size_t bytes) { char* p = w; w += bytes; return p; };
    _Float16* xf   = (_Float16*)alloc(16777216);  // x fp16 [4096][2048]
    _Float16* ckf  = (_Float16*)alloc(4194304);   // c_kv fp16 [4096][512]
    float*    krr  = (float*)alloc(4194304);      // K-rope raw fp32 [4096][256]
    _Float16* dqc  = (_Float16*)alloc(12582912);  // c_q fp16 [4096][1536]
    _Float16* qrf  = (_Float16*)alloc(8388608);   // q_rope_raw fp16 [4096][1024]
    u16*      qb16 = (u16*)alloc(25165824);       // Q bf16 pre-scaled [4096][16][192]
    u16*      Kp   = (u16*)alloc(6291456);        // [8][2048][192] bf16
    u16*      Vt   = (u16*)alloc(4194304);        // [8][128][2048] bf16
    _Float16* atf  = (_Float16*)alloc(16777216);  // attn out fp16 [4096][2048]
    _Float16* Wmeg = (_Float16*)alloc(13631488);  // [3328][2048] (DKV|KR|DQ|QR)
    _Float16* Wuq  = (_Float16*)alloc(6291456);   // [2048][1536]
    _Float16* Wukv = (_Float16*)alloc(1048576);   // [1024][512]  (UK|UV)
    _Float16* Wo   = (_Float16*)alloc(8388608);   // [2048][2048]

    const float sc = 0.07216878364870322f;        // 1/sqrt(192)

    // input / weight prep: ONE launch (8 transposes + x->fp16)
    prep_all<<<18432, dim3(32, 8), 0, stream>>>(x, xf,
                                                W_DKV, W_KR, W_DQ, W_QR,
                                                W_UQ, W_UK, W_UV, W_O,
                                                Wmeg, Wuq, Wukv, Wo);

    // mega projection: c_kv (Output 1) | ckf | K-rope-raw | c_q | q-rope-raw
    gemm_f16<<<dim3(26, 32), 256, 0, stream>>>(xf, 2048, Wmeg,
                                               ckv_out, ckf, krr, dqc, qrf,
                                               1.f, 6, 3328, 2048);
    // Q content (mode 2) + K content | V pack (mode 3), heterogeneous dispatch
    gemm_uqkv<<<dim3(24, 32), 256, 0, stream>>>(dqc, Wuq, qb16, sc,
                                                ckf, Wukv, Kp, Vt);

    // rope (merged): Q -> qb16 cols 128..191; K -> Output 2 + Kp cols 128..191
    rope_all<<<10240, 256, 0, stream>>>(qrf, krr, cosc, sinc, pos,
                                        qb16, krope_out, Kp);

    // attention + output projection
    attn_mfma<<<512, 256, 0, stream>>>(qb16, Kp, Vt, atf);
    gemm_f16<<<dim3(16, 32), 256, 0, stream>>>(atf, 2048, Wo,
                                               outp, nullptr, nullptr, nullptr, nullptr,
                                               1.f, 0, 2048, 2048);
}

// Round 11
// 482.475 us; speedup vs baseline: 1.1605x; 1.0034x over previous
//
#include <hip/hip_runtime.h>
#include <stdint.h>

typedef unsigned short u16;
typedef unsigned int u32;

// Problem constants
#define B_    2
#define S_    2048
#define NQ_   16
#define NKV_  4
#define DH_   128
#define DR_   64
#define DT_   192
#define M_    4096   // B_*S_

using short8 = __attribute__((ext_vector_type(8))) short;
using f32x4  = __attribute__((ext_vector_type(4))) float;
using half8  = __attribute__((ext_vector_type(8))) _Float16;
using u16x4  = __attribute__((ext_vector_type(4))) u16;

__device__ __forceinline__ float cl(float f) {   // clamp diagnostic: inf/NaN -> +-3.38e38 signature
    return fminf(fmaxf(f, -3.38e38f), 3.38e38f);
}
__device__ __forceinline__ u16 f2b(float f) {    // fp32 -> bf16 RNE
    union { float f; u32 u; } v; v.f = f;
    u32 u = v.u;
    return (u16)((u + 0x7fffu + ((u >> 16) & 1u)) >> 16);
}
// async global->LDS, 16B per lane. LDS dest is wave-uniform base + lane*16.
__device__ __forceinline__ void gload16(const void* g, void* l) {
    __builtin_amdgcn_global_load_lds(
        (const __attribute__((address_space(1))) void*)g,
        (__attribute__((address_space(3))) void*)l,
        16, 0, 0);
}

// ---------------------------------------------------------------------------
// prep_all: ONE launch for all weight transposes + x->fp16. [verified r9/r10]
// block (32,8); flat-id range decode (all shapes compile-time).
// ---------------------------------------------------------------------------
__device__ __forceinline__ void wt_body(const float* __restrict__ W,
                                        _Float16* __restrict__ T,
                                        int K, int N, int kx, int ny,
                                        float (*tile)[33]) {
    int k0 = kx * 32, n0 = ny * 32;
    int tx = threadIdx.x, ty = threadIdx.y;
#pragma unroll
    for (int i = 0; i < 32; i += 8)
        tile[ty + i][tx] = W[(size_t)(k0 + ty + i) * N + n0 + tx];
    __syncthreads();
#pragma unroll
    for (int i = 0; i < 32; i += 8)
        T[(size_t)(n0 + ty + i) * K + k0 + tx] = (_Float16)tile[tx][ty + i];
}

__global__ __launch_bounds__(256) void prep_all(const float* __restrict__ x,
                                                _Float16* __restrict__ xf,
                                                const float* __restrict__ W_DKV,
                                                const float* __restrict__ W_KR,
                                                const float* __restrict__ W_DQ,
                                                const float* __restrict__ W_QR,
                                                const float* __restrict__ W_UQ,
                                                const float* __restrict__ W_UK,
                                                const float* __restrict__ W_UV,
                                                const float* __restrict__ W_O,
                                                _Float16* __restrict__ Wmeg,
                                                _Float16* __restrict__ Wuq,
                                                _Float16* __restrict__ Wukv,
                                                _Float16* __restrict__ Wo) {
    __shared__ float tile[32][33];
    const int id = blockIdx.x;
    if (id < 1024) {
        wt_body(W_DKV, Wmeg, 2048, 512, id & 63, id >> 6, tile);
    } else if (id < 1536) {
        int l = id - 1024;
        wt_body(W_KR, Wmeg + (size_t)512 * 2048, 2048, 256, l & 63, l >> 6, tile);
    } else if (id < 4608) {
        int l = id - 1536;
        wt_body(W_DQ, Wmeg + (size_t)768 * 2048, 2048, 1536, l & 63, l >> 6, tile);
    } else if (id < 6656) {
        int l = id - 4608;
        wt_body(W_QR, Wmeg + (size_t)2304 * 2048, 2048, 1024, l & 63, l >> 6, tile);
    } else if (id < 9728) {
        int l = id - 6656;
        wt_body(W_UQ, Wuq, 1536, 2048, l % 48, l / 48, tile);
    } else if (id < 9984) {
        int l = id - 9728;
        wt_body(W_UK, Wukv, 512, 512, l & 15, l >> 4, tile);
    } else if (id < 10240) {
        int l = id - 9984;
        wt_body(W_UV, Wukv + (size_t)512 * 512, 512, 512, l & 15, l >> 4, tile);
    } else if (id < 14336) {
        int l = id - 10240;
        wt_body(W_O, Wo, 2048, 2048, l & 63, l >> 6, tile);
    } else {
        int l = id - 14336;
        int t1 = threadIdx.y * 32 + threadIdx.x;
        size_t i = ((size_t)l * 256 + t1) * 8;
        float4 a = *(const float4*)(x + i);
        float4 b4 = *(const float4*)(x + i + 4);
        float va[8] = {a.x, a.y, a.z, a.w, b4.x, b4.y, b4.z, b4.w};
        half8 f;
#pragma unroll
        for (int j = 0; j < 8; ++j) f[j] = (_Float16)va[j];
        *(half8*)(xf + i) = f;
    }
}

// ---------------------------------------------------------------------------
// 128-tile fp16 MFMA GEMM (kept for the small UKV GEMM). [verified r3-r10]
// mode 3: p0 = Kp bf16 [g][s][192] cols 0..127 (n<512);
//         p1 = Vt bf16 [g][d][2048]           (n>=512) -- fused K/V pack
// ---------------------------------------------------------------------------
__device__ __forceinline__ void gemm_body(const _Float16* __restrict__ A, int lda,
                                          const _Float16* __restrict__ Bt,
                                          void* p0, void* p1,
                                          float cscale, int mode,
                                          int N, int K, int bx,
                                          _Float16* lA, _Float16* lB) {
    const int t = threadIdx.x, lane = t & 63, w = t >> 6;
    const int quad = lane >> 4, l16 = lane & 15;
    const int wr = w >> 1, wc = w & 1;
    const int m0 = blockIdx.y * 128, n0 = bx * 128;
    f32x4 acc[4][4] = {};

    for (int kt = 0; kt < K; kt += 32) {
        __syncthreads();
#pragma unroll
        for (int c = 0; c < 2; ++c) {
            const int chunk = c * 256 + t;
            const int row = chunk >> 2, co = (chunk & 3) * 8;
            const int lofs = (c * 256 + w * 64) * 8;   // fp16 units, wave-uniform
            gload16(A + (size_t)(m0 + row) * lda + kt + co, lA + lofs);
            gload16(Bt + (size_t)(n0 + row) * K + kt + co, lB + lofs);
        }
        __syncthreads();
        half8 af[4], bf4[4];
#pragma unroll
        for (int i = 0; i < 4; ++i) {
            af[i]  = *(const half8*)&lA[(wr * 64 + i * 16 + l16) * 32 + quad * 8];
            bf4[i] = *(const half8*)&lB[(wc * 64 + i * 16 + l16) * 32 + quad * 8];
        }
#pragma unroll
        for (int i = 0; i < 4; ++i)
#pragma unroll
            for (int j = 0; j < 4; ++j)
                acc[i][j] = __builtin_amdgcn_mfma_f32_16x16x32_f16(af[i], bf4[j], acc[i][j], 0, 0, 0);
    }
#pragma unroll
    for (int i = 0; i < 4; ++i)
#pragma unroll
        for (int j = 0; j < 4; ++j) {
            const int mbase = m0 + wr * 64 + i * 16 + quad * 4;
            const int nn = n0 + wc * 64 + j * 16 + l16;
            if (mode == 3) {
                const int bb = mbase >> 11, s = mbase & 2047;
                if (nn < 512) {
                    u16* Kp = (u16*)p0;
                    const int kv = nn >> 7, d = nn & 127;
                    const size_t rb = ((size_t)((bb * 4 + kv) * 2048 + s)) * 192 + d;
#pragma unroll
                    for (int r = 0; r < 4; ++r)
                        Kp[rb + (size_t)r * 192] = f2b(acc[i][j][r]);
                } else {
                    u16* Vt = (u16*)p1;
                    const int e = nn - 512, kv = e >> 7, d = e & 127;
                    u16x4 pk;
                    pk[0] = f2b(acc[i][j][0]); pk[1] = f2b(acc[i][j][1]);
                    pk[2] = f2b(acc[i][j][2]); pk[3] = f2b(acc[i][j][3]);
                    *(u16x4*)&((u16*)Vt)[((size_t)((bb * 4 + kv) * 128 + d)) * 2048 + s] = pk;
                }
            } else {   // mode 0 fallback (unused in current launch set)
                float* C = (float*)p0;
#pragma unroll
                for (int r = 0; r < 4; ++r)
                    C[(size_t)(mbase + r) * N + nn] = cl(acc[i][j][r]);
            }
        }
}

__global__ __launch_bounds__(256) void gemm_f16(const _Float16* __restrict__ A, int lda,
                                                const _Float16* __restrict__ Bt,
                                                void* p0, void* p1,
                                                float cscale, int mode,
                                                int N, int K) {
    __shared__ __align__(16) _Float16 lA[128 * 32];
    __shared__ __align__(16) _Float16 lB[128 * 32];
    gemm_body(A, lda, Bt, p0, p1, cscale, mode, N, K, blockIdx.x, lA, lB);
}

// ---------------------------------------------------------------------------
// 256-tile fp16 MFMA GEMM: C = A[M][lda] @ Bt[N][K]^T, fp32 accum.
// 512 thr = 8 waves (2x4); per-wave output 128x64 (acc[8][4]); BK=64;
// single-buffered 64KB LDS; global_load_lds staging; 2-barrier K-loop.
// 2.2x the MFMA-per-barrier of the 128 tile (64 MFMA / 12 ds_read vs 16/8)
// and half the barriers -> m230 anchor ~680 TF vs ~400 observed at 128^2.
// Bank conflicts [G4/rule 21]: BK=64 row stride = 128B -> 16-way conflict if
// linear; fixed by XOR pre-swizzle of the SOURCE column (chunk co` holds
// global col (co`^(row&7))*8, LDS stays linear for gload_lds) + the same XOR
// on ds_read addresses -> 2 lanes/bank (free). Involution verified.
// XCD swizzle [T1]: id&7 = XCD (same mapping verified by attn r5 FETCH drop);
// swz = (id&7)*cpx + id>>3 gives each XCD a contiguous by-range -> A-panel
// L2 locality. nwg%8==0 for all grids used (208/128/128).
// No setprio: m190 showed null-to-negative on lockstep 2-phase GEMM.
// Epilogue modes: 0 = fp32 C (clamped); 2 = qb16 bf16 pre-scaled;
// 6 = mega split (ckv fp32+fp16 | krr fp32 | dqc fp16 | qrf fp16).
// Mode-6 boundaries 512/768/2304 all 256-aligned.
// Layouts [m89/m91 verified]: A-frag A[m=lane&15][k=quad*8+j];
// B-frag B[n=lane&15][k=quad*8+j]; C/D col=lane&15, row=quad*4+reg.
// ---------------------------------------------------------------------------
__global__ __launch_bounds__(512) void gemm256(const _Float16* __restrict__ A, int lda,
                                               const _Float16* __restrict__ Bt,
                                               void* p0, void* p1, void* p2,
                                               void* p3, void* p4,
                                               float cscale, int mode,
                                               int N, int K, int NBX) {
    __shared__ __align__(16) _Float16 lA[256 * 64];
    __shared__ __align__(16) _Float16 lB[256 * 64];
    const int t = threadIdx.x, lane = t & 63, w = t >> 6;   // 8 waves
    const int quad = lane >> 4, l16 = lane & 15;
    const int wr = w >> 2, wc = w & 3;                      // 2 x 4 wave grid
    const int id = blockIdx.x;
    const int cpx = (NBX * 16) >> 3;
    const int swz = (id & 7) * cpx + (id >> 3);
    const int bx = swz % NBX, by = swz / NBX;
    const int m0 = by * 256, n0 = bx * 256;
    f32x4 acc[8][4] = {};

    for (int kt = 0; kt < K; kt += 64) {
        __syncthreads();
        // stage A,B: 256 rows x 64 fp16 = 2048 x 16B chunks each, 4+4/thread
#pragma unroll
        for (int q = 0; q < 4; ++q) {
            const int chunk = q * 512 + t;
            const int row = chunk >> 3, cop = chunk & 7;
            const int co = (cop ^ (row & 7)) * 8;           // source pre-swizzle
            const int lofs = (q * 512 + w * 64) * 8;        // fp16 units, wave-uniform
            gload16(A + (size_t)(m0 + row) * lda + kt + co, lA + lofs);
            gload16(Bt + (size_t)(n0 + row) * K + kt + co, lB + lofs);
        }
        __syncthreads();
#pragma unroll
        for (int kc = 0; kc < 2; ++kc) {
            half8 af[8], bf[4];
#pragma unroll
            for (int i = 0; i < 8; ++i) {
                const int r = wr * 128 + i * 16 + l16;
                af[i] = *(const half8*)&lA[(r * 8 + ((kc * 4 + quad) ^ (r & 7))) * 8];
            }
#pragma unroll
            for (int j = 0; j < 4; ++j) {
                const int r = wc * 64 + j * 16 + l16;
                bf[j] = *(const half8*)&lB[(r * 8 + ((kc * 4 + quad) ^ (r & 7))) * 8];
            }
#pragma unroll
            for (int i = 0; i < 8; ++i)
#pragma unroll
                for (int j = 0; j < 4; ++j)
                    acc[i][j] = __builtin_amdgcn_mfma_f32_16x16x32_f16(af[i], bf[j], acc[i][j], 0, 0, 0);
        }
    }
#pragma unroll
    for (int i = 0; i < 8; ++i)
#pragma unroll
        for (int j = 0; j < 4; ++j) {
            const int mbase = m0 + wr * 128 + i * 16 + quad * 4;
            const int nn = n0 + wc * 64 + j * 16 + l16;
            if (mode == 0) {
                float* C = (float*)p0;
#pragma unroll
                for (int r = 0; r < 4; ++r)
                    C[(size_t)(mbase + r) * N + nn] = cl(acc[i][j][r]);
            } else if (mode == 2) {
                u16* Q = (u16*)p0;
                const int h = nn >> 7, dcol = nn & 127;
#pragma unroll
                for (int r = 0; r < 4; ++r)
                    Q[(size_t)(mbase + r) * 3072 + h * 192 + dcol] =
                        f2b(acc[i][j][r] * cscale);
            } else {   // mode 6: mega projection split
                if (nn < 512) {
                    float* ckv = (float*)p0;
                    _Float16* ckf = (_Float16*)p1;
#pragma unroll
                    for (int r = 0; r < 4; ++r) {
                        float v = acc[i][j][r];
                        ckv[(size_t)(mbase + r) * 512 + nn] = cl(v);
                        ckf[(size_t)(mbase + r) * 512 + nn] = (_Float16)v;
                    }
                } else if (nn < 768) {
                    float* krr = (float*)p2;
#pragma unroll
                    for (int r = 0; r < 4; ++r)
                        krr[(size_t)(mbase + r) * 256 + (nn - 512)] = acc[i][j][r];
                } else if (nn < 2304) {
                    _Float16* dqc = (_Float16*)p3;
#pragma unroll
                    for (int r = 0; r < 4; ++r)
                        dqc[(size_t)(mbase + r) * 1536 + (nn - 768)] = (_Float16)acc[i][j][r];
                } else {
                    _Float16* qrf = (_Float16*)p4;
#pragma unroll
                    for (int r = 0; r < 4; ++r)
                        qrf[(size_t)(mbase + r) * 1024 + (nn - 2304)] = (_Float16)acc[i][j][r];
                }
            }
        }
}

// ---------------------------------------------------------------------------
// Merged RoPE (one launch). Blocks 0..8191: Q rope -- qrf fp16 [(b,s)][1024]
// -> qb16 bf16 [(b,s)][h*192+128+d], pre-scaled by 1/sqrt(192).
// Blocks 8192..10239: K rope -- krr fp32 [(b,s)][256] -> Krope fp32 (Output 2)
// + Kp bf16 cols 128..191. Math byte-identical to the split kernels [r3-r10].
// ---------------------------------------------------------------------------
__global__ __launch_bounds__(256) void rope_all(const _Float16* __restrict__ qrf,
                                                const float* __restrict__ krr,
                                                const float* __restrict__ cosc,
                                                const float* __restrict__ sinc,
                                                const int* __restrict__ pos,
                                                u16* __restrict__ qb16,
                                                float* __restrict__ Krope,
                                                u16* __restrict__ Kp) {
    const float sc = 0.07216878364870322f;           // 1/sqrt(192)
    if ((int)blockIdx.x < 8192) {
        int t = blockIdx.x * 256 + threadIdx.x;      // t < 4096*16*32
        int d = t & 31, h = (t >> 5) & 15, rowi = t >> 9;
        int s = rowi & 2047;
        int p = pos[s];
        float c1 = cosc[p * 64 + d],      s1 = sinc[p * 64 + d];
        float c2 = cosc[p * 64 + 32 + d], s2 = sinc[p * 64 + 32 + d];
        const _Float16* base = qrf + (size_t)rowi * 1024 + h * 64;
        float x1 = (float)base[d];
        float x2 = (float)base[d + 32];
        u16* q = qb16 + (size_t)rowi * 3072 + h * 192 + 128;
        q[d]      = f2b((x1 * c1 - x2 * s1) * sc);
        q[d + 32] = f2b((x2 * c2 + x1 * s2) * sc);
    } else {
        int t = (blockIdx.x - 8192) * 256 + threadIdx.x;   // t < 4096*4*32
        int d = t & 31, kv = (t >> 5) & 3, rowi = t >> 7;
        int b = rowi >> 11, s = rowi & 2047;
        int p = pos[s];
        float c1 = cosc[p * 64 + d],      s1 = sinc[p * 64 + d];
        float c2 = cosc[p * 64 + 32 + d], s2 = sinc[p * 64 + 32 + d];
        float x1 = krr[(size_t)rowi * 256 + kv * 64 + d];
        float x2 = krr[(size_t)rowi * 256 + kv * 64 + 32 + d];
        float o1 = x1 * c1 - x2 * s1;
        float o2 = x2 * c2 + x1 * s2;
        int g = b * NKV_ + kv;
        size_t ob = ((size_t)(g * S_) + s) * 64;
        Krope[ob + d]      = cl(o1);
        Krope[ob + 32 + d] = cl(o2);
        u16* kp = Kp + ((size_t)(g * S_ + s)) * 192 + 128;
        kp[d]      = f2b(o1);
        kp[32 + d] = f2b(o2);
    }
}

// ---------------------------------------------------------------------------
// MFMA flash attention -- EXACT r5 version (109us, VGPR 116, occ 20.4%).
// [r6-r9 post-mortem: mask-skip conditional correlated with VGPR 116->132
// and halved occupancy; three rewrites + launch_bounds failed to undo it.
// DO NOT reintroduce conditional-mask or reg-prefetch variants.]
// Block = 4 waves = 64 q-rows of one (b,h). Paired q-tiles: qt = 31-px then
// px -> 33 kv-tile units per block, uniform. Flat grid 512; id&7 == g puts
// each KV group's 64 blocks on one XCD (K/V ~1.3MB L2-resident; FETCH
// 48.8->17.7MB, r5). Row-sum l via bf16-ones d-row: PV's 9th n-chunk
// accumulates l into O9[8]. Defer-max (T13, THR=8).
// ---------------------------------------------------------------------------
__global__ __launch_bounds__(256) void attn_mfma(const u16* __restrict__ qb16,
                                                 const u16* __restrict__ Kp,
                                                 const u16* __restrict__ Vt,
                                                 _Float16* __restrict__ atf) {
    __shared__ __align__(16) u16 lK[64 * 200];     // 64 kv-rows x 192 (+8 pad)
    __shared__ __align__(16) u16 lVt[144 * 72];    // 128 d-rows + 16 (ones) x 64 (+8 pad)
    __shared__ __align__(16) u16 lP[4][16 * 72];   // per-wave P 16x64 (+8 pad)

    const int t = threadIdx.x, lane = t & 63, w = t >> 6;
    const int quad = lane >> 4, l16 = lane & 15;
    const int id = blockIdx.x;                     // 0..511
    const int g = id & 7;                          // (b*4 + kv)
    const int b = g >> 2;
    const int k = id >> 3;                         // 0..63
    const int h = (g & 3) * 4 + (k & 3);
    const int px = k >> 2;                         // 0..15

    // ones-row init for the l-column trick (rows 128..143, cols 0..63)
#pragma unroll
    for (int c = 0; c < 4; ++c) {
        int i = c * 256 + t;                       // 0..1023
        int rr = 128 + (i >> 6), ccol = i & 63;
        lVt[rr * 72 + ccol] = (rr == 128) ? (u16)0x3F80 : (u16)0;
    }

    for (int ph = 0; ph < 2; ++ph) {
        const int qt = ph ? px : (31 - px);        // heavy tile first
        const int q0 = qt * 64;
        const int iw = q0 + w * 16;                // wave's q-row base

        short8 qf[6];
        {
            const u16* qp = qb16 + ((size_t)(b * S_ + iw + l16)) * 3072 + h * 192;
#pragma unroll
            for (int kc = 0; kc < 6; ++kc)
                qf[kc] = *(const short8*)&qp[kc * 32 + quad * 8];
        }

        f32x4 O9[9] = {};                          // [0..7]=O d-chunks, [8]=l (col l16==0)
        float mr[4] = {-1e30f, -1e30f, -1e30f, -1e30f};

        const int ntile = qt + 1;
        for (int tile = 0; tile < ntile; ++tile) {
            const int j0 = tile * 64;
            __syncthreads();
            // stage K tile: 64 rows x 192 u16 = 1536 x 16B, 6/thread
#pragma unroll
            for (int c = 0; c < 6; ++c) {
                int seg = c * 256 + t;
                int row = seg / 24, ch = (seg % 24) * 8;
                *(uint4*)&lK[row * 200 + ch] =
                    *(const uint4*)&Kp[((size_t)g * S_ + j0 + row) * 192 + ch];
            }
            // stage Vt tile: 128 d-rows x 64 u16 = 1024 x 16B, 4/thread
#pragma unroll
            for (int c = 0; c < 4; ++c) {
                int seg = c * 256 + t;
                int d = seg >> 3, ch = (seg & 7) * 8;
                *(uint4*)&lVt[d * 72 + ch] =
                    *(const uint4*)&Vt[((size_t)g * 128 + d) * S_ + j0 + ch];
            }
            __syncthreads();

            // S = Q K^T, four 16-col chunks
            f32x4 s4[4];
            __builtin_amdgcn_s_setprio(1);
#pragma unroll
            for (int cc = 0; cc < 4; ++cc) {
                f32x4 sx = {};
#pragma unroll
                for (int kc = 0; kc < 6; ++kc) {
                    short8 kf = *(const short8*)&lK[(cc * 16 + l16) * 200 + kc * 32 + quad * 8];
                    sx = __builtin_amdgcn_mfma_f32_16x16x32_bf16(qf[kc], kf, sx, 0, 0, 0);
                }
                s4[cc] = sx;
            }
            __builtin_amdgcn_s_setprio(0);

            // causal mask; rows ir = iw + quad*4 + r, cols j0 + cc*16 + l16
            float sv[4][4];
#pragma unroll
            for (int cc = 0; cc < 4; ++cc)
#pragma unroll
                for (int r = 0; r < 4; ++r) {
                    int ir = iw + quad * 4 + r;
                    sv[cc][r] = (j0 + cc * 16 + l16 <= ir) ? s4[cc][r] : -1e30f;
                }
            // row max across the 16-lane group
            float tm[4];
#pragma unroll
            for (int r = 0; r < 4; ++r)
                tm[r] = fmaxf(fmaxf(sv[0][r], sv[1][r]), fmaxf(sv[2][r], sv[3][r]));
#pragma unroll
            for (int m = 1; m < 16; m <<= 1)
#pragma unroll
                for (int r = 0; r < 4; ++r) tm[r] = fmaxf(tm[r], __shfl_xor(tm[r], m));
            // defer-max: only rescale when the max grew by > 8
            int small = (tm[0] <= mr[0] + 8.f) && (tm[1] <= mr[1] + 8.f) &&
                        (tm[2] <= mr[2] + 8.f) && (tm[3] <= mr[3] + 8.f);
            if (!__all(small)) {
                float al[4];
#pragma unroll
                for (int r = 0; r < 4; ++r) {
                    float mn = fmaxf(mr[r], tm[r]);
                    al[r] = __expf(mr[r] - mn);
                    mr[r] = mn;
                }
#pragma unroll
                for (int dc = 0; dc < 9; ++dc)
#pragma unroll
                    for (int r = 0; r < 4; ++r) O9[dc][r] *= al[r];
            }
            // P = exp(S - mr)  (bounded by e^8 when deferred)
            float p[4][4];
#pragma unroll
            for (int cc = 0; cc < 4; ++cc)
#pragma unroll
                for (int r = 0; r < 4; ++r)
                    p[cc][r] = __expf(sv[cc][r] - mr[r]);
            // P (C layout) -> LDS -> A-layout frags (k = 0..31, 32..63)
#pragma unroll
            for (int cc = 0; cc < 4; ++cc)
#pragma unroll
                for (int r = 0; r < 4; ++r)
                    lP[w][(quad * 4 + r) * 72 + cc * 16 + l16] = f2b(p[cc][r]);
            short8 pf0 = *(const short8*)&lP[w][l16 * 72 + quad * 8];
            short8 pf1 = *(const short8*)&lP[w][l16 * 72 + 32 + quad * 8];
            // O += P V ; 9th chunk accumulates l via the ones-row
            __builtin_amdgcn_s_setprio(1);
#pragma unroll
            for (int dc = 0; dc < 9; ++dc) {
                short8 vf0 = *(const short8*)&lVt[(dc * 16 + l16) * 72 + quad * 8];
                short8 vf1 = *(const short8*)&lVt[(dc * 16 + l16) * 72 + 32 + quad * 8];
                O9[dc] = __builtin_amdgcn_mfma_f32_16x16x32_bf16(pf0, vf0, O9[dc], 0, 0, 0);
                O9[dc] = __builtin_amdgcn_mfma_f32_16x16x32_bf16(pf1, vf1, O9[dc], 0, 0, 0);
            }
            __builtin_amdgcn_s_setprio(0);
        }
        // epilogue: l lives in O9[8] at col l16==0; broadcast within quad
        float inv[4];
#pragma unroll
        for (int r = 0; r < 4; ++r) {
            float lr = __shfl(O9[8][r], quad * 16);
            inv[r] = 1.f / fmaxf(lr, 1e-30f);
        }
#pragma unroll
        for (int dc = 0; dc < 8; ++dc)
#pragma unroll
            for (int r = 0; r < 4; ++r) {
                int ir = iw + quad * 4 + r;
                atf[((size_t)(b * S_ + ir)) * 2048 + h * 128 + dc * 16 + l16] =
                    (_Float16)cl(O9[dc][r] * inv[r]);
            }
    }
}

// ---------------------------------------------------------------------------
extern "C" void kernel_launch(void* const* d_in, const int* in_sizes, int n_in,
                              void* d_out, int out_size, void* d_ws, size_t ws_size,
                              hipStream_t stream) {
    const float* x     = (const float*)d_in[0];
    const float* cosc  = (const float*)d_in[1];
    const float* sinc  = (const float*)d_in[2];
    const int*   pos   = (const int*)d_in[3];
    // d_in[4] = attn_mask (causal tril) -- implemented analytically
    const float* W_DKV = (const float*)d_in[5];
    const float* W_UK  = (const float*)d_in[6];
    const float* W_UV  = (const float*)d_in[7];
    const float* W_DQ  = (const float*)d_in[8];
    const float* W_UQ  = (const float*)d_in[9];
    const float* W_KR  = (const float*)d_in[10];
    const float* W_QR  = (const float*)d_in[11];
    const float* W_O   = (const float*)d_in[12];
    (void)ws_size;

    float* outp      = (float*)d_out;            // [B,S,2048]
    float* ckv_out   = outp + 8388608;           // [B,S,512]
    float* krope_out = outp + 10485760;          // [B,NKV,S,64]

    // ---- workspace (~128 MB) ----
    char* w = (char*)d_ws;
    auto alloc = [&](size_t bytes) { char* p = w; w += bytes; return p; };
    _Float16* xf   = (_Float16*)alloc(16777216);  // x fp16 [4096][2048]
    _Float16* ckf  = (_Float16*)alloc(4194304);   // c_kv fp16 [4096][512]
    float*    krr  = (float*)alloc(4194304);      // K-rope raw fp32 [4096][256]
    _Float16* dqc  = (_Float16*)alloc(12582912);  // c_q fp16 [4096][1536]
    _Float16* qrf  = (_Float16*)alloc(8388608);   // q_rope_raw fp16 [4096][1024]
    u16*      qb16 = (u16*)alloc(25165824);       // Q bf16 pre-scaled [4096][16][192]
    u16*      Kp   = (u16*)alloc(6291456);        // [8][2048][192] bf16
    u16*      Vt   = (u16*)alloc(4194304);        // [8][128][2048] bf16
    _Float16* atf  = (_Float16*)alloc(16777216);  // attn out fp16 [4096][2048]
    _Float16* Wmeg = (_Float16*)alloc(13631488);  // [3328][2048] (DKV|KR|DQ|QR)
    _Float16* Wuq  = (_Float16*)alloc(6291456);   // [2048][1536]
    _Float16* Wukv = (_Float16*)alloc(1048576);   // [1024][512]  (UK|UV)
    _Float16* Wo   = (_Float16*)alloc(8388608);   // [2048][2048]

    const float sc = 0.07216878364870322f;        // 1/sqrt(192)

    // input / weight prep: ONE launch (8 transposes + x->fp16)
    prep_all<<<18432, dim3(32, 8), 0, stream>>>(x, xf,
                                                W_DKV, W_KR, W_DQ, W_QR,
                                                W_UQ, W_UK, W_UV, W_O,
                                                Wmeg, Wuq, Wukv, Wo);

    // mega projection (256-tile): c_kv (Output 1) | ckf | krr | dqc | qrf
    gemm256<<<208, 512, 0, stream>>>(xf, 2048, Wmeg,
                                     ckv_out, ckf, krr, dqc, qrf,
                                     1.f, 6, 3328, 2048, 13);
    // Q content (256-tile, mode 2): dqc @ Wuq^T -> qb16 bf16 pre-scaled
    gemm256<<<128, 512, 0, stream>>>(dqc, 1536, Wuq,
                                     qb16, nullptr, nullptr, nullptr, nullptr,
                                     sc, 2, 2048, 1536, 8);
    // K content | V pack (128-tile, mode 3): ckf @ Wukv^T -> Kp cols 0..127, Vt
    gemm_f16<<<dim3(8, 32), 256, 0, stream>>>(ckf, 512, Wukv,
                                              Kp, Vt, 1.f, 3, 1024, 512);

    // rope (merged): Q -> qb16 cols 128..191; K -> Output 2 + Kp cols 128..191
    rope_all<<<10240, 256, 0, stream>>>(qrf, krr, cosc, sinc, pos,
                                        qb16, krope_out, Kp);

    // attention + output projection (256-tile, mode 0)
    attn_mfma<<<512, 256, 0, stream>>>(qb16, Kp, Vt, atf);
    gemm256<<<128, 512, 0, stream>>>(atf, 2048, Wo,
                                     outp, nullptr, nullptr, nullptr, nullptr,
                                     1.f, 0, 2048, 2048, 8);
}

// Round 12
// 437.735 us; speedup vs baseline: 1.2791x; 1.1022x over previous
//
#include <hip/hip_runtime.h>
#include <stdint.h>

typedef unsigned short u16;
typedef unsigned int u32;

// Problem constants
#define B_    2
#define S_    2048
#define NQ_   16
#define NKV_  4
#define DH_   128
#define DR_   64
#define DT_   192
#define M_    4096   // B_*S_

using short8 = __attribute__((ext_vector_type(8))) short;
using f32x4  = __attribute__((ext_vector_type(4))) float;
using half8  = __attribute__((ext_vector_type(8))) _Float16;
using u16x4  = __attribute__((ext_vector_type(4))) u16;

__device__ __forceinline__ float cl(float f) {   // clamp diagnostic: inf/NaN -> +-3.38e38 signature
    return fminf(fmaxf(f, -3.38e38f), 3.38e38f);
}
__device__ __forceinline__ u16 f2b(float f) {    // fp32 -> bf16 RNE
    union { float f; u32 u; } v; v.f = f;
    u32 u = v.u;
    return (u16)((u + 0x7fffu + ((u >> 16) & 1u)) >> 16);
}
// async global->LDS, 16B per lane. LDS dest is wave-uniform base + lane*16.
__device__ __forceinline__ void gload16(const void* g, void* l) {
    __builtin_amdgcn_global_load_lds(
        (const __attribute__((address_space(1))) void*)g,
        (__attribute__((address_space(3))) void*)l,
        16, 0, 0);
}

// ---------------------------------------------------------------------------
// prep_all: ONE launch for all weight transposes + x->fp16. [verified r9-r11]
// block (32,8); flat-id range decode (all shapes compile-time).
// ---------------------------------------------------------------------------
__device__ __forceinline__ void wt_body(const float* __restrict__ W,
                                        _Float16* __restrict__ T,
                                        int K, int N, int kx, int ny,
                                        float (*tile)[33]) {
    int k0 = kx * 32, n0 = ny * 32;
    int tx = threadIdx.x, ty = threadIdx.y;
#pragma unroll
    for (int i = 0; i < 32; i += 8)
        tile[ty + i][tx] = W[(size_t)(k0 + ty + i) * N + n0 + tx];
    __syncthreads();
#pragma unroll
    for (int i = 0; i < 32; i += 8)
        T[(size_t)(n0 + ty + i) * K + k0 + tx] = (_Float16)tile[tx][ty + i];
}

__global__ __launch_bounds__(256) void prep_all(const float* __restrict__ x,
                                                _Float16* __restrict__ xf,
                                                const float* __restrict__ W_DKV,
                                                const float* __restrict__ W_KR,
                                                const float* __restrict__ W_DQ,
                                                const float* __restrict__ W_QR,
                                                const float* __restrict__ W_UQ,
                                                const float* __restrict__ W_UK,
                                                const float* __restrict__ W_UV,
                                                const float* __restrict__ W_O,
                                                _Float16* __restrict__ Wmeg,
                                                _Float16* __restrict__ Wuq,
                                                _Float16* __restrict__ Wukv,
                                                _Float16* __restrict__ Wo) {
    __shared__ float tile[32][33];
    const int id = blockIdx.x;
    if (id < 1024) {
        wt_body(W_DKV, Wmeg, 2048, 512, id & 63, id >> 6, tile);
    } else if (id < 1536) {
        int l = id - 1024;
        wt_body(W_KR, Wmeg + (size_t)512 * 2048, 2048, 256, l & 63, l >> 6, tile);
    } else if (id < 4608) {
        int l = id - 1536;
        wt_body(W_DQ, Wmeg + (size_t)768 * 2048, 2048, 1536, l & 63, l >> 6, tile);
    } else if (id < 6656) {
        int l = id - 4608;
        wt_body(W_QR, Wmeg + (size_t)2304 * 2048, 2048, 1024, l & 63, l >> 6, tile);
    } else if (id < 9728) {
        int l = id - 6656;
        wt_body(W_UQ, Wuq, 1536, 2048, l % 48, l / 48, tile);
    } else if (id < 9984) {
        int l = id - 9728;
        wt_body(W_UK, Wukv, 512, 512, l & 15, l >> 4, tile);
    } else if (id < 10240) {
        int l = id - 9984;
        wt_body(W_UV, Wukv + (size_t)512 * 512, 512, 512, l & 15, l >> 4, tile);
    } else if (id < 14336) {
        int l = id - 10240;
        wt_body(W_O, Wo, 2048, 2048, l & 63, l >> 6, tile);
    } else {
        int l = id - 14336;
        int t1 = threadIdx.y * 32 + threadIdx.x;
        size_t i = ((size_t)l * 256 + t1) * 8;
        float4 a = *(const float4*)(x + i);
        float4 b4 = *(const float4*)(x + i + 4);
        float va[8] = {a.x, a.y, a.z, a.w, b4.x, b4.y, b4.z, b4.w};
        half8 f;
#pragma unroll
        for (int j = 0; j < 8; ++j) f[j] = (_Float16)va[j];
        *(half8*)(xf + i) = f;
    }
}

// ---------------------------------------------------------------------------
// 128-tile fp16 MFMA GEMM (kept for the small UKV GEMM). [verified r3-r11]
// mode 3: p0 = Kp bf16 [g][s][192] cols 0..127 (n<512);
//         p1 = Vt bf16 [g][d][2048]           (n>=512) -- fused K/V pack
// ---------------------------------------------------------------------------
__device__ __forceinline__ void gemm_body(const _Float16* __restrict__ A, int lda,
                                          const _Float16* __restrict__ Bt,
                                          void* p0, void* p1,
                                          float cscale, int mode,
                                          int N, int K, int bx,
                                          _Float16* lA, _Float16* lB) {
    const int t = threadIdx.x, lane = t & 63, w = t >> 6;
    const int quad = lane >> 4, l16 = lane & 15;
    const int wr = w >> 1, wc = w & 1;
    const int m0 = blockIdx.y * 128, n0 = bx * 128;
    f32x4 acc[4][4] = {};

    for (int kt = 0; kt < K; kt += 32) {
        __syncthreads();
#pragma unroll
        for (int c = 0; c < 2; ++c) {
            const int chunk = c * 256 + t;
            const int row = chunk >> 2, co = (chunk & 3) * 8;
            const int lofs = (c * 256 + w * 64) * 8;   // fp16 units, wave-uniform
            gload16(A + (size_t)(m0 + row) * lda + kt + co, lA + lofs);
            gload16(Bt + (size_t)(n0 + row) * K + kt + co, lB + lofs);
        }
        __syncthreads();
        half8 af[4], bf4[4];
#pragma unroll
        for (int i = 0; i < 4; ++i) {
            af[i]  = *(const half8*)&lA[(wr * 64 + i * 16 + l16) * 32 + quad * 8];
            bf4[i] = *(const half8*)&lB[(wc * 64 + i * 16 + l16) * 32 + quad * 8];
        }
#pragma unroll
        for (int i = 0; i < 4; ++i)
#pragma unroll
            for (int j = 0; j < 4; ++j)
                acc[i][j] = __builtin_amdgcn_mfma_f32_16x16x32_f16(af[i], bf4[j], acc[i][j], 0, 0, 0);
    }
#pragma unroll
    for (int i = 0; i < 4; ++i)
#pragma unroll
        for (int j = 0; j < 4; ++j) {
            const int mbase = m0 + wr * 64 + i * 16 + quad * 4;
            const int nn = n0 + wc * 64 + j * 16 + l16;
            if (mode == 3) {
                const int bb = mbase >> 11, s = mbase & 2047;
                if (nn < 512) {
                    u16* Kp = (u16*)p0;
                    const int kv = nn >> 7, d = nn & 127;
                    const size_t rb = ((size_t)((bb * 4 + kv) * 2048 + s)) * 192 + d;
#pragma unroll
                    for (int r = 0; r < 4; ++r)
                        Kp[rb + (size_t)r * 192] = f2b(acc[i][j][r]);
                } else {
                    u16* Vt = (u16*)p1;
                    const int e = nn - 512, kv = e >> 7, d = e & 127;
                    u16x4 pk;
                    pk[0] = f2b(acc[i][j][0]); pk[1] = f2b(acc[i][j][1]);
                    pk[2] = f2b(acc[i][j][2]); pk[3] = f2b(acc[i][j][3]);
                    *(u16x4*)&((u16*)Vt)[((size_t)((bb * 4 + kv) * 128 + d)) * 2048 + s] = pk;
                }
            } else {   // mode 0 fallback (unused in current launch set)
                float* C = (float*)p0;
#pragma unroll
                for (int r = 0; r < 4; ++r)
                    C[(size_t)(mbase + r) * N + nn] = cl(acc[i][j][r]);
            }
        }
}

__global__ __launch_bounds__(256) void gemm_f16(const _Float16* __restrict__ A, int lda,
                                                const _Float16* __restrict__ Bt,
                                                void* p0, void* p1,
                                                float cscale, int mode,
                                                int N, int K) {
    __shared__ __align__(16) _Float16 lA[128 * 32];
    __shared__ __align__(16) _Float16 lB[128 * 32];
    gemm_body(A, lda, Bt, p0, p1, cscale, mode, N, K, blockIdx.x, lA, lB);
}

// ---------------------------------------------------------------------------
// 128x256 fp16 MFMA GEMM, T3-minimum 2-phase double-buffer [guide recipe].
// C = A[M][lda] @ Bt[N][K]^T, fp32 accum. 512 thr = 8 waves (2x4);
// per-wave output 64x64 (acc[4][4], ~115 VGPR); BK=64; LDS 2 x (16+32)KB=96KB.
// Schedule per K-step: STAGE(buf^1, kt+64) issued FIRST, then ds_read+32 MFMA
// per wave on buf[cur], then ONE __syncthreads() (compiler's auto
// vmcnt(0)+lgkmcnt(0) drain before s_barrier IS the recipe's wait: prefetch
// latency hides under the 256-MFMA compute phase). 4x fewer barriers per
// K-element than the 128^2 2-barrier loop; within-block overlap replaces the
// cross-block overlap lost at 1 block/CU.
// [r11 post-mortem: 256^2 tile made grids 208/128/128 blocks -> half the CUs
// idle on UQ/W_O; this geometry gives 416/256/256.]
// Bank conflicts [G4/rule 21]: BK=64 rows = 128B stride -> XOR pre-swizzle of
// SOURCE column (chunk cop holds global col (cop^(row&7))*8, LDS linear for
// gload_lds) + same XOR on ds_read addrs -> 2 lanes/bank (free). [verified
// r11: absmax unchanged]
// XCD swizzle [T1]: swz=(id&7)*cpx+id>>3; all grids %8==0 (416/256/256).
// No setprio (m190: null-to-negative on lockstep GEMM).
// Epilogue modes: 0 = fp32 C (cl); 2 = qb16 bf16 pre-scaled; 6 = mega split.
// Mode-6 boundaries 512/768/2304 are 256-aligned -> every tile region-pure.
// Layouts [m89/m91 verified]: A-frag A[m=lane&15][k=quad*8+j];
// B-frag B[n=lane&15][k=quad*8+j]; C/D col=lane&15, row=quad*4+reg.
// ---------------------------------------------------------------------------
__global__ __launch_bounds__(512) void gemm2ph(const _Float16* __restrict__ A, int lda,
                                               const _Float16* __restrict__ Bt,
                                               void* p0, void* p1, void* p2,
                                               void* p3, void* p4,
                                               float cscale, int mode,
                                               int N, int K, int NBX) {
    __shared__ __align__(16) _Float16 lA[2][128 * 64];
    __shared__ __align__(16) _Float16 lB[2][256 * 64];
    const int t = threadIdx.x, lane = t & 63, w = t >> 6;   // 8 waves
    const int quad = lane >> 4, l16 = lane & 15;
    const int wr = w >> 2, wc = w & 3;                      // 2 x 4 wave grid
    const int id = blockIdx.x;
    const int cpx = (NBX * 32) >> 3;                        // nwg = NBX*32
    const int swz = (id & 7) * cpx + (id >> 3);
    const int bx = swz % NBX, by = swz / NBX;
    const int m0 = by * 128, n0 = bx * 256;
    f32x4 acc[4][4] = {};

    auto STAGE = [&](int buf, int kt) {
        // A: 128x64 = 1024 x16B chunks, 2/thread; B: 256x64 = 2048, 4/thread
#pragma unroll
        for (int q = 0; q < 2; ++q) {
            const int chunk = q * 512 + t;
            const int row = chunk >> 3, cop = chunk & 7;
            const int co = (cop ^ (row & 7)) * 8;           // source pre-swizzle
            gload16(A + (size_t)(m0 + row) * lda + kt + co,
                    lA[buf] + (q * 512 + w * 64) * 8);
        }
#pragma unroll
        for (int q = 0; q < 4; ++q) {
            const int chunk = q * 512 + t;
            const int row = chunk >> 3, cop = chunk & 7;
            const int co = (cop ^ (row & 7)) * 8;
            gload16(Bt + (size_t)(n0 + row) * K + kt + co,
                    lB[buf] + (q * 512 + w * 64) * 8);
        }
    };

    STAGE(0, 0);
    __syncthreads();
    int cur = 0;
    for (int kt = 0; kt < K; kt += 64) {
        if (kt + 64 < K) STAGE(cur ^ 1, kt + 64);           // prefetch next
        const _Float16* bufA = lA[cur];
        const _Float16* bufB = lB[cur];
#pragma unroll
        for (int kc = 0; kc < 2; ++kc) {
            half8 af[4], bf[4];
#pragma unroll
            for (int i = 0; i < 4; ++i) {
                const int r = wr * 64 + i * 16 + l16;
                af[i] = *(const half8*)&bufA[(r * 8 + ((kc * 4 + quad) ^ (r & 7))) * 8];
            }
#pragma unroll
            for (int j = 0; j < 4; ++j) {
                const int r = wc * 64 + j * 16 + l16;
                bf[j] = *(const half8*)&bufB[(r * 8 + ((kc * 4 + quad) ^ (r & 7))) * 8];
            }
#pragma unroll
            for (int i = 0; i < 4; ++i)
#pragma unroll
                for (int j = 0; j < 4; ++j)
                    acc[i][j] = __builtin_amdgcn_mfma_f32_16x16x32_f16(af[i], bf[j], acc[i][j], 0, 0, 0);
        }
        __syncthreads();                                    // drains prefetch + reads
        cur ^= 1;
    }
#pragma unroll
    for (int i = 0; i < 4; ++i)
#pragma unroll
        for (int j = 0; j < 4; ++j) {
            const int mbase = m0 + wr * 64 + i * 16 + quad * 4;
            const int nn = n0 + wc * 64 + j * 16 + l16;
            if (mode == 0) {
                float* C = (float*)p0;
#pragma unroll
                for (int r = 0; r < 4; ++r)
                    C[(size_t)(mbase + r) * N + nn] = cl(acc[i][j][r]);
            } else if (mode == 2) {
                u16* Q = (u16*)p0;
                const int h = nn >> 7, dcol = nn & 127;
#pragma unroll
                for (int r = 0; r < 4; ++r)
                    Q[(size_t)(mbase + r) * 3072 + h * 192 + dcol] =
                        f2b(acc[i][j][r] * cscale);
            } else {   // mode 6: mega projection split
                if (nn < 512) {
                    float* ckv = (float*)p0;
                    _Float16* ckf = (_Float16*)p1;
#pragma unroll
                    for (int r = 0; r < 4; ++r) {
                        float v = acc[i][j][r];
                        ckv[(size_t)(mbase + r) * 512 + nn] = cl(v);
                        ckf[(size_t)(mbase + r) * 512 + nn] = (_Float16)v;
                    }
                } else if (nn < 768) {
                    float* krr = (float*)p2;
#pragma unroll
                    for (int r = 0; r < 4; ++r)
                        krr[(size_t)(mbase + r) * 256 + (nn - 512)] = acc[i][j][r];
                } else if (nn < 2304) {
                    _Float16* dqc = (_Float16*)p3;
#pragma unroll
                    for (int r = 0; r < 4; ++r)
                        dqc[(size_t)(mbase + r) * 1536 + (nn - 768)] = (_Float16)acc[i][j][r];
                } else {
                    _Float16* qrf = (_Float16*)p4;
#pragma unroll
                    for (int r = 0; r < 4; ++r)
                        qrf[(size_t)(mbase + r) * 1024 + (nn - 2304)] = (_Float16)acc[i][j][r];
                }
            }
        }
}

// ---------------------------------------------------------------------------
// Merged RoPE (one launch). Blocks 0..8191: Q rope -- qrf fp16 [(b,s)][1024]
// -> qb16 bf16 [(b,s)][h*192+128+d], pre-scaled by 1/sqrt(192).
// Blocks 8192..10239: K rope -- krr fp32 [(b,s)][256] -> Krope fp32 (Output 2)
// + Kp bf16 cols 128..191. Math byte-identical to the split kernels [r3-r11].
// ---------------------------------------------------------------------------
__global__ __launch_bounds__(256) void rope_all(const _Float16* __restrict__ qrf,
                                                const float* __restrict__ krr,
                                                const float* __restrict__ cosc,
                                                const float* __restrict__ sinc,
                                                const int* __restrict__ pos,
                                                u16* __restrict__ qb16,
                                                float* __restrict__ Krope,
                                                u16* __restrict__ Kp) {
    const float sc = 0.07216878364870322f;           // 1/sqrt(192)
    if ((int)blockIdx.x < 8192) {
        int t = blockIdx.x * 256 + threadIdx.x;      // t < 4096*16*32
        int d = t & 31, h = (t >> 5) & 15, rowi = t >> 9;
        int s = rowi & 2047;
        int p = pos[s];
        float c1 = cosc[p * 64 + d],      s1 = sinc[p * 64 + d];
        float c2 = cosc[p * 64 + 32 + d], s2 = sinc[p * 64 + 32 + d];
        const _Float16* base = qrf + (size_t)rowi * 1024 + h * 64;
        float x1 = (float)base[d];
        float x2 = (float)base[d + 32];
        u16* q = qb16 + (size_t)rowi * 3072 + h * 192 + 128;
        q[d]      = f2b((x1 * c1 - x2 * s1) * sc);
        q[d + 32] = f2b((x2 * c2 + x1 * s2) * sc);
    } else {
        int t = (blockIdx.x - 8192) * 256 + threadIdx.x;   // t < 4096*4*32
        int d = t & 31, kv = (t >> 5) & 3, rowi = t >> 7;
        int b = rowi >> 11, s = rowi & 2047;
        int p = pos[s];
        float c1 = cosc[p * 64 + d],      s1 = sinc[p * 64 + d];
        float c2 = cosc[p * 64 + 32 + d], s2 = sinc[p * 64 + 32 + d];
        float x1 = krr[(size_t)rowi * 256 + kv * 64 + d];
        float x2 = krr[(size_t)rowi * 256 + kv * 64 + 32 + d];
        float o1 = x1 * c1 - x2 * s1;
        float o2 = x2 * c2 + x1 * s2;
        int g = b * NKV_ + kv;
        size_t ob = ((size_t)(g * S_) + s) * 64;
        Krope[ob + d]      = cl(o1);
        Krope[ob + 32 + d] = cl(o2);
        u16* kp = Kp + ((size_t)(g * S_ + s)) * 192 + 128;
        kp[d]      = f2b(o1);
        kp[32 + d] = f2b(o2);
    }
}

// ---------------------------------------------------------------------------
// MFMA flash attention -- EXACT r5 version (109us, VGPR 116, occ 20.4%).
// [r6-r9 post-mortem: mask-skip conditional correlated with VGPR 116->132
// and halved occupancy; DO NOT reintroduce conditional-mask or reg-prefetch.]
// Block = 4 waves = 64 q-rows of one (b,h). Paired q-tiles: qt = 31-px then
// px -> 33 kv-tile units per block, uniform. Flat grid 512; id&7 == g puts
// each KV group's 64 blocks on one XCD (K/V ~1.3MB L2-resident; FETCH
// 48.8->17.7MB, r5). Row-sum l via bf16-ones d-row: PV's 9th n-chunk
// accumulates l into O9[8]. Defer-max (T13, THR=8).
// ---------------------------------------------------------------------------
__global__ __launch_bounds__(256) void attn_mfma(const u16* __restrict__ qb16,
                                                 const u16* __restrict__ Kp,
                                                 const u16* __restrict__ Vt,
                                                 _Float16* __restrict__ atf) {
    __shared__ __align__(16) u16 lK[64 * 200];     // 64 kv-rows x 192 (+8 pad)
    __shared__ __align__(16) u16 lVt[144 * 72];    // 128 d-rows + 16 (ones) x 64 (+8 pad)
    __shared__ __align__(16) u16 lP[4][16 * 72];   // per-wave P 16x64 (+8 pad)

    const int t = threadIdx.x, lane = t & 63, w = t >> 6;
    const int quad = lane >> 4, l16 = lane & 15;
    const int id = blockIdx.x;                     // 0..511
    const int g = id & 7;                          // (b*4 + kv)
    const int b = g >> 2;
    const int k = id >> 3;                         // 0..63
    const int h = (g & 3) * 4 + (k & 3);
    const int px = k >> 2;                         // 0..15

    // ones-row init for the l-column trick (rows 128..143, cols 0..63)
#pragma unroll
    for (int c = 0; c < 4; ++c) {
        int i = c * 256 + t;                       // 0..1023
        int rr = 128 + (i >> 6), ccol = i & 63;
        lVt[rr * 72 + ccol] = (rr == 128) ? (u16)0x3F80 : (u16)0;
    }

    for (int ph = 0; ph < 2; ++ph) {
        const int qt = ph ? px : (31 - px);        // heavy tile first
        const int q0 = qt * 64;
        const int iw = q0 + w * 16;                // wave's q-row base

        short8 qf[6];
        {
            const u16* qp = qb16 + ((size_t)(b * S_ + iw + l16)) * 3072 + h * 192;
#pragma unroll
            for (int kc = 0; kc < 6; ++kc)
                qf[kc] = *(const short8*)&qp[kc * 32 + quad * 8];
        }

        f32x4 O9[9] = {};                          // [0..7]=O d-chunks, [8]=l (col l16==0)
        float mr[4] = {-1e30f, -1e30f, -1e30f, -1e30f};

        const int ntile = qt + 1;
        for (int tile = 0; tile < ntile; ++tile) {
            const int j0 = tile * 64;
            __syncthreads();
            // stage K tile: 64 rows x 192 u16 = 1536 x 16B, 6/thread
#pragma unroll
            for (int c = 0; c < 6; ++c) {
                int seg = c * 256 + t;
                int row = seg / 24, ch = (seg % 24) * 8;
                *(uint4*)&lK[row * 200 + ch] =
                    *(const uint4*)&Kp[((size_t)g * S_ + j0 + row) * 192 + ch];
            }
            // stage Vt tile: 128 d-rows x 64 u16 = 1024 x 16B, 4/thread
#pragma unroll
            for (int c = 0; c < 4; ++c) {
                int seg = c * 256 + t;
                int d = seg >> 3, ch = (seg & 7) * 8;
                *(uint4*)&lVt[d * 72 + ch] =
                    *(const uint4*)&Vt[((size_t)g * 128 + d) * S_ + j0 + ch];
            }
            __syncthreads();

            // S = Q K^T, four 16-col chunks
            f32x4 s4[4];
            __builtin_amdgcn_s_setprio(1);
#pragma unroll
            for (int cc = 0; cc < 4; ++cc) {
                f32x4 sx = {};
#pragma unroll
                for (int kc = 0; kc < 6; ++kc) {
                    short8 kf = *(const short8*)&lK[(cc * 16 + l16) * 200 + kc * 32 + quad * 8];
                    sx = __builtin_amdgcn_mfma_f32_16x16x32_bf16(qf[kc], kf, sx, 0, 0, 0);
                }
                s4[cc] = sx;
            }
            __builtin_amdgcn_s_setprio(0);

            // causal mask; rows ir = iw + quad*4 + r, cols j0 + cc*16 + l16
            float sv[4][4];
#pragma unroll
            for (int cc = 0; cc < 4; ++cc)
#pragma unroll
                for (int r = 0; r < 4; ++r) {
                    int ir = iw + quad * 4 + r;
                    sv[cc][r] = (j0 + cc * 16 + l16 <= ir) ? s4[cc][r] : -1e30f;
                }
            // row max across the 16-lane group
            float tm[4];
#pragma unroll
            for (int r = 0; r < 4; ++r)
                tm[r] = fmaxf(fmaxf(sv[0][r], sv[1][r]), fmaxf(sv[2][r], sv[3][r]));
#pragma unroll
            for (int m = 1; m < 16; m <<= 1)
#pragma unroll
                for (int r = 0; r < 4; ++r) tm[r] = fmaxf(tm[r], __shfl_xor(tm[r], m));
            // defer-max: only rescale when the max grew by > 8
            int small = (tm[0] <= mr[0] + 8.f) && (tm[1] <= mr[1] + 8.f) &&
                        (tm[2] <= mr[2] + 8.f) && (tm[3] <= mr[3] + 8.f);
            if (!__all(small)) {
                float al[4];
#pragma unroll
                for (int r = 0; r < 4; ++r) {
                    float mn = fmaxf(mr[r], tm[r]);
                    al[r] = __expf(mr[r] - mn);
                    mr[r] = mn;
                }
#pragma unroll
                for (int dc = 0; dc < 9; ++dc)
#pragma unroll
                    for (int r = 0; r < 4; ++r) O9[dc][r] *= al[r];
            }
            // P = exp(S - mr)  (bounded by e^8 when deferred)
            float p[4][4];
#pragma unroll
            for (int cc = 0; cc < 4; ++cc)
#pragma unroll
                for (int r = 0; r < 4; ++r)
                    p[cc][r] = __expf(sv[cc][r] - mr[r]);
            // P (C layout) -> LDS -> A-layout frags (k = 0..31, 32..63)
#pragma unroll
            for (int cc = 0; cc < 4; ++cc)
#pragma unroll
                for (int r = 0; r < 4; ++r)
                    lP[w][(quad * 4 + r) * 72 + cc * 16 + l16] = f2b(p[cc][r]);
            short8 pf0 = *(const short8*)&lP[w][l16 * 72 + quad * 8];
            short8 pf1 = *(const short8*)&lP[w][l16 * 72 + 32 + quad * 8];
            // O += P V ; 9th chunk accumulates l via the ones-row
            __builtin_amdgcn_s_setprio(1);
#pragma unroll
            for (int dc = 0; dc < 9; ++dc) {
                short8 vf0 = *(const short8*)&lVt[(dc * 16 + l16) * 72 + quad * 8];
                short8 vf1 = *(const short8*)&lVt[(dc * 16 + l16) * 72 + 32 + quad * 8];
                O9[dc] = __builtin_amdgcn_mfma_f32_16x16x32_bf16(pf0, vf0, O9[dc], 0, 0, 0);
                O9[dc] = __builtin_amdgcn_mfma_f32_16x16x32_bf16(pf1, vf1, O9[dc], 0, 0, 0);
            }
            __builtin_amdgcn_s_setprio(0);
        }
        // epilogue: l lives in O9[8] at col l16==0; broadcast within quad
        float inv[4];
#pragma unroll
        for (int r = 0; r < 4; ++r) {
            float lr = __shfl(O9[8][r], quad * 16);
            inv[r] = 1.f / fmaxf(lr, 1e-30f);
        }
#pragma unroll
        for (int dc = 0; dc < 8; ++dc)
#pragma unroll
            for (int r = 0; r < 4; ++r) {
                int ir = iw + quad * 4 + r;
                atf[((size_t)(b * S_ + ir)) * 2048 + h * 128 + dc * 16 + l16] =
                    (_Float16)cl(O9[dc][r] * inv[r]);
            }
    }
}

// ---------------------------------------------------------------------------
extern "C" void kernel_launch(void* const* d_in, const int* in_sizes, int n_in,
                              void* d_out, int out_size, void* d_ws, size_t ws_size,
                              hipStream_t stream) {
    const float* x     = (const float*)d_in[0];
    const float* cosc  = (const float*)d_in[1];
    const float* sinc  = (const float*)d_in[2];
    const int*   pos   = (const int*)d_in[3];
    // d_in[4] = attn_mask (causal tril) -- implemented analytically
    const float* W_DKV = (const float*)d_in[5];
    const float* W_UK  = (const float*)d_in[6];
    const float* W_UV  = (const float*)d_in[7];
    const float* W_DQ  = (const float*)d_in[8];
    const float* W_UQ  = (const float*)d_in[9];
    const float* W_KR  = (const float*)d_in[10];
    const float* W_QR  = (const float*)d_in[11];
    const float* W_O   = (const float*)d_in[12];
    (void)ws_size;

    float* outp      = (float*)d_out;            // [B,S,2048]
    float* ckv_out   = outp + 8388608;           // [B,S,512]
    float* krope_out = outp + 10485760;          // [B,NKV,S,64]

    // ---- workspace (~128 MB) ----
    char* w = (char*)d_ws;
    auto alloc = [&](size_t bytes) { char* p = w; w += bytes; return p; };
    _Float16* xf   = (_Float16*)alloc(16777216);  // x fp16 [4096][2048]
    _Float16* ckf  = (_Float16*)alloc(4194304);   // c_kv fp16 [4096][512]
    float*    krr  = (float*)alloc(4194304);      // K-rope raw fp32 [4096][256]
    _Float16* dqc  = (_Float16*)alloc(12582912);  // c_q fp16 [4096][1536]
    _Float16* qrf  = (_Float16*)alloc(8388608);   // q_rope_raw fp16 [4096][1024]
    u16*      qb16 = (u16*)alloc(25165824);       // Q bf16 pre-scaled [4096][16][192]
    u16*      Kp   = (u16*)alloc(6291456);        // [8][2048][192] bf16
    u16*      Vt   = (u16*)alloc(4194304);        // [8][128][2048] bf16
    _Float16* atf  = (_Float16*)alloc(16777216);  // attn out fp16 [4096][2048]
    _Float16* Wmeg = (_Float16*)alloc(13631488);  // [3328][2048] (DKV|KR|DQ|QR)
    _Float16* Wuq  = (_Float16*)alloc(6291456);   // [2048][1536]
    _Float16* Wukv = (_Float16*)alloc(1048576);   // [1024][512]  (UK|UV)
    _Float16* Wo   = (_Float16*)alloc(8388608);   // [2048][2048]

    const float sc = 0.07216878364870322f;        // 1/sqrt(192)

    // input / weight prep: ONE launch (8 transposes + x->fp16)
    prep_all<<<18432, dim3(32, 8), 0, stream>>>(x, xf,
                                                W_DKV, W_KR, W_DQ, W_QR,
                                                W_UQ, W_UK, W_UV, W_O,
                                                Wmeg, Wuq, Wukv, Wo);

    // mega projection (128x256 2-phase): c_kv (Output 1) | ckf | krr | dqc | qrf
    gemm2ph<<<416, 512, 0, stream>>>(xf, 2048, Wmeg,
                                     ckv_out, ckf, krr, dqc, qrf,
                                     1.f, 6, 3328, 2048, 13);
    // Q content (128x256 2-phase, mode 2): dqc @ Wuq^T -> qb16 bf16 pre-scaled
    gemm2ph<<<256, 512, 0, stream>>>(dqc, 1536, Wuq,
                                     qb16, nullptr, nullptr, nullptr, nullptr,
                                     sc, 2, 2048, 1536, 8);
    // K content | V pack (128-tile, mode 3): ckf @ Wukv^T -> Kp cols 0..127, Vt
    gemm_f16<<<dim3(8, 32), 256, 0, stream>>>(ckf, 512, Wukv,
                                              Kp, Vt, 1.f, 3, 1024, 512);

    // rope (merged): Q -> qb16 cols 128..191; K -> Output 2 + Kp cols 128..191
    rope_all<<<10240, 256, 0, stream>>>(qrf, krr, cosc, sinc, pos,
                                        qb16, krope_out, Kp);

    // attention + output projection (128x256 2-phase, mode 0)
    attn_mfma<<<512, 256, 0, stream>>>(qb16, Kp, Vt, atf);
    gemm2ph<<<256, 512, 0, stream>>>(atf, 2048, Wo,
                                     outp, nullptr, nullptr, nullptr, nullptr,
                                     1.f, 0, 2048, 2048, 8);
}

// Round 13
// 435.100 us; speedup vs baseline: 1.2869x; 1.0061x over previous
//
#include <hip/hip_runtime.h>
#include <stdint.h>

typedef unsigned short u16;
typedef unsigned int u32;

// Problem constants
#define B_    2
#define S_    2048
#define NQ_   16
#define NKV_  4
#define DH_   128
#define DR_   64
#define DT_   192
#define M_    4096   // B_*S_

using short8 = __attribute__((ext_vector_type(8))) short;
using f32x4  = __attribute__((ext_vector_type(4))) float;
using half8  = __attribute__((ext_vector_type(8))) _Float16;
using u16x4  = __attribute__((ext_vector_type(4))) u16;

__device__ __forceinline__ float cl(float f) {   // clamp diagnostic: inf/NaN -> +-3.38e38 signature
    return fminf(fmaxf(f, -3.38e38f), 3.38e38f);
}
__device__ __forceinline__ u16 f2b(float f) {    // fp32 -> bf16 RNE
    union { float f; u32 u; } v; v.f = f;
    u32 u = v.u;
    return (u16)((u + 0x7fffu + ((u >> 16) & 1u)) >> 16);
}
// async global->LDS, 16B per lane. LDS dest is wave-uniform base + lane*16.
__device__ __forceinline__ void gload16(const void* g, void* l) {
    __builtin_amdgcn_global_load_lds(
        (const __attribute__((address_space(1))) void*)g,
        (__attribute__((address_space(3))) void*)l,
        16, 0, 0);
}

// ---------------------------------------------------------------------------
// prep_all: ONE launch for all weight transposes + x->fp16. [verified r9-r12]
// block (32,8); flat-id range decode (all shapes compile-time).
// ---------------------------------------------------------------------------
__device__ __forceinline__ void wt_body(const float* __restrict__ W,
                                        _Float16* __restrict__ T,
                                        int K, int N, int kx, int ny,
                                        float (*tile)[33]) {
    int k0 = kx * 32, n0 = ny * 32;
    int tx = threadIdx.x, ty = threadIdx.y;
#pragma unroll
    for (int i = 0; i < 32; i += 8)
        tile[ty + i][tx] = W[(size_t)(k0 + ty + i) * N + n0 + tx];
    __syncthreads();
#pragma unroll
    for (int i = 0; i < 32; i += 8)
        T[(size_t)(n0 + ty + i) * K + k0 + tx] = (_Float16)tile[tx][ty + i];
}

__global__ __launch_bounds__(256) void prep_all(const float* __restrict__ x,
                                                _Float16* __restrict__ xf,
                                                const float* __restrict__ W_DKV,
                                                const float* __restrict__ W_KR,
                                                const float* __restrict__ W_DQ,
                                                const float* __restrict__ W_QR,
                                                const float* __restrict__ W_UQ,
                                                const float* __restrict__ W_UK,
                                                const float* __restrict__ W_UV,
                                                const float* __restrict__ W_O,
                                                _Float16* __restrict__ Wmeg,
                                                _Float16* __restrict__ Wuq,
                                                _Float16* __restrict__ Wukv,
                                                _Float16* __restrict__ Wo) {
    __shared__ float tile[32][33];
    const int id = blockIdx.x;
    if (id < 1024) {
        wt_body(W_DKV, Wmeg, 2048, 512, id & 63, id >> 6, tile);
    } else if (id < 1536) {
        int l = id - 1024;
        wt_body(W_KR, Wmeg + (size_t)512 * 2048, 2048, 256, l & 63, l >> 6, tile);
    } else if (id < 4608) {
        int l = id - 1536;
        wt_body(W_DQ, Wmeg + (size_t)768 * 2048, 2048, 1536, l & 63, l >> 6, tile);
    } else if (id < 6656) {
        int l = id - 4608;
        wt_body(W_QR, Wmeg + (size_t)2304 * 2048, 2048, 1024, l & 63, l >> 6, tile);
    } else if (id < 9728) {
        int l = id - 6656;
        wt_body(W_UQ, Wuq, 1536, 2048, l % 48, l / 48, tile);
    } else if (id < 9984) {
        int l = id - 9728;
        wt_body(W_UK, Wukv, 512, 512, l & 15, l >> 4, tile);
    } else if (id < 10240) {
        int l = id - 9984;
        wt_body(W_UV, Wukv + (size_t)512 * 512, 512, 512, l & 15, l >> 4, tile);
    } else if (id < 14336) {
        int l = id - 10240;
        wt_body(W_O, Wo, 2048, 2048, l & 63, l >> 6, tile);
    } else {
        int l = id - 14336;
        int t1 = threadIdx.y * 32 + threadIdx.x;
        size_t i = ((size_t)l * 256 + t1) * 8;
        float4 a = *(const float4*)(x + i);
        float4 b4 = *(const float4*)(x + i + 4);
        float va[8] = {a.x, a.y, a.z, a.w, b4.x, b4.y, b4.z, b4.w};
        half8 f;
#pragma unroll
        for (int j = 0; j < 8; ++j) f[j] = (_Float16)va[j];
        *(half8*)(xf + i) = f;
    }
}

// ---------------------------------------------------------------------------
// 128x256 fp16 MFMA GEMM body, BK=32 double-buffer. LDS 2x(128+256)x32x2B =
// 48KB -> 3 blocks/CU capacity [r12 post-mortem: BK=64's 96KB gave 1/CU ->
// 416-block mega ran as 256+160 rounds (81% util) and 2 waves/SIMD had
// nothing to hide the barrier drain; MfmaUtil 18.7%. At 48KB all mega blocks
// co-reside (13 waves/CU) and cross-block TLP hides the drain].
// Schedule per K-step: STAGE(buf^1, kt+32) FIRST, then ds_read + 16 MFMA per
// wave on buf[cur], then ONE __syncthreads() (compiler's auto vmcnt/lgkm
// drain). 8 waves (2x4), per-wave output 64x64 (acc[4][4]).
// Bank conflicts [G4/rule21]: rows of 32 fp16 = 4 chunks; source pre-swizzle
// col slot = cop ^ ((row>>1)&3) (LDS linear for gload_lds) + same XOR on
// ds_read -> every bank exactly 2 lanes (free, m136). [BK=64 variant of this
// scheme measured SQ_LDS_BANK_CONFLICT == 0 in r12.]
// XCD swizzle [T1]: swz=(id&7)*cpx+id>>3; all sub-grids %8==0.
// Epilogue modes: 0=fp32 C (cl); 2=qb16 bf16 pre-scaled; 3=Kp|Vt pack;
// 6=mega split (boundaries 512/768/2304 are 256-aligned -> tiles region-pure).
// Layouts [m89/m91 verified]: A-frag A[m=lane&15][k=quad*8+j];
// B-frag B[n=lane&15][k=quad*8+j]; C/D col=lane&15, row=quad*4+reg.
// ---------------------------------------------------------------------------
__device__ __forceinline__ void g2ph32_body(const _Float16* __restrict__ A, int lda,
                                            const _Float16* __restrict__ Bt,
                                            void* p0, void* p1, void* p2,
                                            void* p3, void* p4,
                                            float cscale, int mode,
                                            int N, int K, int NBX, int id,
                                            _Float16 (*lA)[128 * 32],
                                            _Float16 (*lB)[256 * 32]) {
    const int t = threadIdx.x, lane = t & 63, w = t >> 6;   // 8 waves
    const int quad = lane >> 4, l16 = lane & 15;
    const int wr = w >> 2, wc = w & 3;                      // 2 x 4 wave grid
    const int cpx = (NBX * 32) >> 3;                        // nwg = NBX*32
    const int swz = (id & 7) * cpx + (id >> 3);
    const int bx = swz % NBX, by = swz / NBX;
    const int m0 = by * 128, n0 = bx * 256;
    f32x4 acc[4][4] = {};

    auto STAGE = [&](int buf, int kt) {
        // A: 128x32 = 512 x16B chunks, 1/thread
        {
            const int chunk = t;
            const int row = chunk >> 2, cop = chunk & 3;
            const int co = (cop ^ ((row >> 1) & 3)) * 8;    // source pre-swizzle
            gload16(A + (size_t)(m0 + row) * lda + kt + co, lA[buf] + chunk * 8);
        }
        // B: 256x32 = 1024 x16B chunks, 2/thread
#pragma unroll
        for (int q = 0; q < 2; ++q) {
            const int chunk = q * 512 + t;
            const int row = chunk >> 2, cop = chunk & 3;
            const int co = (cop ^ ((row >> 1) & 3)) * 8;
            gload16(Bt + (size_t)(n0 + row) * K + kt + co, lB[buf] + chunk * 8);
        }
    };

    STAGE(0, 0);
    __syncthreads();
    int cur = 0;
    for (int kt = 0; kt < K; kt += 32) {
        if (kt + 32 < K) STAGE(cur ^ 1, kt + 32);           // prefetch next
        half8 af[4], bf[4];
#pragma unroll
        for (int i = 0; i < 4; ++i) {
            const int r = wr * 64 + i * 16 + l16;
            af[i] = *(const half8*)&lA[cur][(r * 4 + (quad ^ ((r >> 1) & 3))) * 8];
        }
#pragma unroll
        for (int j = 0; j < 4; ++j) {
            const int r = wc * 64 + j * 16 + l16;
            bf[j] = *(const half8*)&lB[cur][(r * 4 + (quad ^ ((r >> 1) & 3))) * 8];
        }
#pragma unroll
        for (int i = 0; i < 4; ++i)
#pragma unroll
            for (int j = 0; j < 4; ++j)
                acc[i][j] = __builtin_amdgcn_mfma_f32_16x16x32_f16(af[i], bf[j], acc[i][j], 0, 0, 0);
        __syncthreads();                                    // drains prefetch + reads
        cur ^= 1;
    }
#pragma unroll
    for (int i = 0; i < 4; ++i)
#pragma unroll
        for (int j = 0; j < 4; ++j) {
            const int mbase = m0 + wr * 64 + i * 16 + quad * 4;
            const int nn = n0 + wc * 64 + j * 16 + l16;
            if (mode == 0) {
                float* C = (float*)p0;
#pragma unroll
                for (int r = 0; r < 4; ++r)
                    C[(size_t)(mbase + r) * N + nn] = cl(acc[i][j][r]);
            } else if (mode == 2) {
                u16* Q = (u16*)p0;
                const int h = nn >> 7, dcol = nn & 127;
#pragma unroll
                for (int r = 0; r < 4; ++r)
                    Q[(size_t)(mbase + r) * 3072 + h * 192 + dcol] =
                        f2b(acc[i][j][r] * cscale);
            } else if (mode == 3) {
                const int bb = mbase >> 11, s = mbase & 2047;
                if (nn < 512) {
                    u16* Kp = (u16*)p0;
                    const int kv = nn >> 7, d = nn & 127;
                    const size_t rb = ((size_t)((bb * 4 + kv) * 2048 + s)) * 192 + d;
#pragma unroll
                    for (int r = 0; r < 4; ++r)
                        Kp[rb + (size_t)r * 192] = f2b(acc[i][j][r]);
                } else {
                    u16* Vt = (u16*)p1;
                    const int e = nn - 512, kv = e >> 7, d = e & 127;
                    u16x4 pk;
                    pk[0] = f2b(acc[i][j][0]); pk[1] = f2b(acc[i][j][1]);
                    pk[2] = f2b(acc[i][j][2]); pk[3] = f2b(acc[i][j][3]);
                    *(u16x4*)&((u16*)Vt)[((size_t)((bb * 4 + kv) * 128 + d)) * 2048 + s] = pk;
                }
            } else {   // mode 6: mega projection split
                if (nn < 512) {
                    float* ckv = (float*)p0;
                    _Float16* ckf = (_Float16*)p1;
#pragma unroll
                    for (int r = 0; r < 4; ++r) {
                        float v = acc[i][j][r];
                        ckv[(size_t)(mbase + r) * 512 + nn] = cl(v);
                        ckf[(size_t)(mbase + r) * 512 + nn] = (_Float16)v;
                    }
                } else if (nn < 768) {
                    float* krr = (float*)p2;
#pragma unroll
                    for (int r = 0; r < 4; ++r)
                        krr[(size_t)(mbase + r) * 256 + (nn - 512)] = acc[i][j][r];
                } else if (nn < 2304) {
                    _Float16* dqc = (_Float16*)p3;
#pragma unroll
                    for (int r = 0; r < 4; ++r)
                        dqc[(size_t)(mbase + r) * 1536 + (nn - 768)] = (_Float16)acc[i][j][r];
                } else {
                    _Float16* qrf = (_Float16*)p4;
#pragma unroll
                    for (int r = 0; r < 4; ++r)
                        qrf[(size_t)(mbase + r) * 1024 + (nn - 2304)] = (_Float16)acc[i][j][r];
                }
            }
        }
}

// mega projection: N=3328, NBX=13, grid 416 -> ALL co-resident at 3 blk/CU.
__global__ __launch_bounds__(512) void gemm_mega(const _Float16* __restrict__ xf,
                                                 const _Float16* __restrict__ Wmeg,
                                                 float* __restrict__ ckv,
                                                 _Float16* __restrict__ ckf,
                                                 float* __restrict__ krr,
                                                 _Float16* __restrict__ dqc,
                                                 _Float16* __restrict__ qrf) {
    __shared__ __align__(16) _Float16 lA[2][128 * 32];
    __shared__ __align__(16) _Float16 lB[2][256 * 32];
    g2ph32_body(xf, 2048, Wmeg, ckv, ckf, krr, dqc, qrf,
                1.f, 6, 3328, 2048, 13, blockIdx.x, lA, lB);
}

// ---------------------------------------------------------------------------
// stage3: ONE hetero launch for everything that depends only on mega outputs.
//   [0,256)    : UQ   (dqc @ Wuq^T -> qb16 bf16 pre-scaled, mode 2, NBX=8)
//   [256,384)  : UKV  (ckf @ Wukv^T -> Kp cols 0..127 | Vt, mode 3, NBX=4)
//   [384,5504) : rope (Q -> qb16 cols 128..191; K -> Krope + Kp cols 128..191)
// All GEMM blocks (384) co-resident at 48KB/3-per-CU; rope blocks fill the
// remaining slots CONCURRENTLY (was ~25us of serial launches). Concurrent-
// writer safety: qb16 head base h*384B and Kp row base s*384B are 128-aligned,
// so every 128B line is written by exactly one path. Rope math byte-identical
// to r12's rope_all (512-thread re-index).
// ---------------------------------------------------------------------------
__global__ __launch_bounds__(512) void stage3(const _Float16* __restrict__ dqc,
                                              const _Float16* __restrict__ Wuq,
                                              u16* __restrict__ qb16, float scq,
                                              const _Float16* __restrict__ ckf,
                                              const _Float16* __restrict__ Wukv,
                                              u16* __restrict__ Kp,
                                              u16* __restrict__ Vt,
                                              const _Float16* __restrict__ qrf,
                                              const float* __restrict__ krr,
                                              const float* __restrict__ cosc,
                                              const float* __restrict__ sinc,
                                              const int* __restrict__ pos,
                                              float* __restrict__ Krope) {
    __shared__ __align__(16) _Float16 lA[2][128 * 32];
    __shared__ __align__(16) _Float16 lB[2][256 * 32];
    const int id = blockIdx.x;
    if (id < 256) {
        g2ph32_body(dqc, 1536, Wuq, qb16, nullptr, nullptr, nullptr, nullptr,
                    scq, 2, 2048, 1536, 8, id, lA, lB);
    } else if (id < 384) {
        g2ph32_body(ckf, 512, Wukv, Kp, Vt, nullptr, nullptr, nullptr,
                    1.f, 3, 1024, 512, 4, id - 256, lA, lB);
    } else {
        const float sc = 0.07216878364870322f;       // 1/sqrt(192)
        int ti = (id - 384) * 512 + threadIdx.x;
        if (ti < 4096 * 16 * 32) {
            int d = ti & 31, h = (ti >> 5) & 15, rowi = ti >> 9;
            int s = rowi & 2047;
            int p = pos[s];
            float c1 = cosc[p * 64 + d],      s1 = sinc[p * 64 + d];
            float c2 = cosc[p * 64 + 32 + d], s2 = sinc[p * 64 + 32 + d];
            const _Float16* base = qrf + (size_t)rowi * 1024 + h * 64;
            float x1 = (float)base[d];
            float x2 = (float)base[d + 32];
            u16* q = qb16 + (size_t)rowi * 3072 + h * 192 + 128;
            q[d]      = f2b((x1 * c1 - x2 * s1) * sc);
            q[d + 32] = f2b((x2 * c2 + x1 * s2) * sc);
        } else {
            int t2 = ti - 4096 * 16 * 32;            // < 4096*4*32
            int d = t2 & 31, kv = (t2 >> 5) & 3, rowi = t2 >> 7;
            int b = rowi >> 11, s = rowi & 2047;
            int p = pos[s];
            float c1 = cosc[p * 64 + d],      s1 = sinc[p * 64 + d];
            float c2 = cosc[p * 64 + 32 + d], s2 = sinc[p * 64 + 32 + d];
            float x1 = krr[(size_t)rowi * 256 + kv * 64 + d];
            float x2 = krr[(size_t)rowi * 256 + kv * 64 + 32 + d];
            float o1 = x1 * c1 - x2 * s1;
            float o2 = x2 * c2 + x1 * s2;
            int g = b * NKV_ + kv;
            size_t ob = ((size_t)(g * S_) + s) * 64;
            Krope[ob + d]      = cl(o1);
            Krope[ob + 32 + d] = cl(o2);
            u16* kp = Kp + ((size_t)(g * S_ + s)) * 192 + 128;
            kp[d]      = f2b(o1);
            kp[32 + d] = f2b(o2);
        }
    }
}

// ---------------------------------------------------------------------------
// 128x256 fp16 MFMA GEMM, BK=64 2-phase double-buffer (W_O only; grid 256 =
// 1/CU either way, so the 96KB variant's longer compute phase per barrier is
// the right trade here -- measured ~77us in r12, keep verbatim).
// [bank-conflict-free swizzle verified r12: SQ_LDS_BANK_CONFLICT == 0]
// ---------------------------------------------------------------------------
__global__ __launch_bounds__(512) void gemm2ph(const _Float16* __restrict__ A, int lda,
                                               const _Float16* __restrict__ Bt,
                                               void* p0,
                                               float cscale, int mode,
                                               int N, int K, int NBX) {
    __shared__ __align__(16) _Float16 lA[2][128 * 64];
    __shared__ __align__(16) _Float16 lB[2][256 * 64];
    const int t = threadIdx.x, lane = t & 63, w = t >> 6;   // 8 waves
    const int quad = lane >> 4, l16 = lane & 15;
    const int wr = w >> 2, wc = w & 3;                      // 2 x 4 wave grid
    const int id = blockIdx.x;
    const int cpx = (NBX * 32) >> 3;                        // nwg = NBX*32
    const int swz = (id & 7) * cpx + (id >> 3);
    const int bx = swz % NBX, by = swz / NBX;
    const int m0 = by * 128, n0 = bx * 256;
    f32x4 acc[4][4] = {};

    auto STAGE = [&](int buf, int kt) {
#pragma unroll
        for (int q = 0; q < 2; ++q) {
            const int chunk = q * 512 + t;
            const int row = chunk >> 3, cop = chunk & 7;
            const int co = (cop ^ (row & 7)) * 8;           // source pre-swizzle
            gload16(A + (size_t)(m0 + row) * lda + kt + co,
                    lA[buf] + (q * 512 + w * 64) * 8);
        }
#pragma unroll
        for (int q = 0; q < 4; ++q) {
            const int chunk = q * 512 + t;
            const int row = chunk >> 3, cop = chunk & 7;
            const int co = (cop ^ (row & 7)) * 8;
            gload16(Bt + (size_t)(n0 + row) * K + kt + co,
                    lB[buf] + (q * 512 + w * 64) * 8);
        }
    };

    STAGE(0, 0);
    __syncthreads();
    int cur = 0;
    for (int kt = 0; kt < K; kt += 64) {
        if (kt + 64 < K) STAGE(cur ^ 1, kt + 64);           // prefetch next
        const _Float16* bufA = lA[cur];
        const _Float16* bufB = lB[cur];
#pragma unroll
        for (int kc = 0; kc < 2; ++kc) {
            half8 af[4], bf[4];
#pragma unroll
            for (int i = 0; i < 4; ++i) {
                const int r = wr * 64 + i * 16 + l16;
                af[i] = *(const half8*)&bufA[(r * 8 + ((kc * 4 + quad) ^ (r & 7))) * 8];
            }
#pragma unroll
            for (int j = 0; j < 4; ++j) {
                const int r = wc * 64 + j * 16 + l16;
                bf[j] = *(const half8*)&bufB[(r * 8 + ((kc * 4 + quad) ^ (r & 7))) * 8];
            }
#pragma unroll
            for (int i = 0; i < 4; ++i)
#pragma unroll
                for (int j = 0; j < 4; ++j)
                    acc[i][j] = __builtin_amdgcn_mfma_f32_16x16x32_f16(af[i], bf[j], acc[i][j], 0, 0, 0);
        }
        __syncthreads();                                    // drains prefetch + reads
        cur ^= 1;
    }
#pragma unroll
    for (int i = 0; i < 4; ++i)
#pragma unroll
        for (int j = 0; j < 4; ++j) {
            const int mbase = m0 + wr * 64 + i * 16 + quad * 4;
            const int nn = n0 + wc * 64 + j * 16 + l16;
            float* C = (float*)p0;                          // mode 0 only (W_O)
#pragma unroll
            for (int r = 0; r < 4; ++r)
                C[(size_t)(mbase + r) * N + nn] = cl(acc[i][j][r]);
        }
    (void)cscale; (void)mode;
}

// ---------------------------------------------------------------------------
// MFMA flash attention -- EXACT r5 version (109us, VGPR 116, occ 20.4%).
// [r6-r9 post-mortem: mask-skip conditional correlated with VGPR 116->132
// and halved occupancy; DO NOT reintroduce conditional-mask or reg-prefetch.]
// Block = 4 waves = 64 q-rows of one (b,h). Paired q-tiles: qt = 31-px then
// px -> 33 kv-tile units per block, uniform. Flat grid 512; id&7 == g puts
// each KV group's 64 blocks on one XCD (K/V ~1.3MB L2-resident; FETCH
// 48.8->17.7MB, r5). Row-sum l via bf16-ones d-row: PV's 9th n-chunk
// accumulates l into O9[8]. Defer-max (T13, THR=8).
// ---------------------------------------------------------------------------
__global__ __launch_bounds__(256) void attn_mfma(const u16* __restrict__ qb16,
                                                 const u16* __restrict__ Kp,
                                                 const u16* __restrict__ Vt,
                                                 _Float16* __restrict__ atf) {
    __shared__ __align__(16) u16 lK[64 * 200];     // 64 kv-rows x 192 (+8 pad)
    __shared__ __align__(16) u16 lVt[144 * 72];    // 128 d-rows + 16 (ones) x 64 (+8 pad)
    __shared__ __align__(16) u16 lP[4][16 * 72];   // per-wave P 16x64 (+8 pad)

    const int t = threadIdx.x, lane = t & 63, w = t >> 6;
    const int quad = lane >> 4, l16 = lane & 15;
    const int id = blockIdx.x;                     // 0..511
    const int g = id & 7;                          // (b*4 + kv)
    const int b = g >> 2;
    const int k = id >> 3;                         // 0..63
    const int h = (g & 3) * 4 + (k & 3);
    const int px = k >> 2;                         // 0..15

    // ones-row init for the l-column trick (rows 128..143, cols 0..63)
#pragma unroll
    for (int c = 0; c < 4; ++c) {
        int i = c * 256 + t;                       // 0..1023
        int rr = 128 + (i >> 6), ccol = i & 63;
        lVt[rr * 72 + ccol] = (rr == 128) ? (u16)0x3F80 : (u16)0;
    }

    for (int ph = 0; ph < 2; ++ph) {
        const int qt = ph ? px : (31 - px);        // heavy tile first
        const int q0 = qt * 64;
        const int iw = q0 + w * 16;                // wave's q-row base

        short8 qf[6];
        {
            const u16* qp = qb16 + ((size_t)(b * S_ + iw + l16)) * 3072 + h * 192;
#pragma unroll
            for (int kc = 0; kc < 6; ++kc)
                qf[kc] = *(const short8*)&qp[kc * 32 + quad * 8];
        }

        f32x4 O9[9] = {};                          // [0..7]=O d-chunks, [8]=l (col l16==0)
        float mr[4] = {-1e30f, -1e30f, -1e30f, -1e30f};

        const int ntile = qt + 1;
        for (int tile = 0; tile < ntile; ++tile) {
            const int j0 = tile * 64;
            __syncthreads();
            // stage K tile: 64 rows x 192 u16 = 1536 x 16B, 6/thread
#pragma unroll
            for (int c = 0; c < 6; ++c) {
                int seg = c * 256 + t;
                int row = seg / 24, ch = (seg % 24) * 8;
                *(uint4*)&lK[row * 200 + ch] =
                    *(const uint4*)&Kp[((size_t)g * S_ + j0 + row) * 192 + ch];
            }
            // stage Vt tile: 128 d-rows x 64 u16 = 1024 x 16B, 4/thread
#pragma unroll
            for (int c = 0; c < 4; ++c) {
                int seg = c * 256 + t;
                int d = seg >> 3, ch = (seg & 7) * 8;
                *(uint4*)&lVt[d * 72 + ch] =
                    *(const uint4*)&Vt[((size_t)g * 128 + d) * S_ + j0 + ch];
            }
            __syncthreads();

            // S = Q K^T, four 16-col chunks
            f32x4 s4[4];
            __builtin_amdgcn_s_setprio(1);
#pragma unroll
            for (int cc = 0; cc < 4; ++cc) {
                f32x4 sx = {};
#pragma unroll
                for (int kc = 0; kc < 6; ++kc) {
                    short8 kf = *(const short8*)&lK[(cc * 16 + l16) * 200 + kc * 32 + quad * 8];
                    sx = __builtin_amdgcn_mfma_f32_16x16x32_bf16(qf[kc], kf, sx, 0, 0, 0);
                }
                s4[cc] = sx;
            }
            __builtin_amdgcn_s_setprio(0);

            // causal mask; rows ir = iw + quad*4 + r, cols j0 + cc*16 + l16
            float sv[4][4];
#pragma unroll
            for (int cc = 0; cc < 4; ++cc)
#pragma unroll
                for (int r = 0; r < 4; ++r) {
                    int ir = iw + quad * 4 + r;
                    sv[cc][r] = (j0 + cc * 16 + l16 <= ir) ? s4[cc][r] : -1e30f;
                }
            // row max across the 16-lane group
            float tm[4];
#pragma unroll
            for (int r = 0; r < 4; ++r)
                tm[r] = fmaxf(fmaxf(sv[0][r], sv[1][r]), fmaxf(sv[2][r], sv[3][r]));
#pragma unroll
            for (int m = 1; m < 16; m <<= 1)
#pragma unroll
                for (int r = 0; r < 4; ++r) tm[r] = fmaxf(tm[r], __shfl_xor(tm[r], m));
            // defer-max: only rescale when the max grew by > 8
            int small = (tm[0] <= mr[0] + 8.f) && (tm[1] <= mr[1] + 8.f) &&
                        (tm[2] <= mr[2] + 8.f) && (tm[3] <= mr[3] + 8.f);
            if (!__all(small)) {
                float al[4];
#pragma unroll
                for (int r = 0; r < 4; ++r) {
                    float mn = fmaxf(mr[r], tm[r]);
                    al[r] = __expf(mr[r] - mn);
                    mr[r] = mn;
                }
#pragma unroll
                for (int dc = 0; dc < 9; ++dc)
#pragma unroll
                    for (int r = 0; r < 4; ++r) O9[dc][r] *= al[r];
            }
            // P = exp(S - mr)  (bounded by e^8 when deferred)
            float p[4][4];
#pragma unroll
            for (int cc = 0; cc < 4; ++cc)
#pragma unroll
                for (int r = 0; r < 4; ++r)
                    p[cc][r] = __expf(sv[cc][r] - mr[r]);
            // P (C layout) -> LDS -> A-layout frags (k = 0..31, 32..63)
#pragma unroll
            for (int cc = 0; cc < 4; ++cc)
#pragma unroll
                for (int r = 0; r < 4; ++r)
                    lP[w][(quad * 4 + r) * 72 + cc * 16 + l16] = f2b(p[cc][r]);
            short8 pf0 = *(const short8*)&lP[w][l16 * 72 + quad * 8];
            short8 pf1 = *(const short8*)&lP[w][l16 * 72 + 32 + quad * 8];
            // O += P V ; 9th chunk accumulates l via the ones-row
            __builtin_amdgcn_s_setprio(1);
#pragma unroll
            for (int dc = 0; dc < 9; ++dc) {
                short8 vf0 = *(const short8*)&lVt[(dc * 16 + l16) * 72 + quad * 8];
                short8 vf1 = *(const short8*)&lVt[(dc * 16 + l16) * 72 + 32 + quad * 8];
                O9[dc] = __builtin_amdgcn_mfma_f32_16x16x32_bf16(pf0, vf0, O9[dc], 0, 0, 0);
                O9[dc] = __builtin_amdgcn_mfma_f32_16x16x32_bf16(pf1, vf1, O9[dc], 0, 0, 0);
            }
            __builtin_amdgcn_s_setprio(0);
        }
        // epilogue: l lives in O9[8] at col l16==0; broadcast within quad
        float inv[4];
#pragma unroll
        for (int r = 0; r < 4; ++r) {
            float lr = __shfl(O9[8][r], quad * 16);
            inv[r] = 1.f / fmaxf(lr, 1e-30f);
        }
#pragma unroll
        for (int dc = 0; dc < 8; ++dc)
#pragma unroll
            for (int r = 0; r < 4; ++r) {
                int ir = iw + quad * 4 + r;
                atf[((size_t)(b * S_ + ir)) * 2048 + h * 128 + dc * 16 + l16] =
                    (_Float16)cl(O9[dc][r] * inv[r]);
            }
    }
}

// ---------------------------------------------------------------------------
extern "C" void kernel_launch(void* const* d_in, const int* in_sizes, int n_in,
                              void* d_out, int out_size, void* d_ws, size_t ws_size,
                              hipStream_t stream) {
    const float* x     = (const float*)d_in[0];
    const float* cosc  = (const float*)d_in[1];
    const float* sinc  = (const float*)d_in[2];
    const int*   pos   = (const int*)d_in[3];
    // d_in[4] = attn_mask (causal tril) -- implemented analytically
    const float* W_DKV = (const float*)d_in[5];
    const float* W_UK  = (const float*)d_in[6];
    const float* W_UV  = (const float*)d_in[7];
    const float* W_DQ  = (const float*)d_in[8];
    const float* W_UQ  = (const float*)d_in[9];
    const float* W_KR  = (const float*)d_in[10];
    const float* W_QR  = (const float*)d_in[11];
    const float* W_O   = (const float*)d_in[12];
    (void)ws_size;

    float* outp      = (float*)d_out;            // [B,S,2048]
    float* ckv_out   = outp + 8388608;           // [B,S,512]
    float* krope_out = outp + 10485760;          // [B,NKV,S,64]

    // ---- workspace (~128 MB) ----
    char* w = (char*)d_ws;
    auto alloc = [&](size_t bytes) { char* p = w; w += bytes; return p; };
    _Float16* xf   = (_Float16*)alloc(16777216);  // x fp16 [4096][2048]
    _Float16* ckf  = (_Float16*)alloc(4194304);   // c_kv fp16 [4096][512]
    float*    krr  = (float*)alloc(4194304);      // K-rope raw fp32 [4096][256]
    _Float16* dqc  = (_Float16*)alloc(12582912);  // c_q fp16 [4096][1536]
    _Float16* qrf  = (_Float16*)alloc(8388608);   // q_rope_raw fp16 [4096][1024]
    u16*      qb16 = (u16*)alloc(25165824);       // Q bf16 pre-scaled [4096][16][192]
    u16*      Kp   = (u16*)alloc(6291456);        // [8][2048][192] bf16
    u16*      Vt   = (u16*)alloc(4194304);        // [8][128][2048] bf16
    _Float16* atf  = (_Float16*)alloc(16777216);  // attn out fp16 [4096][2048]
    _Float16* Wmeg = (_Float16*)alloc(13631488);  // [3328][2048] (DKV|KR|DQ|QR)
    _Float16* Wuq  = (_Float16*)alloc(6291456);   // [2048][1536]
    _Float16* Wukv = (_Float16*)alloc(1048576);   // [1024][512]  (UK|UV)
    _Float16* Wo   = (_Float16*)alloc(8388608);   // [2048][2048]

    const float sc = 0.07216878364870322f;        // 1/sqrt(192)

    // input / weight prep: ONE launch (8 transposes + x->fp16)
    prep_all<<<18432, dim3(32, 8), 0, stream>>>(x, xf,
                                                W_DKV, W_KR, W_DQ, W_QR,
                                                W_UQ, W_UK, W_UV, W_O,
                                                Wmeg, Wuq, Wukv, Wo);

    // mega projection (BK=32 dbuf, 416 blocks all co-resident at 3/CU):
    // c_kv (Output 1) | ckf | krr | dqc | qrf
    gemm_mega<<<416, 512, 0, stream>>>(xf, Wmeg, ckv_out, ckf, krr, dqc, qrf);

    // stage3 hetero: UQ + UKV + rope, all concurrent (depend only on mega)
    stage3<<<5504, 512, 0, stream>>>(dqc, Wuq, qb16, sc,
                                     ckf, Wukv, Kp, Vt,
                                     qrf, krr, cosc, sinc, pos, krope_out);

    // attention + output projection (W_O: BK=64 2ph, verified r12)
    attn_mfma<<<512, 256, 0, stream>>>(qb16, Kp, Vt, atf);
    gemm2ph<<<256, 512, 0, stream>>>(atf, 2048, Wo,
                                     outp, 1.f, 0, 2048, 2048, 8);
}